// Round 10
// baseline (1269.870 us; speedup 1.0000x reference)
//
#include <hip/hip_runtime.h>
#include <math.h>

#define BB 8
#define TT 512
#define HH 8
#define ESS 96
#define EMBD 768
#define FFD 3072
#define NLAYER 6
#define KHMAX 576   // 96 * 6, history feature pitch

typedef unsigned short ushort_t;
typedef __attribute__((ext_vector_type(8))) short short8;
typedef __attribute__((ext_vector_type(4))) float f32x4;
typedef __attribute__((ext_vector_type(4))) unsigned short ushort4v;

static __device__ __forceinline__ ushort_t f2b(float f) {
    unsigned u = __builtin_bit_cast(unsigned, f);
    unsigned r = (u + 0x7fffu + ((u >> 16) & 1u)) >> 16;
    return (ushort_t)r;
}

#define GLDS(gp, lp) __builtin_amdgcn_global_load_lds( \
    (const __attribute__((address_space(1))) void*)(gp), \
    (__attribute__((address_space(3))) void*)(lp), 16, 0, 0)

// ---------------------------------------------------------------------------
// bf16 MFMA GEMM: C = alpha * A(M,K) * B(N,K)^T (+beta*C) (+bias) (+gelu)
// ---------------------------------------------------------------------------
template<int BM, int BN, int WM, int WN, int OUTBF, int HASBIAS, int GELU, int BETA>
__global__ __launch_bounds__(256) void gemm_mfma(
    const ushort_t* __restrict__ A, int lda,
    const ushort_t* __restrict__ B, int ldb,
    void* __restrict__ Cv, int ldc,
    int K, float alpha,
    const float* __restrict__ bias,
    int bdiv, long sAb, long sAh, long sBb, long sBh, long sCb, long sCh)
{
    constexpr int BK = 32;
    constexpr int WTM = BM / WM;
    constexpr int WTN = BN / WN;
    constexpr int MF = WTM / 16, NF = WTN / 16;
    constexpr int ACH = (BM * BK * 2) / 1024;
    constexpr int BCH = (BN * BK * 2) / 1024;

    const int z = blockIdx.z;
    const int zb = z / bdiv, zh = z % bdiv;
    A += (long)zb * sAb + (long)zh * sAh;
    B += (long)zb * sBb + (long)zh * sBh;
    const long coff = (long)zb * sCb + (long)zh * sCh;

    __shared__ ushort_t As[BM * BK];
    __shared__ ushort_t Bs[BN * BK];

    const int tid = threadIdx.x;
    const int w = tid >> 6, lane = tid & 63;
    const int wr = w / WN, wc = w % WN;
    const int m0 = blockIdx.y * BM;
    const int n0 = blockIdx.x * BN;

    f32x4 acc[MF][NF] = {};

    const int fr = lane & 15;
    const int kb = lane >> 4;

    for (int k0 = 0; k0 < K; k0 += BK) {
#pragma unroll
        for (int q = 0; q < (ACH + 3) / 4; ++q) {
            int ci = q * 4 + w;
            if (ci < ACH) {
                int e = ci * 512 + lane * 8;
                int r = e >> 5, c = e & 31;
                GLDS(A + (long)(m0 + r) * lda + (k0 + c), (char*)As + ci * 1024);
            }
        }
#pragma unroll
        for (int q = 0; q < (BCH + 3) / 4; ++q) {
            int ci = q * 4 + w;
            if (ci < BCH) {
                int e = ci * 512 + lane * 8;
                int r = e >> 5, c = e & 31;
                GLDS(B + (long)(n0 + r) * ldb + (k0 + c), (char*)Bs + ci * 1024);
            }
        }
        __syncthreads();

        short8 af[MF], bfr[NF];
#pragma unroll
        for (int fm = 0; fm < MF; ++fm)
            af[fm] = *(const short8*)&As[(wr * WTM + fm * 16 + fr) * 32 + kb * 8];
#pragma unroll
        for (int fn = 0; fn < NF; ++fn)
            bfr[fn] = *(const short8*)&Bs[(wc * WTN + fn * 16 + fr) * 32 + kb * 8];
#pragma unroll
        for (int fm = 0; fm < MF; ++fm)
#pragma unroll
            for (int fn = 0; fn < NF; ++fn)
                acc[fm][fn] = __builtin_amdgcn_mfma_f32_16x16x32_bf16(
                    af[fm], bfr[fn], acc[fm][fn], 0, 0, 0);
        __syncthreads();
    }

    const int cr = lane >> 4;
    const int cc = lane & 15;
#pragma unroll
    for (int fm = 0; fm < MF; ++fm) {
#pragma unroll
        for (int fn = 0; fn < NF; ++fn) {
#pragma unroll
            for (int j = 0; j < 4; ++j) {
                int gm = m0 + wr * WTM + fm * 16 + cr * 4 + j;
                int gn = n0 + wc * WTN + fn * 16 + cc;
                float v = alpha * acc[fm][fn][j];
                if (HASBIAS) v += bias[gn];
                if (GELU) v = 0.5f * v * (1.f + erff(v * 0.70710678118654752f));
                long idx = coff + (long)gm * ldc + gn;
                if (BETA) v += ((const float*)Cv)[idx];
                if (OUTBF) ((ushort_t*)Cv)[idx] = f2b(v);
                else       ((float*)Cv)[idx] = v;
            }
        }
    }
}

// ---------------------------------------------------------------------------
// kqv GEMM with scatter epilogue: A = xb (B*T*H, 96), B = Wkqv (288, 96).
// Writes K -> Kh[..,loff+n], Q*scale -> Qh[..,loff+n], V -> Vt[(bh,s),t].
// BM=128, BN=96 (block x: 0=K,1=Q,2=V uniformly), grid (3,256).
// ---------------------------------------------------------------------------
__global__ __launch_bounds__(256) void kqv_gemm(
    const ushort_t* __restrict__ A,       // xb, lda 96
    const ushort_t* __restrict__ Bw,      // Wkqvb, ldb 96
    ushort_t* __restrict__ Kh, ushort_t* __restrict__ Qh,
    ushort_t* __restrict__ Vt, int loff, float scale)
{
    constexpr int BM = 128, BN = 96, BK = 32;
    __shared__ ushort_t As[BM * BK];
    __shared__ ushort_t Bs[BN * BK];

    const int tid = threadIdx.x;
    const int w = tid >> 6, lane = tid & 63;
    const int m0 = blockIdx.y * BM;
    const int n0 = blockIdx.x * BN;

    f32x4 acc[2][6] = {};
    const int fr = lane & 15;
    const int kb = lane >> 4;

    for (int k0 = 0; k0 < 96; k0 += BK) {
#pragma unroll
        for (int q = 0; q < 2; ++q) {
            int ci = q * 4 + w;
            int e = ci * 512 + lane * 8;
            int r = e >> 5, c = e & 31;
            GLDS(A + (long)(m0 + r) * ESS + (k0 + c), (char*)As + ci * 1024);
        }
        {
            int ci = w;
            int e = ci * 512 + lane * 8;
            int r = e >> 5, c = e & 31;
            GLDS(Bw + (long)(n0 + r) * ESS + (k0 + c), (char*)Bs + ci * 1024);
            if (w < 2) {
                int ci2 = 4 + w;
                int e2 = ci2 * 512 + lane * 8;
                int r2 = e2 >> 5, c2 = e2 & 31;
                GLDS(Bw + (long)(n0 + r2) * ESS + (k0 + c2), (char*)Bs + ci2 * 1024);
            }
        }
        __syncthreads();

        short8 af[2], bfr[6];
#pragma unroll
        for (int fm = 0; fm < 2; ++fm)
            af[fm] = *(const short8*)&As[(w * 32 + fm * 16 + fr) * 32 + kb * 8];
#pragma unroll
        for (int fn = 0; fn < 6; ++fn)
            bfr[fn] = *(const short8*)&Bs[(fn * 16 + fr) * 32 + kb * 8];
#pragma unroll
        for (int fm = 0; fm < 2; ++fm)
#pragma unroll
            for (int fn = 0; fn < 6; ++fn)
                acc[fm][fn] = __builtin_amdgcn_mfma_f32_16x16x32_bf16(
                    af[fm], bfr[fn], acc[fm][fn], 0, 0, 0);
        __syncthreads();
    }

    const int cr = lane >> 4;
    const int cc = lane & 15;
    const int kind = blockIdx.x;      // 0 = K, 1 = Q, 2 = V
#pragma unroll
    for (int fm = 0; fm < 2; ++fm) {
#pragma unroll
        for (int fn = 0; fn < 6; ++fn) {
#pragma unroll
            for (int j = 0; j < 4; ++j) {
                int gm = m0 + w * 32 + fm * 16 + cr * 4 + j;
                int s = fn * 16 + cc;
                float v = acc[fm][fn][j];
                int h = gm & 7;
                int bt = gm >> 3;
                int t = bt & 511, b = bt >> 9;
                int bh = b * HH + h;
                if (kind == 0)
                    Kh[((long)(bh * TT + t)) * KHMAX + loff + s] = f2b(v);
                else if (kind == 1)
                    Qh[((long)(bh * TT + t)) * KHMAX + loff + s] = f2b(v * scale);
                else
                    Vt[((long)(bh * ESS + s)) * TT + t] = f2b(v);
            }
        }
    }
}

// ---------------------------------------------------------------------------
// Fused attention with Q/K-history accumulation (RealFormer carry).
// XCD-aware 1D grid (1024 blocks). Phase 1 (QK^T over history) is now
// ZERO-LDS / ZERO-BARRIER: A/B fragments are lane-private 16B global loads
// from L2 (per-XCD panel residency via the swizzle); the Kd loop is
// unrolled 3x (trip = 3*(l+1)) so loads pipeline under MFMAs.
// Phases 2/3 unchanged from R9 (best measured).
// ---------------------------------------------------------------------------
__global__ __launch_bounds__(256) void fused_attn(
    const ushort_t* __restrict__ Qh,    // (B*H, T, 576) bf16, cols [0,Kd), pre-scaled
    const ushort_t* __restrict__ Kh,    // (B*H, T, 576) bf16
    const ushort_t* __restrict__ Vt,    // (B*H, 96, T) bf16
    ushort_t* __restrict__ attn,        // (B,T,EMB) bf16
    int Kd)
{
    __shared__ char lds[38912];
    ushort_t* Pt = (ushort_t*)lds;              // 32 KiB: P 32x512 bf16 (swizzled)
    ushort_t* Vs = (ushort_t*)(lds + 32768);    // 6 KiB: V^T chunk 96x32
    float* red   = (float*)(lds + 32768);       // 512 B (union w/ Vs, barrier-ordered)
    float* red2  = (float*)(lds + 33280);       // 512 B

    // XCD swizzle: hw xcd = wg & 7 (round-robin)
    const int wg = blockIdx.x;
    const int xcd = wg & 7;
    const int sub = wg >> 3;          // 0..127, sequential within an XCD
    const int m0 = (sub & 15) * 32;   // m-tile fastest -> same bh consecutive
    const int bh = (sub >> 4) * 8 + xcd;
    const int b = bh >> 3, h = bh & 7;

    const int tid = threadIdx.x;
    const int w = tid >> 6, lane = tid & 63;
    const int fr = lane & 15, kb = lane >> 4;
    const int cr = kb, cc = fr;

    f32x4 acc[2][8] = {};

    // ---- phase 1: S = Q_hist K_hist^T, direct global->reg fragments ----
    const ushort_t* Qbase = Qh + ((long)(bh * TT + m0 + fr)) * KHMAX + kb * 8;
    const ushort_t* Kbase = Kh + ((long)(bh * TT + w * 128 + fr)) * KHMAX + kb * 8;

#pragma unroll 3
    for (int k0 = 0; k0 < Kd; k0 += 32) {
        short8 af0 = *(const short8*)(Qbase + k0);
        short8 af1 = *(const short8*)(Qbase + 16 * KHMAX + k0);
        short8 bf0 = *(const short8*)(Kbase + k0);
        short8 bf1 = *(const short8*)(Kbase + 16 * KHMAX + k0);
        short8 bf2 = *(const short8*)(Kbase + 32 * KHMAX + k0);
        short8 bf3 = *(const short8*)(Kbase + 48 * KHMAX + k0);
        short8 bf4 = *(const short8*)(Kbase + 64 * KHMAX + k0);
        short8 bf5 = *(const short8*)(Kbase + 80 * KHMAX + k0);
        short8 bf6 = *(const short8*)(Kbase + 96 * KHMAX + k0);
        short8 bf7 = *(const short8*)(Kbase + 112 * KHMAX + k0);
        acc[0][0] = __builtin_amdgcn_mfma_f32_16x16x32_bf16(af0, bf0, acc[0][0], 0, 0, 0);
        acc[1][0] = __builtin_amdgcn_mfma_f32_16x16x32_bf16(af1, bf0, acc[1][0], 0, 0, 0);
        acc[0][1] = __builtin_amdgcn_mfma_f32_16x16x32_bf16(af0, bf1, acc[0][1], 0, 0, 0);
        acc[1][1] = __builtin_amdgcn_mfma_f32_16x16x32_bf16(af1, bf1, acc[1][1], 0, 0, 0);
        acc[0][2] = __builtin_amdgcn_mfma_f32_16x16x32_bf16(af0, bf2, acc[0][2], 0, 0, 0);
        acc[1][2] = __builtin_amdgcn_mfma_f32_16x16x32_bf16(af1, bf2, acc[1][2], 0, 0, 0);
        acc[0][3] = __builtin_amdgcn_mfma_f32_16x16x32_bf16(af0, bf3, acc[0][3], 0, 0, 0);
        acc[1][3] = __builtin_amdgcn_mfma_f32_16x16x32_bf16(af1, bf3, acc[1][3], 0, 0, 0);
        acc[0][4] = __builtin_amdgcn_mfma_f32_16x16x32_bf16(af0, bf4, acc[0][4], 0, 0, 0);
        acc[1][4] = __builtin_amdgcn_mfma_f32_16x16x32_bf16(af1, bf4, acc[1][4], 0, 0, 0);
        acc[0][5] = __builtin_amdgcn_mfma_f32_16x16x32_bf16(af0, bf5, acc[0][5], 0, 0, 0);
        acc[1][5] = __builtin_amdgcn_mfma_f32_16x16x32_bf16(af1, bf5, acc[1][5], 0, 0, 0);
        acc[0][6] = __builtin_amdgcn_mfma_f32_16x16x32_bf16(af0, bf6, acc[0][6], 0, 0, 0);
        acc[1][6] = __builtin_amdgcn_mfma_f32_16x16x32_bf16(af1, bf6, acc[1][6], 0, 0, 0);
        acc[0][7] = __builtin_amdgcn_mfma_f32_16x16x32_bf16(af0, bf7, acc[0][7], 0, 0, 0);
        acc[1][7] = __builtin_amdgcn_mfma_f32_16x16x32_bf16(af1, bf7, acc[1][7], 0, 0, 0);
    }

    // ---- phase 2: softmax over key axis ----
#pragma unroll
    for (int fm = 0; fm < 2; ++fm)
#pragma unroll
        for (int j = 0; j < 4; ++j) {
            float mx = -1e30f;
#pragma unroll
            for (int fn = 0; fn < 8; ++fn) mx = fmaxf(mx, acc[fm][fn][j]);
            for (int o = 1; o <= 8; o <<= 1) mx = fmaxf(mx, __shfl_xor(mx, o));
            if (cc == 0) red[w * 32 + fm * 16 + cr * 4 + j] = mx;
        }
    __syncthreads();

    float inv[2][4];
#pragma unroll
    for (int fm = 0; fm < 2; ++fm)
#pragma unroll
        for (int j = 0; j < 4; ++j) {
            int r = fm * 16 + cr * 4 + j;
            float mx = fmaxf(fmaxf(red[r], red[32 + r]), fmaxf(red[64 + r], red[96 + r]));
            float s = 0.f;
#pragma unroll
            for (int fn = 0; fn < 8; ++fn) {
                float e = __expf(acc[fm][fn][j] - mx);
                acc[fm][fn][j] = e;
                s += e;
            }
            for (int o = 1; o <= 8; o <<= 1) s += __shfl_xor(s, o);
            if (cc == 0) red2[w * 32 + r] = s;
        }
    __syncthreads();
#pragma unroll
    for (int fm = 0; fm < 2; ++fm)
#pragma unroll
        for (int j = 0; j < 4; ++j) {
            int r = fm * 16 + cr * 4 + j;
            inv[fm][j] = 1.f / (red2[r] + red2[32 + r] + red2[64 + r] + red2[96 + r]);
        }

    // write P (bf16) into swizzled LDS tile (elem col ^= (row&7)<<3)
#pragma unroll
    for (int fm = 0; fm < 2; ++fm)
#pragma unroll
        for (int fn = 0; fn < 8; ++fn)
#pragma unroll
            for (int j = 0; j < 4; ++j) {
                int row = fm * 16 + cr * 4 + j;
                int col = w * 128 + fn * 16 + cc;
                Pt[row * 512 + (col ^ ((row & 7) << 3))] = f2b(acc[fm][fn][j] * inv[fm][j]);
            }
    __syncthreads();

    // ---- phase 3: attn = P @ V (LDS-staged V^T chunks) ----
    const int wr = w >> 1, wc2 = w & 1;
    f32x4 po[3] = {};
    for (int j0 = 0; j0 < TT; j0 += 32) {
#pragma unroll
        for (int q = 0; q < 2; ++q) {
            int ci = q * 4 + w;
            if (ci < 6) {
                int e = ci * 512 + lane * 8;
                int r = e >> 5, c = e & 31;
                GLDS(Vt + ((long)(bh * ESS + r)) * TT + j0 + c, (char*)Vs + ci * 1024);
            }
        }
        __syncthreads();
        int prow = wr * 16 + fr;
        short8 pa = *(const short8*)&Pt[prow * 512 + ((j0 + kb * 8) ^ ((prow & 7) << 3))];
#pragma unroll
        for (int fn = 0; fn < 3; ++fn) {
            short8 vb = *(const short8*)&Vs[(wc2 * 48 + fn * 16 + fr) * 32 + kb * 8];
            po[fn] = __builtin_amdgcn_mfma_f32_16x16x32_bf16(pa, vb, po[fn], 0, 0, 0);
        }
        __syncthreads();
    }

#pragma unroll
    for (int fn = 0; fn < 3; ++fn)
#pragma unroll
        for (int j = 0; j < 4; ++j) {
            int grow = m0 + wr * 16 + cr * 4 + j;
            int gcol = h * ESS + wc2 * 48 + fn * 16 + cc;
            attn[((long)(b * TT + grow)) * EMBD + gcol] = f2b(po[fn][j]);
        }
}

// ---------------------------------------------------------------------------
__global__ __launch_bounds__(256) void cvt_f2b(
    const float* __restrict__ in, ushort_t* __restrict__ out)
{
    const int i = blockIdx.x * 256 + threadIdx.x;
    float4 v = ((const float4*)in)[i];
    ushort4v o = {f2b(v.x), f2b(v.y), f2b(v.z), f2b(v.w)};
    ((ushort4v*)out)[i] = o;
}

// ---------------------------------------------------------------------------
// Weight conversion. Per-layer contiguous layout (float4/ushort4v units):
//   [wkqv 6912 | wproj 147456 | w1 589824 | w2 589824] = 1334016 per layer
// ---------------------------------------------------------------------------
static __device__ __forceinline__ void cvt_w_one(
    int r, int layer,
    const float* Wkqv, const float* Wproj, const float* w1, const float* w2,
    ushort_t* dst_layer)
{
    const float* src; int base;
    if (r < 6912)        { src = Wkqv  + (long)layer * 27648;   base = 0; }
    else if (r < 154368) { src = Wproj + (long)layer * 589824;  base = 6912; }
    else if (r < 744192) { src = w1    + (long)layer * 2359296; base = 154368; }
    else                 { src = w2    + (long)layer * 2359296; base = 744192; }
    int j = r - base;
    float4 v = ((const float4*)src)[j];
    ushort4v o = {f2b(v.x), f2b(v.y), f2b(v.z), f2b(v.w)};
    ((ushort4v*)dst_layer)[r] = o;
}

__global__ __launch_bounds__(256) void cvt_weights_all(
    const float* __restrict__ Wkqv, const float* __restrict__ Wproj,
    const float* __restrict__ w1, const float* __restrict__ w2,
    ushort_t* __restrict__ dst)      // 6 layers, stride 5336064 ushorts
{
    int i4 = blockIdx.x * 256 + threadIdx.x;    // 0 .. 8004095
    int layer = i4 / 1334016;
    int r = i4 - layer * 1334016;
    cvt_w_one(r, layer, Wkqv, Wproj, w1, w2, dst + (long)layer * 5336064);
}

__global__ __launch_bounds__(256) void cvt_weights_layer(
    const float* __restrict__ Wkqv, const float* __restrict__ Wproj,
    const float* __restrict__ w1, const float* __restrict__ w2,
    ushort_t* __restrict__ dst, int layer)      // one layer into dst
{
    int r = blockIdx.x * 256 + threadIdx.x;     // 0 .. 1334015
    cvt_w_one(r, layer, Wkqv, Wproj, w1, w2, dst);
}

// ---------------------------------------------------------------------------
// x = LayerNorm(x + r0 + r1 (+bias)) * g + b ; also emit bf16 copy.
// ---------------------------------------------------------------------------
__global__ __launch_bounds__(192) void add_ln(
    float* __restrict__ x, const float* __restrict__ r0,
    const float* __restrict__ r1, const float* __restrict__ bias,
    const float* __restrict__ g, const float* __restrict__ bta,
    ushort_t* __restrict__ xb)
{
    const long row = blockIdx.x;
    float4* xr = (float4*)(x + row * EMBD);
    const float4* q0 = (const float4*)(r0 + row * EMBD);
    const float4* q1 = (const float4*)(r1 + row * EMBD);
    __shared__ float sh[4];
    const int tid = threadIdx.x;
    const int lane = tid & 63, w = tid >> 6;

    float4 a = xr[tid], u0 = q0[tid], u1 = q1[tid];
    float v[4] = {a.x + u0.x + u1.x, a.y + u0.y + u1.y,
                  a.z + u0.z + u1.z, a.w + u0.w + u1.w};
    if (bias) {
        float4 b4 = ((const float4*)bias)[tid];
        v[0] += b4.x; v[1] += b4.y; v[2] += b4.z; v[3] += b4.w;
    }
    float s = v[0] + v[1] + v[2] + v[3];
    for (int o = 32; o; o >>= 1) s += __shfl_xor(s, o);
    if (lane == 0) sh[w] = s;
    __syncthreads();
    float mu = (sh[0] + sh[1] + sh[2]) * (1.f / EMBD);

    float var = 0.f;
#pragma unroll
    for (int c = 0; c < 4; ++c) { float d = v[c] - mu; var += d * d; }
    for (int o = 32; o; o >>= 1) var += __shfl_xor(var, o);
    __syncthreads();
    if (lane == 0) sh[w] = var;
    __syncthreads();
    var = (sh[0] + sh[1] + sh[2]) * (1.f / EMBD);
    float rstd = rsqrtf(var + 1e-5f);

    const float4 g4 = ((const float4*)g)[tid];
    const float4 b4 = ((const float4*)bta)[tid];
    float o0 = (v[0] - mu) * rstd * g4.x + b4.x;
    float o1 = (v[1] - mu) * rstd * g4.y + b4.y;
    float o2 = (v[2] - mu) * rstd * g4.z + b4.z;
    float o3 = (v[3] - mu) * rstd * g4.w + b4.w;
    float4 ov = {o0, o1, o2, o3};
    xr[tid] = ov;
    ushort4v ob = {f2b(o0), f2b(o1), f2b(o2), f2b(o3)};
    ((ushort4v*)(xb + row * EMBD))[tid] = ob;
}

// ---------------------------------------------------------------------------
extern "C" void kernel_launch(void* const* d_in, const int* in_sizes, int n_in,
                              void* d_out, int out_size, void* d_ws, size_t ws_size,
                              hipStream_t stream) {
    const float* x_in  = (const float*)d_in[0];
    const float* Wkqv  = (const float*)d_in[1];
    const float* Wproj = (const float*)d_in[2];
    const float* ln1_g = (const float*)d_in[3];
    const float* ln1_b = (const float*)d_in[4];
    const float* ln2_g = (const float*)d_in[5];
    const float* ln2_b = (const float*)d_in[6];
    const float* ff_w1 = (const float*)d_in[7];
    const float* ff_b1 = (const float*)d_in[8];
    const float* ff_w2 = (const float*)d_in[9];
    const float* ff_b2 = (const float*)d_in[10];

    float* x = (float*)d_out;
    char* ws = (char*)d_ws;
    ushort_t* Qh     = (ushort_t*)(ws);                   // 37.7 MB
    ushort_t* Kh     = (ushort_t*)(ws + 37748736);        // 37.7 MB
    ushort_t* Vtb    = (ushort_t*)(ws + 75497472);        // 6.3 MB
    float*    res0   = (float*)(ws + 75497472);           // 12.6 MB (union Vtb)
    float*    res1   = (float*)(ws + 88080384);           // 12.6 MB
    ushort_t* h1b    = (ushort_t*)(ws + 100663296);       // 25.2 MB
    ushort_t* xb     = (ushort_t*)(ws + 125829120);       // 6.3 MB
    ushort_t* attnb  = (ushort_t*)(ws + 132120576);       // 6.3 MB
    ushort_t* Wall   = (ushort_t*)(ws + 138412032);
    const size_t WLAYER_B = 10672128;          // bytes per layer slot
    const int    WLAYER_E = 5336064;           // ushorts per layer slot
    const int big = (ws_size >= 138412032 + 6 * WLAYER_B) ? 1 : 0;

    hipMemcpyAsync(x, x_in, (size_t)BB * TT * EMBD * sizeof(float),
                   hipMemcpyDeviceToDevice, stream);
    cvt_f2b<<<3072, 256, 0, stream>>>(x_in, xb);
    if (big)
        cvt_weights_all<<<31266, 256, 0, stream>>>(Wkqv, Wproj, ff_w1, ff_w2, Wall);

    const float scale = 0.10206207261596577f;  // 1/sqrt(96)

    for (int l = 0; l < NLAYER; ++l) {
        const float* b1 = ff_b1 + (size_t)l * FFD;
        const float* b2 = ff_b2 + (size_t)l * EMBD;

        ushort_t* Wl = Wall + (big ? (long)l * WLAYER_E : 0);
        if (!big)
            cvt_weights_layer<<<5211, 256, 0, stream>>>(Wkqv, Wproj, ff_w1, ff_w2, Wl, l);
        ushort_t* Wkqvb  = Wl;
        ushort_t* Wprojb = Wl + 27648;
        ushort_t* W1b    = Wl + 617472;
        ushort_t* W2b    = Wl + 2976768;

        // kqv GEMM with direct scatter epilogue: K,Q(scaled) -> history, V -> Vt
        kqv_gemm<<<dim3(3, 256, 1), 256, 0, stream>>>(
            xb, Wkqvb, Kh, Qh, Vtb, l * ESS, scale);

        // fused: S = Qh Kh^T (scale pre-folded, Kd=96*(l+1)); attn = softmax @ V
        fused_attn<<<1024, 256, 0, stream>>>(
            Qh, Kh, Vtb, attnb, ESS * (l + 1));

        // res0/res1 = attn @ Wproj^T split-K (Vtb dead)
        gemm_mfma<128, 128, 2, 2, 0, 0, 0, 0><<<dim3(6, 32, 2), 256, 0, stream>>>(
            attnb, EMBD, Wprojb, EMBD, res0, EMBD, EMBD / 2, 1.f, nullptr,
            1, 384, 0, 384, 0, (long)(res1 - res0), 0);

        add_ln<<<BB * TT, 192, 0, stream>>>(x, res0, res1, nullptr,
            ln1_g + (size_t)l * EMBD, ln1_b + (size_t)l * EMBD, xb);

        // h1 = gelu(xb @ W1^T + b1)
        gemm_mfma<128, 128, 2, 2, 1, 1, 1, 0><<<dim3(24, 32, 1), 256, 0, stream>>>(
            xb, EMBD, W1b, EMBD, h1b, FFD, EMBD, 1.f, b1,
            1, 0, 0, 0, 0, 0, 0);

        // res0/res1 = h1 @ W2^T split-K (b2 applied in ln2)
        gemm_mfma<128, 128, 2, 2, 0, 0, 0, 0><<<dim3(6, 32, 2), 256, 0, stream>>>(
            h1b, FFD, W2b, FFD, res0, EMBD, FFD / 2, 1.f, nullptr,
            1, 1536, 0, 1536, 0, (long)(res1 - res0), 0);

        add_ln<<<BB * TT, 192, 0, stream>>>(x, res0, res1, b2,
            ln2_g + (size_t)l * EMBD, ln2_b + (size_t)l * EMBD, xb);
    }
}

// Round 11
// 1174.760 us; speedup vs baseline: 1.0810x; 1.0810x over previous
//
#include <hip/hip_runtime.h>
#include <math.h>

#define BB 8
#define TT 512
#define HH 8
#define ESS 96
#define EMBD 768
#define FFD 3072
#define NLAYER 6
#define KHMAX 576   // 96 * 6, history feature pitch

typedef unsigned short ushort_t;
typedef __attribute__((ext_vector_type(8))) short short8;
typedef __attribute__((ext_vector_type(4))) float f32x4;
typedef __attribute__((ext_vector_type(4))) unsigned short ushort4v;

static __device__ __forceinline__ ushort_t f2b(float f) {
    unsigned u = __builtin_bit_cast(unsigned, f);
    unsigned r = (u + 0x7fffu + ((u >> 16) & 1u)) >> 16;
    return (ushort_t)r;
}

#define GLDS(gp, lp) __builtin_amdgcn_global_load_lds( \
    (const __attribute__((address_space(1))) void*)(gp), \
    (__attribute__((address_space(3))) void*)(lp), 16, 0, 0)

// ---------------------------------------------------------------------------
// bf16 MFMA GEMM: C = alpha * A(M,K) * B(N,K)^T (+beta*C) (+bias) (+gelu)
// ---------------------------------------------------------------------------
template<int BM, int BN, int WM, int WN, int OUTBF, int HASBIAS, int GELU, int BETA>
__global__ __launch_bounds__(256) void gemm_mfma(
    const ushort_t* __restrict__ A, int lda,
    const ushort_t* __restrict__ B, int ldb,
    void* __restrict__ Cv, int ldc,
    int K, float alpha,
    const float* __restrict__ bias,
    int bdiv, long sAb, long sAh, long sBb, long sBh, long sCb, long sCh)
{
    constexpr int BK = 32;
    constexpr int WTM = BM / WM;
    constexpr int WTN = BN / WN;
    constexpr int MF = WTM / 16, NF = WTN / 16;
    constexpr int ACH = (BM * BK * 2) / 1024;
    constexpr int BCH = (BN * BK * 2) / 1024;

    const int z = blockIdx.z;
    const int zb = z / bdiv, zh = z % bdiv;
    A += (long)zb * sAb + (long)zh * sAh;
    B += (long)zb * sBb + (long)zh * sBh;
    const long coff = (long)zb * sCb + (long)zh * sCh;

    __shared__ ushort_t As[BM * BK];
    __shared__ ushort_t Bs[BN * BK];

    const int tid = threadIdx.x;
    const int w = tid >> 6, lane = tid & 63;
    const int wr = w / WN, wc = w % WN;
    const int m0 = blockIdx.y * BM;
    const int n0 = blockIdx.x * BN;

    f32x4 acc[MF][NF] = {};

    const int fr = lane & 15;
    const int kb = lane >> 4;

    for (int k0 = 0; k0 < K; k0 += BK) {
#pragma unroll
        for (int q = 0; q < (ACH + 3) / 4; ++q) {
            int ci = q * 4 + w;
            if (ci < ACH) {
                int e = ci * 512 + lane * 8;
                int r = e >> 5, c = e & 31;
                GLDS(A + (long)(m0 + r) * lda + (k0 + c), (char*)As + ci * 1024);
            }
        }
#pragma unroll
        for (int q = 0; q < (BCH + 3) / 4; ++q) {
            int ci = q * 4 + w;
            if (ci < BCH) {
                int e = ci * 512 + lane * 8;
                int r = e >> 5, c = e & 31;
                GLDS(B + (long)(n0 + r) * ldb + (k0 + c), (char*)Bs + ci * 1024);
            }
        }
        __syncthreads();

        short8 af[MF], bfr[NF];
#pragma unroll
        for (int fm = 0; fm < MF; ++fm)
            af[fm] = *(const short8*)&As[(wr * WTM + fm * 16 + fr) * 32 + kb * 8];
#pragma unroll
        for (int fn = 0; fn < NF; ++fn)
            bfr[fn] = *(const short8*)&Bs[(wc * WTN + fn * 16 + fr) * 32 + kb * 8];
#pragma unroll
        for (int fm = 0; fm < MF; ++fm)
#pragma unroll
            for (int fn = 0; fn < NF; ++fn)
                acc[fm][fn] = __builtin_amdgcn_mfma_f32_16x16x32_bf16(
                    af[fm], bfr[fn], acc[fm][fn], 0, 0, 0);
        __syncthreads();
    }

    const int cr = lane >> 4;
    const int cc = lane & 15;
#pragma unroll
    for (int fm = 0; fm < MF; ++fm) {
#pragma unroll
        for (int fn = 0; fn < NF; ++fn) {
#pragma unroll
            for (int j = 0; j < 4; ++j) {
                int gm = m0 + wr * WTM + fm * 16 + cr * 4 + j;
                int gn = n0 + wc * WTN + fn * 16 + cc;
                float v = alpha * acc[fm][fn][j];
                if (HASBIAS) v += bias[gn];
                if (GELU) v = 0.5f * v * (1.f + erff(v * 0.70710678118654752f));
                long idx = coff + (long)gm * ldc + gn;
                if (BETA) v += ((const float*)Cv)[idx];
                if (OUTBF) ((ushort_t*)Cv)[idx] = f2b(v);
                else       ((float*)Cv)[idx] = v;
            }
        }
    }
}

// ---------------------------------------------------------------------------
// kqv GEMM with scatter epilogue: A = xb (B*T*H, 96), B = Wkqv (288, 96).
// Writes K -> Kh[..,loff+n], Q*scale -> Qh[..,loff+n], V -> Vt[(bh,s),t].
// BM=128, BN=96 (block x: 0=K,1=Q,2=V uniformly), grid (3,256).
// ---------------------------------------------------------------------------
__global__ __launch_bounds__(256) void kqv_gemm(
    const ushort_t* __restrict__ A,       // xb, lda 96
    const ushort_t* __restrict__ Bw,      // Wkqvb, ldb 96
    ushort_t* __restrict__ Kh, ushort_t* __restrict__ Qh,
    ushort_t* __restrict__ Vt, int loff, float scale)
{
    constexpr int BM = 128, BN = 96, BK = 32;
    __shared__ ushort_t As[BM * BK];
    __shared__ ushort_t Bs[BN * BK];

    const int tid = threadIdx.x;
    const int w = tid >> 6, lane = tid & 63;
    const int m0 = blockIdx.y * BM;
    const int n0 = blockIdx.x * BN;

    f32x4 acc[2][6] = {};
    const int fr = lane & 15;
    const int kb = lane >> 4;

    for (int k0 = 0; k0 < 96; k0 += BK) {
#pragma unroll
        for (int q = 0; q < 2; ++q) {
            int ci = q * 4 + w;
            int e = ci * 512 + lane * 8;
            int r = e >> 5, c = e & 31;
            GLDS(A + (long)(m0 + r) * ESS + (k0 + c), (char*)As + ci * 1024);
        }
        {
            int ci = w;
            int e = ci * 512 + lane * 8;
            int r = e >> 5, c = e & 31;
            GLDS(Bw + (long)(n0 + r) * ESS + (k0 + c), (char*)Bs + ci * 1024);
            if (w < 2) {
                int ci2 = 4 + w;
                int e2 = ci2 * 512 + lane * 8;
                int r2 = e2 >> 5, c2 = e2 & 31;
                GLDS(Bw + (long)(n0 + r2) * ESS + (k0 + c2), (char*)Bs + ci2 * 1024);
            }
        }
        __syncthreads();

        short8 af[2], bfr[6];
#pragma unroll
        for (int fm = 0; fm < 2; ++fm)
            af[fm] = *(const short8*)&As[(w * 32 + fm * 16 + fr) * 32 + kb * 8];
#pragma unroll
        for (int fn = 0; fn < 6; ++fn)
            bfr[fn] = *(const short8*)&Bs[(fn * 16 + fr) * 32 + kb * 8];
#pragma unroll
        for (int fm = 0; fm < 2; ++fm)
#pragma unroll
            for (int fn = 0; fn < 6; ++fn)
                acc[fm][fn] = __builtin_amdgcn_mfma_f32_16x16x32_bf16(
                    af[fm], bfr[fn], acc[fm][fn], 0, 0, 0);
        __syncthreads();
    }

    const int cr = lane >> 4;
    const int cc = lane & 15;
    const int kind = blockIdx.x;      // 0 = K, 1 = Q, 2 = V
#pragma unroll
    for (int fm = 0; fm < 2; ++fm) {
#pragma unroll
        for (int fn = 0; fn < 6; ++fn) {
#pragma unroll
            for (int j = 0; j < 4; ++j) {
                int gm = m0 + w * 32 + fm * 16 + cr * 4 + j;
                int s = fn * 16 + cc;
                float v = acc[fm][fn][j];
                int h = gm & 7;
                int bt = gm >> 3;
                int t = bt & 511, b = bt >> 9;
                int bh = b * HH + h;
                if (kind == 0)
                    Kh[((long)(bh * TT + t)) * KHMAX + loff + s] = f2b(v);
                else if (kind == 1)
                    Qh[((long)(bh * TT + t)) * KHMAX + loff + s] = f2b(v * scale);
                else
                    Vt[((long)(bh * ESS + s)) * TT + t] = f2b(v);
            }
        }
    }
}

// ---------------------------------------------------------------------------
// Fused attention with Q/K-history accumulation (RealFormer carry).
// XCD-aware 1D grid (1024 blocks). Phase 1: each wave stages ITS OWN 128
// K-rows via coalesced global_load_lds (no cross-wave sharing exists), and
// synchronizes with wave-local s_waitcnt only — ZERO block barriers in the
// Kd loop. Q fragments are 2 lane-private gather loads. Phases 2/3 = R9.
// ---------------------------------------------------------------------------
__global__ __launch_bounds__(256) void fused_attn(
    const ushort_t* __restrict__ Qh,    // (B*H, T, 576) bf16, cols [0,Kd), pre-scaled
    const ushort_t* __restrict__ Kh,    // (B*H, T, 576) bf16
    const ushort_t* __restrict__ Vt,    // (B*H, 96, T) bf16
    ushort_t* __restrict__ attn,        // (B,T,EMB) bf16
    int Kd)
{
    __shared__ char lds[38912];
    ushort_t* Bs = (ushort_t*)lds;              // 32 KiB: K tile 512x32 (phase 1)
    ushort_t* Pt = (ushort_t*)lds;              // union: P 32x512 bf16 (swizzled)
    ushort_t* Vs = (ushort_t*)(lds + 32768);    // 6 KiB: V^T chunk 96x32
    float* red   = (float*)(lds + 32768);       // 512 B (union w/ Vs, barrier-ordered)
    float* red2  = (float*)(lds + 33280);       // 512 B

    // XCD swizzle: hw xcd = wg & 7 (round-robin)
    const int wg = blockIdx.x;
    const int xcd = wg & 7;
    const int sub = wg >> 3;          // 0..127, sequential within an XCD
    const int m0 = (sub & 15) * 32;   // m-tile fastest -> same bh consecutive
    const int bh = (sub >> 4) * 8 + xcd;
    const int b = bh >> 3, h = bh & 7;

    const int tid = threadIdx.x;
    const int w = tid >> 6, lane = tid & 63;
    const int fr = lane & 15, kb = lane >> 4;
    const int cr = kb, cc = fr;

    f32x4 acc[2][8] = {};

    // ---- phase 1: S = Q_hist K_hist^T, per-wave staging, no block barriers ----
    const ushort_t* Qbase = Qh + ((long)(bh * TT + m0 + fr)) * KHMAX + kb * 8;
    // precompute this wave's 8 chunk source rows / dests (rows 128w..128w+127)
    const int ci0 = w * 8;

#pragma unroll 3
    for (int k0 = 0; k0 < Kd; k0 += 32) {
        // WAR guard: last step's ds_reads must have completed before restage
        asm volatile("s_waitcnt lgkmcnt(0)" ::: "memory");
#pragma unroll
        for (int q = 0; q < 8; ++q) {
            int ci = ci0 + q;
            int e = ci * 512 + lane * 8;
            int r = e >> 5, c = e & 31;
            GLDS(Kh + ((long)(bh * TT + r)) * KHMAX + k0 + c, (char*)Bs + ci * 1024);
        }
        short8 af0 = *(const short8*)(Qbase + k0);
        short8 af1 = *(const short8*)(Qbase + 16 * KHMAX + k0);
        asm volatile("s_waitcnt vmcnt(0)" ::: "memory");
        __builtin_amdgcn_sched_barrier(0);

#pragma unroll
        for (int fn = 0; fn < 8; ++fn) {
            short8 bf = *(const short8*)&Bs[(w * 128 + fn * 16 + fr) * 32 + kb * 8];
            acc[0][fn] = __builtin_amdgcn_mfma_f32_16x16x32_bf16(af0, bf, acc[0][fn], 0, 0, 0);
            acc[1][fn] = __builtin_amdgcn_mfma_f32_16x16x32_bf16(af1, bf, acc[1][fn], 0, 0, 0);
        }
    }

    // ---- phase 2: softmax over key axis (barriers here re-sync the block) ----
#pragma unroll
    for (int fm = 0; fm < 2; ++fm)
#pragma unroll
        for (int j = 0; j < 4; ++j) {
            float mx = -1e30f;
#pragma unroll
            for (int fn = 0; fn < 8; ++fn) mx = fmaxf(mx, acc[fm][fn][j]);
            for (int o = 1; o <= 8; o <<= 1) mx = fmaxf(mx, __shfl_xor(mx, o));
            if (cc == 0) red[w * 32 + fm * 16 + cr * 4 + j] = mx;
        }
    __syncthreads();

    float inv[2][4];
#pragma unroll
    for (int fm = 0; fm < 2; ++fm)
#pragma unroll
        for (int j = 0; j < 4; ++j) {
            int r = fm * 16 + cr * 4 + j;
            float mx = fmaxf(fmaxf(red[r], red[32 + r]), fmaxf(red[64 + r], red[96 + r]));
            float s = 0.f;
#pragma unroll
            for (int fn = 0; fn < 8; ++fn) {
                float e = __expf(acc[fm][fn][j] - mx);
                acc[fm][fn][j] = e;
                s += e;
            }
            for (int o = 1; o <= 8; o <<= 1) s += __shfl_xor(s, o);
            if (cc == 0) red2[w * 32 + r] = s;
        }
    __syncthreads();
#pragma unroll
    for (int fm = 0; fm < 2; ++fm)
#pragma unroll
        for (int j = 0; j < 4; ++j) {
            int r = fm * 16 + cr * 4 + j;
            inv[fm][j] = 1.f / (red2[r] + red2[32 + r] + red2[64 + r] + red2[96 + r]);
        }

    // write P (bf16) into swizzled LDS tile (elem col ^= (row&7)<<3)
#pragma unroll
    for (int fm = 0; fm < 2; ++fm)
#pragma unroll
        for (int fn = 0; fn < 8; ++fn)
#pragma unroll
            for (int j = 0; j < 4; ++j) {
                int row = fm * 16 + cr * 4 + j;
                int col = w * 128 + fn * 16 + cc;
                Pt[row * 512 + (col ^ ((row & 7) << 3))] = f2b(acc[fm][fn][j] * inv[fm][j]);
            }
    __syncthreads();

    // ---- phase 3: attn = P @ V (LDS-staged V^T chunks) ----
    const int wr = w >> 1, wc2 = w & 1;
    f32x4 po[3] = {};
    for (int j0 = 0; j0 < TT; j0 += 32) {
#pragma unroll
        for (int q = 0; q < 2; ++q) {
            int ci = q * 4 + w;
            if (ci < 6) {
                int e = ci * 512 + lane * 8;
                int r = e >> 5, c = e & 31;
                GLDS(Vt + ((long)(bh * ESS + r)) * TT + j0 + c, (char*)Vs + ci * 1024);
            }
        }
        __syncthreads();
        int prow = wr * 16 + fr;
        short8 pa = *(const short8*)&Pt[prow * 512 + ((j0 + kb * 8) ^ ((prow & 7) << 3))];
#pragma unroll
        for (int fn = 0; fn < 3; ++fn) {
            short8 vb = *(const short8*)&Vs[(wc2 * 48 + fn * 16 + fr) * 32 + kb * 8];
            po[fn] = __builtin_amdgcn_mfma_f32_16x16x32_bf16(pa, vb, po[fn], 0, 0, 0);
        }
        __syncthreads();
    }

#pragma unroll
    for (int fn = 0; fn < 3; ++fn)
#pragma unroll
        for (int j = 0; j < 4; ++j) {
            int grow = m0 + wr * 16 + cr * 4 + j;
            int gcol = h * ESS + wc2 * 48 + fn * 16 + cc;
            attn[((long)(b * TT + grow)) * EMBD + gcol] = f2b(po[fn][j]);
        }
}

// ---------------------------------------------------------------------------
__global__ __launch_bounds__(256) void cvt_f2b(
    const float* __restrict__ in, ushort_t* __restrict__ out)
{
    const int i = blockIdx.x * 256 + threadIdx.x;
    float4 v = ((const float4*)in)[i];
    ushort4v o = {f2b(v.x), f2b(v.y), f2b(v.z), f2b(v.w)};
    ((ushort4v*)out)[i] = o;
}

// ---------------------------------------------------------------------------
// Weight conversion. Per-layer contiguous layout (float4/ushort4v units):
//   [wkqv 6912 | wproj 147456 | w1 589824 | w2 589824] = 1334016 per layer
// ---------------------------------------------------------------------------
static __device__ __forceinline__ void cvt_w_one(
    int r, int layer,
    const float* Wkqv, const float* Wproj, const float* w1, const float* w2,
    ushort_t* dst_layer)
{
    const float* src; int base;
    if (r < 6912)        { src = Wkqv  + (long)layer * 27648;   base = 0; }
    else if (r < 154368) { src = Wproj + (long)layer * 589824;  base = 6912; }
    else if (r < 744192) { src = w1    + (long)layer * 2359296; base = 154368; }
    else                 { src = w2    + (long)layer * 2359296; base = 744192; }
    int j = r - base;
    float4 v = ((const float4*)src)[j];
    ushort4v o = {f2b(v.x), f2b(v.y), f2b(v.z), f2b(v.w)};
    ((ushort4v*)dst_layer)[r] = o;
}

__global__ __launch_bounds__(256) void cvt_weights_all(
    const float* __restrict__ Wkqv, const float* __restrict__ Wproj,
    const float* __restrict__ w1, const float* __restrict__ w2,
    ushort_t* __restrict__ dst)      // 6 layers, stride 5336064 ushorts
{
    int i4 = blockIdx.x * 256 + threadIdx.x;    // 0 .. 8004095
    int layer = i4 / 1334016;
    int r = i4 - layer * 1334016;
    cvt_w_one(r, layer, Wkqv, Wproj, w1, w2, dst + (long)layer * 5336064);
}

__global__ __launch_bounds__(256) void cvt_weights_layer(
    const float* __restrict__ Wkqv, const float* __restrict__ Wproj,
    const float* __restrict__ w1, const float* __restrict__ w2,
    ushort_t* __restrict__ dst, int layer)      // one layer into dst
{
    int r = blockIdx.x * 256 + threadIdx.x;     // 0 .. 1334015
    cvt_w_one(r, layer, Wkqv, Wproj, w1, w2, dst);
}

// ---------------------------------------------------------------------------
// x = LayerNorm(x + r0 + r1 (+bias)) * g + b ; also emit bf16 copy.
// ---------------------------------------------------------------------------
__global__ __launch_bounds__(192) void add_ln(
    float* __restrict__ x, const float* __restrict__ r0,
    const float* __restrict__ r1, const float* __restrict__ bias,
    const float* __restrict__ g, const float* __restrict__ bta,
    ushort_t* __restrict__ xb)
{
    const long row = blockIdx.x;
    float4* xr = (float4*)(x + row * EMBD);
    const float4* q0 = (const float4*)(r0 + row * EMBD);
    const float4* q1 = (const float4*)(r1 + row * EMBD);
    __shared__ float sh[4];
    const int tid = threadIdx.x;
    const int lane = tid & 63, w = tid >> 6;

    float4 a = xr[tid], u0 = q0[tid], u1 = q1[tid];
    float v[4] = {a.x + u0.x + u1.x, a.y + u0.y + u1.y,
                  a.z + u0.z + u1.z, a.w + u0.w + u1.w};
    if (bias) {
        float4 b4 = ((const float4*)bias)[tid];
        v[0] += b4.x; v[1] += b4.y; v[2] += b4.z; v[3] += b4.w;
    }
    float s = v[0] + v[1] + v[2] + v[3];
    for (int o = 32; o; o >>= 1) s += __shfl_xor(s, o);
    if (lane == 0) sh[w] = s;
    __syncthreads();
    float mu = (sh[0] + sh[1] + sh[2]) * (1.f / EMBD);

    float var = 0.f;
#pragma unroll
    for (int c = 0; c < 4; ++c) { float d = v[c] - mu; var += d * d; }
    for (int o = 32; o; o >>= 1) var += __shfl_xor(var, o);
    __syncthreads();
    if (lane == 0) sh[w] = var;
    __syncthreads();
    var = (sh[0] + sh[1] + sh[2]) * (1.f / EMBD);
    float rstd = rsqrtf(var + 1e-5f);

    const float4 g4 = ((const float4*)g)[tid];
    const float4 b4 = ((const float4*)bta)[tid];
    float o0 = (v[0] - mu) * rstd * g4.x + b4.x;
    float o1 = (v[1] - mu) * rstd * g4.y + b4.y;
    float o2 = (v[2] - mu) * rstd * g4.z + b4.z;
    float o3 = (v[3] - mu) * rstd * g4.w + b4.w;
    float4 ov = {o0, o1, o2, o3};
    xr[tid] = ov;
    ushort4v ob = {f2b(o0), f2b(o1), f2b(o2), f2b(o3)};
    ((ushort4v*)(xb + row * EMBD))[tid] = ob;
}

// ---------------------------------------------------------------------------
extern "C" void kernel_launch(void* const* d_in, const int* in_sizes, int n_in,
                              void* d_out, int out_size, void* d_ws, size_t ws_size,
                              hipStream_t stream) {
    const float* x_in  = (const float*)d_in[0];
    const float* Wkqv  = (const float*)d_in[1];
    const float* Wproj = (const float*)d_in[2];
    const float* ln1_g = (const float*)d_in[3];
    const float* ln1_b = (const float*)d_in[4];
    const float* ln2_g = (const float*)d_in[5];
    const float* ln2_b = (const float*)d_in[6];
    const float* ff_w1 = (const float*)d_in[7];
    const float* ff_b1 = (const float*)d_in[8];
    const float* ff_w2 = (const float*)d_in[9];
    const float* ff_b2 = (const float*)d_in[10];

    float* x = (float*)d_out;
    char* ws = (char*)d_ws;
    ushort_t* Qh     = (ushort_t*)(ws);                   // 37.7 MB
    ushort_t* Kh     = (ushort_t*)(ws + 37748736);        // 37.7 MB
    ushort_t* Vtb    = (ushort_t*)(ws + 75497472);        // 6.3 MB
    float*    res0   = (float*)(ws + 75497472);           // 12.6 MB (union Vtb)
    float*    res1   = (float*)(ws + 88080384);           // 12.6 MB
    ushort_t* h1b    = (ushort_t*)(ws + 100663296);       // 25.2 MB
    ushort_t* xb     = (ushort_t*)(ws + 125829120);       // 6.3 MB
    ushort_t* attnb  = (ushort_t*)(ws + 132120576);       // 6.3 MB
    ushort_t* Wall   = (ushort_t*)(ws + 138412032);
    const size_t WLAYER_B = 10672128;          // bytes per layer slot
    const int    WLAYER_E = 5336064;           // ushorts per layer slot
    const int big = (ws_size >= 138412032 + 6 * WLAYER_B) ? 1 : 0;

    hipMemcpyAsync(x, x_in, (size_t)BB * TT * EMBD * sizeof(float),
                   hipMemcpyDeviceToDevice, stream);
    cvt_f2b<<<3072, 256, 0, stream>>>(x_in, xb);
    if (big)
        cvt_weights_all<<<31266, 256, 0, stream>>>(Wkqv, Wproj, ff_w1, ff_w2, Wall);

    const float scale = 0.10206207261596577f;  // 1/sqrt(96)

    for (int l = 0; l < NLAYER; ++l) {
        const float* b1 = ff_b1 + (size_t)l * FFD;
        const float* b2 = ff_b2 + (size_t)l * EMBD;

        ushort_t* Wl = Wall + (big ? (long)l * WLAYER_E : 0);
        if (!big)
            cvt_weights_layer<<<5211, 256, 0, stream>>>(Wkqv, Wproj, ff_w1, ff_w2, Wl, l);
        ushort_t* Wkqvb  = Wl;
        ushort_t* Wprojb = Wl + 27648;
        ushort_t* W1b    = Wl + 617472;
        ushort_t* W2b    = Wl + 2976768;

        // kqv GEMM with direct scatter epilogue: K,Q(scaled) -> history, V -> Vt
        kqv_gemm<<<dim3(3, 256, 1), 256, 0, stream>>>(
            xb, Wkqvb, Kh, Qh, Vtb, l * ESS, scale);

        // fused: S = Qh Kh^T (scale pre-folded, Kd=96*(l+1)); attn = softmax @ V
        fused_attn<<<1024, 256, 0, stream>>>(
            Qh, Kh, Vtb, attnb, ESS * (l + 1));

        // res0/res1 = attn @ Wproj^T split-K (Vtb dead)
        gemm_mfma<128, 128, 2, 2, 0, 0, 0, 0><<<dim3(6, 32, 2), 256, 0, stream>>>(
            attnb, EMBD, Wprojb, EMBD, res0, EMBD, EMBD / 2, 1.f, nullptr,
            1, 384, 0, 384, 0, (long)(res1 - res0), 0);

        add_ln<<<BB * TT, 192, 0, stream>>>(x, res0, res1, nullptr,
            ln1_g + (size_t)l * EMBD, ln1_b + (size_t)l * EMBD, xb);

        // h1 = gelu(xb @ W1^T + b1)
        gemm_mfma<128, 128, 2, 2, 1, 1, 1, 0><<<dim3(24, 32, 1), 256, 0, stream>>>(
            xb, EMBD, W1b, EMBD, h1b, FFD, EMBD, 1.f, b1,
            1, 0, 0, 0, 0, 0, 0);

        // res0/res1 = h1 @ W2^T split-K (b2 applied in ln2)
        gemm_mfma<128, 128, 2, 2, 0, 0, 0, 0><<<dim3(6, 32, 2), 256, 0, stream>>>(
            h1b, FFD, W2b, FFD, res0, EMBD, FFD / 2, 1.f, nullptr,
            1, 1536, 0, 1536, 0, (long)(res1 - res0), 0);

        add_ln<<<BB * TT, 192, 0, stream>>>(x, res0, res1, b2,
            ln2_g + (size_t)l * EMBD, ln2_b + (size_t)l * EMBD, xb);
    }
}

// Round 12
// 1142.843 us; speedup vs baseline: 1.1111x; 1.0279x over previous
//
#include <hip/hip_runtime.h>
#include <math.h>

#define BB 8
#define TT 512
#define HH 8
#define ESS 96
#define EMBD 768
#define FFD 3072
#define NLAYER 6
#define KHMAX 576   // 96 * 6, history feature pitch

typedef unsigned short ushort_t;
typedef __attribute__((ext_vector_type(8))) short short8;
typedef __attribute__((ext_vector_type(4))) float f32x4;
typedef __attribute__((ext_vector_type(4))) unsigned short ushort4v;

static __device__ __forceinline__ ushort_t f2b(float f) {
    unsigned u = __builtin_bit_cast(unsigned, f);
    unsigned r = (u + 0x7fffu + ((u >> 16) & 1u)) >> 16;
    return (ushort_t)r;
}
static __device__ __forceinline__ float b2f(ushort_t u) {
    return __builtin_bit_cast(float, ((unsigned)u) << 16);
}

#define GLDS(gp, lp) __builtin_amdgcn_global_load_lds( \
    (const __attribute__((address_space(1))) void*)(gp), \
    (__attribute__((address_space(3))) void*)(lp), 16, 0, 0)

// ---------------------------------------------------------------------------
// bf16 MFMA GEMM: C = alpha * A(M,K) * B(N,K)^T (+beta*C) (+bias) (+gelu)
// GELU uses tanh-form (x*sigmoid(1.5958(x+0.044715x^3))), ~3e-4 abs err.
// ---------------------------------------------------------------------------
template<int BM, int BN, int WM, int WN, int OUTBF, int HASBIAS, int GELU, int BETA>
__global__ __launch_bounds__(256) void gemm_mfma(
    const ushort_t* __restrict__ A, int lda,
    const ushort_t* __restrict__ B, int ldb,
    void* __restrict__ Cv, int ldc,
    int K, float alpha,
    const float* __restrict__ bias,
    int bdiv, long sAb, long sAh, long sBb, long sBh, long sCb, long sCh)
{
    constexpr int BK = 32;
    constexpr int WTM = BM / WM;
    constexpr int WTN = BN / WN;
    constexpr int MF = WTM / 16, NF = WTN / 16;
    constexpr int ACH = (BM * BK * 2) / 1024;
    constexpr int BCH = (BN * BK * 2) / 1024;

    const int z = blockIdx.z;
    const int zb = z / bdiv, zh = z % bdiv;
    A += (long)zb * sAb + (long)zh * sAh;
    B += (long)zb * sBb + (long)zh * sBh;
    const long coff = (long)zb * sCb + (long)zh * sCh;

    __shared__ ushort_t As[BM * BK];
    __shared__ ushort_t Bs[BN * BK];

    const int tid = threadIdx.x;
    const int w = tid >> 6, lane = tid & 63;
    const int wr = w / WN, wc = w % WN;
    const int m0 = blockIdx.y * BM;
    const int n0 = blockIdx.x * BN;

    f32x4 acc[MF][NF] = {};

    const int fr = lane & 15;
    const int kb = lane >> 4;

    for (int k0 = 0; k0 < K; k0 += BK) {
#pragma unroll
        for (int q = 0; q < (ACH + 3) / 4; ++q) {
            int ci = q * 4 + w;
            if (ci < ACH) {
                int e = ci * 512 + lane * 8;
                int r = e >> 5, c = e & 31;
                GLDS(A + (long)(m0 + r) * lda + (k0 + c), (char*)As + ci * 1024);
            }
        }
#pragma unroll
        for (int q = 0; q < (BCH + 3) / 4; ++q) {
            int ci = q * 4 + w;
            if (ci < BCH) {
                int e = ci * 512 + lane * 8;
                int r = e >> 5, c = e & 31;
                GLDS(B + (long)(n0 + r) * ldb + (k0 + c), (char*)Bs + ci * 1024);
            }
        }
        __syncthreads();

        short8 af[MF], bfr[NF];
#pragma unroll
        for (int fm = 0; fm < MF; ++fm)
            af[fm] = *(const short8*)&As[(wr * WTM + fm * 16 + fr) * 32 + kb * 8];
#pragma unroll
        for (int fn = 0; fn < NF; ++fn)
            bfr[fn] = *(const short8*)&Bs[(wc * WTN + fn * 16 + fr) * 32 + kb * 8];
#pragma unroll
        for (int fm = 0; fm < MF; ++fm)
#pragma unroll
            for (int fn = 0; fn < NF; ++fn)
                acc[fm][fn] = __builtin_amdgcn_mfma_f32_16x16x32_bf16(
                    af[fm], bfr[fn], acc[fm][fn], 0, 0, 0);
        __syncthreads();
    }

    const int cr = lane >> 4;
    const int cc = lane & 15;
#pragma unroll
    for (int fm = 0; fm < MF; ++fm) {
#pragma unroll
        for (int fn = 0; fn < NF; ++fn) {
#pragma unroll
            for (int j = 0; j < 4; ++j) {
                int gm = m0 + wr * WTM + fm * 16 + cr * 4 + j;
                int gn = n0 + wc * WTN + fn * 16 + cc;
                float v = alpha * acc[fm][fn][j];
                if (HASBIAS) v += bias[gn];
                if (GELU) {
                    float zz = 1.5957691216f * fmaf(0.044715f * v * v, v, v);
                    v = v / (1.f + __expf(-zz));
                }
                long idx = coff + (long)gm * ldc + gn;
                if (BETA) v += ((const float*)Cv)[idx];
                if (OUTBF) ((ushort_t*)Cv)[idx] = f2b(v);
                else       ((float*)Cv)[idx] = v;
            }
        }
    }
}

// ---------------------------------------------------------------------------
// kqv GEMM with scatter epilogue: A = xb (B*T*H, 96), B = Wkqv (288, 96).
// Writes K -> Kh[..,loff+n], Q*scale -> Qh[..,loff+n], V -> Vt[(bh,s),t].
// ---------------------------------------------------------------------------
__global__ __launch_bounds__(256) void kqv_gemm(
    const ushort_t* __restrict__ A,       // xb, lda 96
    const ushort_t* __restrict__ Bw,      // Wkqvb, ldb 96
    ushort_t* __restrict__ Kh, ushort_t* __restrict__ Qh,
    ushort_t* __restrict__ Vt, int loff, float scale)
{
    constexpr int BM = 128, BN = 96, BK = 32;
    __shared__ ushort_t As[BM * BK];
    __shared__ ushort_t Bs[BN * BK];

    const int tid = threadIdx.x;
    const int w = tid >> 6, lane = tid & 63;
    const int m0 = blockIdx.y * BM;
    const int n0 = blockIdx.x * BN;

    f32x4 acc[2][6] = {};
    const int fr = lane & 15;
    const int kb = lane >> 4;

    for (int k0 = 0; k0 < 96; k0 += BK) {
#pragma unroll
        for (int q = 0; q < 2; ++q) {
            int ci = q * 4 + w;
            int e = ci * 512 + lane * 8;
            int r = e >> 5, c = e & 31;
            GLDS(A + (long)(m0 + r) * ESS + (k0 + c), (char*)As + ci * 1024);
        }
        {
            int ci = w;
            int e = ci * 512 + lane * 8;
            int r = e >> 5, c = e & 31;
            GLDS(Bw + (long)(n0 + r) * ESS + (k0 + c), (char*)Bs + ci * 1024);
            if (w < 2) {
                int ci2 = 4 + w;
                int e2 = ci2 * 512 + lane * 8;
                int r2 = e2 >> 5, c2 = e2 & 31;
                GLDS(Bw + (long)(n0 + r2) * ESS + (k0 + c2), (char*)Bs + ci2 * 1024);
            }
        }
        __syncthreads();

        short8 af[2], bfr[6];
#pragma unroll
        for (int fm = 0; fm < 2; ++fm)
            af[fm] = *(const short8*)&As[(w * 32 + fm * 16 + fr) * 32 + kb * 8];
#pragma unroll
        for (int fn = 0; fn < 6; ++fn)
            bfr[fn] = *(const short8*)&Bs[(fn * 16 + fr) * 32 + kb * 8];
#pragma unroll
        for (int fm = 0; fm < 2; ++fm)
#pragma unroll
            for (int fn = 0; fn < 6; ++fn)
                acc[fm][fn] = __builtin_amdgcn_mfma_f32_16x16x32_bf16(
                    af[fm], bfr[fn], acc[fm][fn], 0, 0, 0);
        __syncthreads();
    }

    const int cr = lane >> 4;
    const int cc = lane & 15;
    const int kind = blockIdx.x;      // 0 = K, 1 = Q, 2 = V
#pragma unroll
    for (int fm = 0; fm < 2; ++fm) {
#pragma unroll
        for (int fn = 0; fn < 6; ++fn) {
#pragma unroll
            for (int j = 0; j < 4; ++j) {
                int gm = m0 + w * 32 + fm * 16 + cr * 4 + j;
                int s = fn * 16 + cc;
                float v = acc[fm][fn][j];
                int h = gm & 7;
                int bt = gm >> 3;
                int t = bt & 511, b = bt >> 9;
                int bh = b * HH + h;
                if (kind == 0)
                    Kh[((long)(bh * TT + t)) * KHMAX + loff + s] = f2b(v);
                else if (kind == 1)
                    Qh[((long)(bh * TT + t)) * KHMAX + loff + s] = f2b(v * scale);
                else
                    Vt[((long)(bh * ESS + s)) * TT + t] = f2b(v);
            }
        }
    }
}

// ---------------------------------------------------------------------------
// Fused attention with Q/K-history accumulation (RealFormer carry).
// R9 structure (best measured): phase 1 = block-barrier GLDS staging.
// Scale pre-folded into Qh.
// ---------------------------------------------------------------------------
__global__ __launch_bounds__(256) void fused_attn(
    const ushort_t* __restrict__ Qh,    // (B*H, T, 576) bf16, cols [0,Kd)
    const ushort_t* __restrict__ Kh,    // (B*H, T, 576) bf16
    const ushort_t* __restrict__ Vt,    // (B*H, 96, T) bf16
    ushort_t* __restrict__ attn,        // (B,T,EMB) bf16
    int Kd)
{
    __shared__ char lds[40960];
    ushort_t* As = (ushort_t*)lds;              // 2 KiB: Q tile 32x32
    ushort_t* Bs = (ushort_t*)(lds + 2048);     // 32 KiB: K tile 512x32
    ushort_t* Pt = (ushort_t*)(lds + 2048);     // union: P 32x512 bf16 (swizzled)
    ushort_t* Vs = (ushort_t*)(lds + 34816);    // 6 KiB: V^T chunk 96x32
    float* red   = (float*)(lds + 34816);       // 512 B (union w/ Vs)
    float* red2  = (float*)(lds + 35328);       // 512 B

    // XCD swizzle: hw xcd = wg & 7 (round-robin)
    const int wg = blockIdx.x;
    const int xcd = wg & 7;
    const int sub = wg >> 3;          // 0..127, sequential within an XCD
    const int m0 = (sub & 15) * 32;   // m-tile fastest -> same bh consecutive
    const int bh = (sub >> 4) * 8 + xcd;
    const int b = bh >> 3, h = bh & 7;

    const int tid = threadIdx.x;
    const int w = tid >> 6, lane = tid & 63;
    const int fr = lane & 15, kb = lane >> 4;
    const int cr = kb, cc = fr;

    f32x4 acc[2][8] = {};

    // ---- phase 1: S = Q_hist K_hist^T over Kd feature cols ----
    for (int k0 = 0; k0 < Kd; k0 += 32) {
        if (w < 2) {
            int e = w * 512 + lane * 8;
            int r = e >> 5, c = e & 31;
            GLDS(Qh + ((long)(bh * TT + m0 + r)) * KHMAX + k0 + c,
                 (char*)As + w * 1024);
        }
#pragma unroll
        for (int q = 0; q < 8; ++q) {
            int ci = q * 4 + w;
            int e = ci * 512 + lane * 8;
            int r = e >> 5, c = e & 31;
            GLDS(Kh + ((long)(bh * TT + r)) * KHMAX + k0 + c,
                 (char*)Bs + ci * 1024);
        }
        __syncthreads();
        short8 af0 = *(const short8*)&As[fr * 32 + kb * 8];
        short8 af1 = *(const short8*)&As[(16 + fr) * 32 + kb * 8];
#pragma unroll
        for (int fn = 0; fn < 8; ++fn) {
            short8 bf = *(const short8*)&Bs[(w * 128 + fn * 16 + fr) * 32 + kb * 8];
            acc[0][fn] = __builtin_amdgcn_mfma_f32_16x16x32_bf16(af0, bf, acc[0][fn], 0, 0, 0);
            acc[1][fn] = __builtin_amdgcn_mfma_f32_16x16x32_bf16(af1, bf, acc[1][fn], 0, 0, 0);
        }
        __syncthreads();
    }

    // ---- phase 2: softmax over key axis ----
#pragma unroll
    for (int fm = 0; fm < 2; ++fm)
#pragma unroll
        for (int j = 0; j < 4; ++j) {
            float mx = -1e30f;
#pragma unroll
            for (int fn = 0; fn < 8; ++fn) mx = fmaxf(mx, acc[fm][fn][j]);
            for (int o = 1; o <= 8; o <<= 1) mx = fmaxf(mx, __shfl_xor(mx, o));
            if (cc == 0) red[w * 32 + fm * 16 + cr * 4 + j] = mx;
        }
    __syncthreads();

    float inv[2][4];
#pragma unroll
    for (int fm = 0; fm < 2; ++fm)
#pragma unroll
        for (int j = 0; j < 4; ++j) {
            int r = fm * 16 + cr * 4 + j;
            float mx = fmaxf(fmaxf(red[r], red[32 + r]), fmaxf(red[64 + r], red[96 + r]));
            float s = 0.f;
#pragma unroll
            for (int fn = 0; fn < 8; ++fn) {
                float e = __expf(acc[fm][fn][j] - mx);
                acc[fm][fn][j] = e;
                s += e;
            }
            for (int o = 1; o <= 8; o <<= 1) s += __shfl_xor(s, o);
            if (cc == 0) red2[w * 32 + r] = s;
        }
    __syncthreads();
#pragma unroll
    for (int fm = 0; fm < 2; ++fm)
#pragma unroll
        for (int j = 0; j < 4; ++j) {
            int r = fm * 16 + cr * 4 + j;
            inv[fm][j] = 1.f / (red2[r] + red2[32 + r] + red2[64 + r] + red2[96 + r]);
        }

    // write P (bf16) into swizzled LDS tile (elem col ^= (row&7)<<3)
#pragma unroll
    for (int fm = 0; fm < 2; ++fm)
#pragma unroll
        for (int fn = 0; fn < 8; ++fn)
#pragma unroll
            for (int j = 0; j < 4; ++j) {
                int row = fm * 16 + cr * 4 + j;
                int col = w * 128 + fn * 16 + cc;
                Pt[row * 512 + (col ^ ((row & 7) << 3))] = f2b(acc[fm][fn][j] * inv[fm][j]);
            }
    __syncthreads();

    // ---- phase 3: attn = P @ V (LDS-staged V^T chunks) ----
    const int wr = w >> 1, wc2 = w & 1;
    f32x4 po[3] = {};
    for (int j0 = 0; j0 < TT; j0 += 32) {
#pragma unroll
        for (int q = 0; q < 2; ++q) {
            int ci = q * 4 + w;
            if (ci < 6) {
                int e = ci * 512 + lane * 8;
                int r = e >> 5, c = e & 31;
                GLDS(Vt + ((long)(bh * ESS + r)) * TT + j0 + c, (char*)Vs + ci * 1024);
            }
        }
        __syncthreads();
        int prow = wr * 16 + fr;
        short8 pa = *(const short8*)&Pt[prow * 512 + ((j0 + kb * 8) ^ ((prow & 7) << 3))];
#pragma unroll
        for (int fn = 0; fn < 3; ++fn) {
            short8 vb = *(const short8*)&Vs[(wc2 * 48 + fn * 16 + fr) * 32 + kb * 8];
            po[fn] = __builtin_amdgcn_mfma_f32_16x16x32_bf16(pa, vb, po[fn], 0, 0, 0);
        }
        __syncthreads();
    }

#pragma unroll
    for (int fn = 0; fn < 3; ++fn)
#pragma unroll
        for (int j = 0; j < 4; ++j) {
            int grow = m0 + wr * 16 + cr * 4 + j;
            int gcol = h * ESS + wc2 * 48 + fn * 16 + cc;
            attn[((long)(b * TT + grow)) * EMBD + gcol] = f2b(po[fn][j]);
        }
}

// ---------------------------------------------------------------------------
__global__ __launch_bounds__(256) void cvt_f2b(
    const float* __restrict__ in, ushort_t* __restrict__ out)
{
    const int i = blockIdx.x * 256 + threadIdx.x;
    float4 v = ((const float4*)in)[i];
    ushort4v o = {f2b(v.x), f2b(v.y), f2b(v.z), f2b(v.w)};
    ((ushort4v*)out)[i] = o;
}

// ---------------------------------------------------------------------------
// Weight conversion. Per-layer contiguous layout (float4/ushort4v units):
//   [wkqv 6912 | wproj 147456 | w1 589824 | w2 589824] = 1334016 per layer
// ---------------------------------------------------------------------------
static __device__ __forceinline__ void cvt_w_one(
    int r, int layer,
    const float* Wkqv, const float* Wproj, const float* w1, const float* w2,
    ushort_t* dst_layer)
{
    const float* src; int base;
    if (r < 6912)        { src = Wkqv  + (long)layer * 27648;   base = 0; }
    else if (r < 154368) { src = Wproj + (long)layer * 589824;  base = 6912; }
    else if (r < 744192) { src = w1    + (long)layer * 2359296; base = 154368; }
    else                 { src = w2    + (long)layer * 2359296; base = 744192; }
    int j = r - base;
    float4 v = ((const float4*)src)[j];
    ushort4v o = {f2b(v.x), f2b(v.y), f2b(v.z), f2b(v.w)};
    ((ushort4v*)dst_layer)[r] = o;
}

__global__ __launch_bounds__(256) void cvt_weights_all(
    const float* __restrict__ Wkqv, const float* __restrict__ Wproj,
    const float* __restrict__ w1, const float* __restrict__ w2,
    ushort_t* __restrict__ dst)      // 6 layers, stride 5336064 ushorts
{
    int i4 = blockIdx.x * 256 + threadIdx.x;    // 0 .. 8004095
    int layer = i4 / 1334016;
    int r = i4 - layer * 1334016;
    cvt_w_one(r, layer, Wkqv, Wproj, w1, w2, dst + (long)layer * 5336064);
}

__global__ __launch_bounds__(256) void cvt_weights_layer(
    const float* __restrict__ Wkqv, const float* __restrict__ Wproj,
    const float* __restrict__ w1, const float* __restrict__ w2,
    ushort_t* __restrict__ dst, int layer)      // one layer into dst
{
    int r = blockIdx.x * 256 + threadIdx.x;     // 0 .. 1334015
    cvt_w_one(r, layer, Wkqv, Wproj, w1, w2, dst);
}

// ---------------------------------------------------------------------------
// x = LayerNorm(x + r0 + r1 (+bias)) * g + b ; r0/r1 are bf16 partials.
// Also emit bf16 copy of x.
// ---------------------------------------------------------------------------
__global__ __launch_bounds__(192) void add_ln(
    float* __restrict__ x, const ushort_t* __restrict__ r0,
    const ushort_t* __restrict__ r1, const float* __restrict__ bias,
    const float* __restrict__ g, const float* __restrict__ bta,
    ushort_t* __restrict__ xb)
{
    const long row = blockIdx.x;
    float4* xr = (float4*)(x + row * EMBD);
    const ushort4v* q0 = (const ushort4v*)(r0 + row * EMBD);
    const ushort4v* q1 = (const ushort4v*)(r1 + row * EMBD);
    __shared__ float sh[4];
    const int tid = threadIdx.x;
    const int lane = tid & 63, w = tid >> 6;

    float4 a = xr[tid];
    ushort4v u0 = q0[tid], u1 = q1[tid];
    float v[4] = {a.x + b2f(u0.x) + b2f(u1.x), a.y + b2f(u0.y) + b2f(u1.y),
                  a.z + b2f(u0.z) + b2f(u1.z), a.w + b2f(u0.w) + b2f(u1.w)};
    if (bias) {
        float4 b4 = ((const float4*)bias)[tid];
        v[0] += b4.x; v[1] += b4.y; v[2] += b4.z; v[3] += b4.w;
    }
    float s = v[0] + v[1] + v[2] + v[3];
    for (int o = 32; o; o >>= 1) s += __shfl_xor(s, o);
    if (lane == 0) sh[w] = s;
    __syncthreads();
    float mu = (sh[0] + sh[1] + sh[2]) * (1.f / EMBD);

    float var = 0.f;
#pragma unroll
    for (int c = 0; c < 4; ++c) { float d = v[c] - mu; var += d * d; }
    for (int o = 32; o; o >>= 1) var += __shfl_xor(var, o);
    __syncthreads();
    if (lane == 0) sh[w] = var;
    __syncthreads();
    var = (sh[0] + sh[1] + sh[2]) * (1.f / EMBD);
    float rstd = rsqrtf(var + 1e-5f);

    const float4 g4 = ((const float4*)g)[tid];
    const float4 b4 = ((const float4*)bta)[tid];
    float o0 = (v[0] - mu) * rstd * g4.x + b4.x;
    float o1 = (v[1] - mu) * rstd * g4.y + b4.y;
    float o2 = (v[2] - mu) * rstd * g4.z + b4.z;
    float o3 = (v[3] - mu) * rstd * g4.w + b4.w;
    float4 ov = {o0, o1, o2, o3};
    xr[tid] = ov;
    ushort4v ob = {f2b(o0), f2b(o1), f2b(o2), f2b(o3)};
    ((ushort4v*)(xb + row * EMBD))[tid] = ob;
}

// ---------------------------------------------------------------------------
extern "C" void kernel_launch(void* const* d_in, const int* in_sizes, int n_in,
                              void* d_out, int out_size, void* d_ws, size_t ws_size,
                              hipStream_t stream) {
    const float* x_in  = (const float*)d_in[0];
    const float* Wkqv  = (const float*)d_in[1];
    const float* Wproj = (const float*)d_in[2];
    const float* ln1_g = (const float*)d_in[3];
    const float* ln1_b = (const float*)d_in[4];
    const float* ln2_g = (const float*)d_in[5];
    const float* ln2_b = (const float*)d_in[6];
    const float* ff_w1 = (const float*)d_in[7];
    const float* ff_b1 = (const float*)d_in[8];
    const float* ff_w2 = (const float*)d_in[9];
    const float* ff_b2 = (const float*)d_in[10];

    float* x = (float*)d_out;
    char* ws = (char*)d_ws;
    ushort_t* Qh     = (ushort_t*)(ws);                   // 37.7 MB
    ushort_t* Kh     = (ushort_t*)(ws + 37748736);        // 37.7 MB
    ushort_t* Vtb    = (ushort_t*)(ws + 75497472);        // 6.3 MB
    ushort_t* res0b  = (ushort_t*)(ws + 75497472);        // 6.3 MB bf16 (union Vtb)
    ushort_t* res1b  = (ushort_t*)(ws + 81788928);        // 6.3 MB bf16
    ushort_t* h1b    = (ushort_t*)(ws + 100663296);       // 25.2 MB
    ushort_t* xb     = (ushort_t*)(ws + 125829120);       // 6.3 MB
    ushort_t* attnb  = (ushort_t*)(ws + 132120576);       // 6.3 MB
    ushort_t* Wall   = (ushort_t*)(ws + 138412032);
    const size_t WLAYER_B = 10672128;          // bytes per layer slot
    const int    WLAYER_E = 5336064;           // ushorts per layer slot
    const int big = (ws_size >= 138412032 + 6 * WLAYER_B) ? 1 : 0;
    const long RES_STRIDE = 3145728;           // res1b - res0b in elements

    hipMemcpyAsync(x, x_in, (size_t)BB * TT * EMBD * sizeof(float),
                   hipMemcpyDeviceToDevice, stream);
    cvt_f2b<<<3072, 256, 0, stream>>>(x_in, xb);
    if (big)
        cvt_weights_all<<<31266, 256, 0, stream>>>(Wkqv, Wproj, ff_w1, ff_w2, Wall);

    const float scale = 0.10206207261596577f;  // 1/sqrt(96)

    for (int l = 0; l < NLAYER; ++l) {
        const float* b1 = ff_b1 + (size_t)l * FFD;
        const float* b2 = ff_b2 + (size_t)l * EMBD;

        ushort_t* Wl = Wall + (big ? (long)l * WLAYER_E : 0);
        if (!big)
            cvt_weights_layer<<<5211, 256, 0, stream>>>(Wkqv, Wproj, ff_w1, ff_w2, Wl, l);
        ushort_t* Wkqvb  = Wl;
        ushort_t* Wprojb = Wl + 27648;
        ushort_t* W1b    = Wl + 617472;
        ushort_t* W2b    = Wl + 2976768;

        // kqv GEMM with direct scatter epilogue: K,Q(scaled) -> history, V -> Vt
        kqv_gemm<<<dim3(3, 256, 1), 256, 0, stream>>>(
            xb, Wkqvb, Kh, Qh, Vtb, l * ESS, scale);

        // fused: S = Qh Kh^T (scale pre-folded, Kd=96*(l+1)); attn = softmax @ V
        fused_attn<<<1024, 256, 0, stream>>>(
            Qh, Kh, Vtb, attnb, ESS * (l + 1));

        // res0/res1 (bf16) = attn @ Wproj^T split-K (Vtb dead)
        gemm_mfma<128, 128, 2, 2, 1, 0, 0, 0><<<dim3(6, 32, 2), 256, 0, stream>>>(
            attnb, EMBD, Wprojb, EMBD, res0b, EMBD, EMBD / 2, 1.f, nullptr,
            1, 384, 0, 384, 0, RES_STRIDE, 0);

        add_ln<<<BB * TT, 192, 0, stream>>>(x, res0b, res1b, nullptr,
            ln1_g + (size_t)l * EMBD, ln1_b + (size_t)l * EMBD, xb);

        // h1 = gelu(xb @ W1^T + b1), fast-gelu epilogue
        gemm_mfma<128, 128, 2, 2, 1, 1, 1, 0><<<dim3(24, 32, 1), 256, 0, stream>>>(
            xb, EMBD, W1b, EMBD, h1b, FFD, EMBD, 1.f, b1,
            1, 0, 0, 0, 0, 0, 0);

        // res0/res1 (bf16) = h1 @ W2^T split-K (b2 applied in ln2)
        gemm_mfma<128, 128, 2, 2, 1, 0, 0, 0><<<dim3(6, 32, 2), 256, 0, stream>>>(
            h1b, FFD, W2b, FFD, res0b, EMBD, FFD / 2, 1.f, nullptr,
            1, 1536, 0, 1536, 0, RES_STRIDE, 0);

        add_ln<<<BB * TT, 192, 0, stream>>>(x, res0b, res1b, b2,
            ln2_g + (size_t)l * EMBD, ln2_b + (size_t)l * EMBD, xb);
    }
}

// Round 13
// 1142.739 us; speedup vs baseline: 1.1113x; 1.0001x over previous
//
#include <hip/hip_runtime.h>
#include <math.h>

#define BB 8
#define TT 512
#define HH 8
#define ESS 96
#define EMBD 768
#define FFD 3072
#define NLAYER 6
#define KHMAX 576   // 96 * 6, history feature pitch

typedef unsigned short ushort_t;
typedef __attribute__((ext_vector_type(8))) short short8;
typedef __attribute__((ext_vector_type(4))) float f32x4;
typedef __attribute__((ext_vector_type(4))) unsigned short ushort4v;

static __device__ __forceinline__ ushort_t f2b(float f) {
    unsigned u = __builtin_bit_cast(unsigned, f);
    unsigned r = (u + 0x7fffu + ((u >> 16) & 1u)) >> 16;
    return (ushort_t)r;
}
static __device__ __forceinline__ float b2f(ushort_t u) {
    return __builtin_bit_cast(float, ((unsigned)u) << 16);
}

#define GLDS(gp, lp) __builtin_amdgcn_global_load_lds( \
    (const __attribute__((address_space(1))) void*)(gp), \
    (__attribute__((address_space(3))) void*)(lp), 16, 0, 0)

// ---------------------------------------------------------------------------
// bf16 MFMA GEMM: C = alpha * A(M,K) * B(N,K)^T (+beta*C) (+bias) (+gelu)
// ---------------------------------------------------------------------------
template<int BM, int BN, int WM, int WN, int OUTBF, int HASBIAS, int GELU, int BETA>
__global__ __launch_bounds__(256) void gemm_mfma(
    const ushort_t* __restrict__ A, int lda,
    const ushort_t* __restrict__ B, int ldb,
    void* __restrict__ Cv, int ldc,
    int K, float alpha,
    const float* __restrict__ bias,
    int bdiv, long sAb, long sAh, long sBb, long sBh, long sCb, long sCh)
{
    constexpr int BK = 32;
    constexpr int WTM = BM / WM;
    constexpr int WTN = BN / WN;
    constexpr int MF = WTM / 16, NF = WTN / 16;
    constexpr int ACH = (BM * BK * 2) / 1024;
    constexpr int BCH = (BN * BK * 2) / 1024;

    const int z = blockIdx.z;
    const int zb = z / bdiv, zh = z % bdiv;
    A += (long)zb * sAb + (long)zh * sAh;
    B += (long)zb * sBb + (long)zh * sBh;
    const long coff = (long)zb * sCb + (long)zh * sCh;

    __shared__ ushort_t As[BM * BK];
    __shared__ ushort_t Bs[BN * BK];

    const int tid = threadIdx.x;
    const int w = tid >> 6, lane = tid & 63;
    const int wr = w / WN, wc = w % WN;
    const int m0 = blockIdx.y * BM;
    const int n0 = blockIdx.x * BN;

    f32x4 acc[MF][NF] = {};

    const int fr = lane & 15;
    const int kb = lane >> 4;

    for (int k0 = 0; k0 < K; k0 += BK) {
#pragma unroll
        for (int q = 0; q < (ACH + 3) / 4; ++q) {
            int ci = q * 4 + w;
            if (ci < ACH) {
                int e = ci * 512 + lane * 8;
                int r = e >> 5, c = e & 31;
                GLDS(A + (long)(m0 + r) * lda + (k0 + c), (char*)As + ci * 1024);
            }
        }
#pragma unroll
        for (int q = 0; q < (BCH + 3) / 4; ++q) {
            int ci = q * 4 + w;
            if (ci < BCH) {
                int e = ci * 512 + lane * 8;
                int r = e >> 5, c = e & 31;
                GLDS(B + (long)(n0 + r) * ldb + (k0 + c), (char*)Bs + ci * 1024);
            }
        }
        __syncthreads();

        short8 af[MF], bfr[NF];
#pragma unroll
        for (int fm = 0; fm < MF; ++fm)
            af[fm] = *(const short8*)&As[(wr * WTM + fm * 16 + fr) * 32 + kb * 8];
#pragma unroll
        for (int fn = 0; fn < NF; ++fn)
            bfr[fn] = *(const short8*)&Bs[(wc * WTN + fn * 16 + fr) * 32 + kb * 8];
#pragma unroll
        for (int fm = 0; fm < MF; ++fm)
#pragma unroll
            for (int fn = 0; fn < NF; ++fn)
                acc[fm][fn] = __builtin_amdgcn_mfma_f32_16x16x32_bf16(
                    af[fm], bfr[fn], acc[fm][fn], 0, 0, 0);
        __syncthreads();
    }

    const int cr = lane >> 4;
    const int cc = lane & 15;
#pragma unroll
    for (int fm = 0; fm < MF; ++fm) {
#pragma unroll
        for (int fn = 0; fn < NF; ++fn) {
#pragma unroll
            for (int j = 0; j < 4; ++j) {
                int gm = m0 + wr * WTM + fm * 16 + cr * 4 + j;
                int gn = n0 + wc * WTN + fn * 16 + cc;
                float v = alpha * acc[fm][fn][j];
                if (HASBIAS) v += bias[gn];
                if (GELU) {
                    float zz = 1.5957691216f * fmaf(0.044715f * v * v, v, v);
                    v = v / (1.f + __expf(-zz));
                }
                long idx = coff + (long)gm * ldc + gn;
                if (BETA) v += ((const float*)Cv)[idx];
                if (OUTBF) ((ushort_t*)Cv)[idx] = f2b(v);
                else       ((float*)Cv)[idx] = v;
            }
        }
    }
}

// ---------------------------------------------------------------------------
// kqv GEMM with scatter epilogue: A = xb (B*T*H, 96), B = Wkqv (288, 96).
// Writes K -> Kh[..,loff+n], Q*scale -> Qh[..,loff+n], V -> Vt[(bh,s),t].
// ---------------------------------------------------------------------------
__global__ __launch_bounds__(256) void kqv_gemm(
    const ushort_t* __restrict__ A,       // xb, lda 96
    const ushort_t* __restrict__ Bw,      // Wkqvb, ldb 96
    ushort_t* __restrict__ Kh, ushort_t* __restrict__ Qh,
    ushort_t* __restrict__ Vt, int loff, float scale)
{
    constexpr int BM = 128, BN = 96, BK = 32;
    __shared__ ushort_t As[BM * BK];
    __shared__ ushort_t Bs[BN * BK];

    const int tid = threadIdx.x;
    const int w = tid >> 6, lane = tid & 63;
    const int m0 = blockIdx.y * BM;
    const int n0 = blockIdx.x * BN;

    f32x4 acc[2][6] = {};
    const int fr = lane & 15;
    const int kb = lane >> 4;

    for (int k0 = 0; k0 < 96; k0 += BK) {
#pragma unroll
        for (int q = 0; q < 2; ++q) {
            int ci = q * 4 + w;
            int e = ci * 512 + lane * 8;
            int r = e >> 5, c = e & 31;
            GLDS(A + (long)(m0 + r) * ESS + (k0 + c), (char*)As + ci * 1024);
        }
        {
            int ci = w;
            int e = ci * 512 + lane * 8;
            int r = e >> 5, c = e & 31;
            GLDS(Bw + (long)(n0 + r) * ESS + (k0 + c), (char*)Bs + ci * 1024);
            if (w < 2) {
                int ci2 = 4 + w;
                int e2 = ci2 * 512 + lane * 8;
                int r2 = e2 >> 5, c2 = e2 & 31;
                GLDS(Bw + (long)(n0 + r2) * ESS + (k0 + c2), (char*)Bs + ci2 * 1024);
            }
        }
        __syncthreads();

        short8 af[2], bfr[6];
#pragma unroll
        for (int fm = 0; fm < 2; ++fm)
            af[fm] = *(const short8*)&As[(w * 32 + fm * 16 + fr) * 32 + kb * 8];
#pragma unroll
        for (int fn = 0; fn < 6; ++fn)
            bfr[fn] = *(const short8*)&Bs[(fn * 16 + fr) * 32 + kb * 8];
#pragma unroll
        for (int fm = 0; fm < 2; ++fm)
#pragma unroll
            for (int fn = 0; fn < 6; ++fn)
                acc[fm][fn] = __builtin_amdgcn_mfma_f32_16x16x32_bf16(
                    af[fm], bfr[fn], acc[fm][fn], 0, 0, 0);
        __syncthreads();
    }

    const int cr = lane >> 4;
    const int cc = lane & 15;
    const int kind = blockIdx.x;      // 0 = K, 1 = Q, 2 = V
#pragma unroll
    for (int fm = 0; fm < 2; ++fm) {
#pragma unroll
        for (int fn = 0; fn < 6; ++fn) {
#pragma unroll
            for (int j = 0; j < 4; ++j) {
                int gm = m0 + w * 32 + fm * 16 + cr * 4 + j;
                int s = fn * 16 + cc;
                float v = acc[fm][fn][j];
                int h = gm & 7;
                int bt = gm >> 3;
                int t = bt & 511, b = bt >> 9;
                int bh = b * HH + h;
                if (kind == 0)
                    Kh[((long)(bh * TT + t)) * KHMAX + loff + s] = f2b(v);
                else if (kind == 1)
                    Qh[((long)(bh * TT + t)) * KHMAX + loff + s] = f2b(v * scale);
                else
                    Vt[((long)(bh * ESS + s)) * TT + t] = f2b(v);
            }
        }
    }
}

// ---------------------------------------------------------------------------
// Fused attention with Q/K-history accumulation (RealFormer carry).
// Phase 1: wave-local double-buffered pipeline with COUNTED vmcnt (T4) —
// each wave owns rows [128w,128w+128) split into two 4KB sub-buffers;
// 4-10 loads stay in flight across every k-step; no block barriers.
// Q = 2 lane-private gather loads folded into the same pipeline.
// Phases 2/3 unchanged (R9/R12 structure). Pt unions the K staging region;
// safe: P-writes happen after two __syncthreads (full drain) in phase 2.
// ---------------------------------------------------------------------------
__global__ __launch_bounds__(256) void fused_attn(
    const ushort_t* __restrict__ Qh,    // (B*H, T, 576) bf16, cols [0,Kd), pre-scaled
    const ushort_t* __restrict__ Kh,    // (B*H, T, 576) bf16
    const ushort_t* __restrict__ Vt,    // (B*H, 96, T) bf16
    ushort_t* __restrict__ attn,        // (B,T,EMB) bf16
    int Kd)
{
    __shared__ char lds[38912];
    ushort_t* Bs = (ushort_t*)lds;              // 32 KiB: K tile 512x32 (phase 1)
    ushort_t* Pt = (ushort_t*)lds;              // union: P 32x512 bf16 (swizzled)
    ushort_t* Vs = (ushort_t*)(lds + 32768);    // 6 KiB: V^T chunk (phase 3)
    float* red   = (float*)(lds + 32768);       // 512 B (union w/ Vs, barrier-ordered)
    float* red2  = (float*)(lds + 33280);       // 512 B

    // XCD swizzle: hw xcd = wg & 7 (round-robin)
    const int wg = blockIdx.x;
    const int xcd = wg & 7;
    const int sub = wg >> 3;
    const int m0 = (sub & 15) * 32;
    const int bh = (sub >> 4) * 8 + xcd;
    const int b = bh >> 3, h = bh & 7;

    const int tid = threadIdx.x;
    const int w = tid >> 6, lane = tid & 63;
    const int fr = lane & 15, kb = lane >> 4;
    const int cr = kb, cc = fr;

    f32x4 acc[2][8] = {};

    const ushort_t* Qbase = Qh + ((long)(bh * TT + m0 + fr)) * KHMAX + kb * 8;
    const int ci0 = w * 8;
    const int nsteps = Kd >> 5;

    // stage sub-buffer s (4 chunks = rows 128w + 64s .. +63) at col kk
#define STAGE_SUB(s, kk) \
    _Pragma("unroll") \
    for (int q = 0; q < 4; ++q) { \
        int ci = ci0 + (s) * 4 + q; \
        int e = ci * 512 + lane * 8; \
        int r = e >> 5, c = e & 31; \
        GLDS(Kh + ((long)(bh * TT + r)) * KHMAX + (kk) + c, (char*)Bs + ci * 1024); \
    }

    // ---- prologue: queue = [Q(0):2, sub0(0):4, sub1(0):4] ----
    short8 afc0 = *(const short8*)(Qbase);
    short8 afc1 = *(const short8*)(Qbase + 16 * KHMAX);
    STAGE_SUB(0, 0)
    STAGE_SUB(1, 0)

    for (int i = 0; i < nsteps; ++i) {
        const int kn = (i + 1 < nsteps) ? (i + 1) * 32 : 0;  // tail prefetch reads col 0 (unused)

        // A: wait Q(i)+sub0(i) (oldest 6), leave sub1(i)=4 in flight
        asm volatile("s_waitcnt vmcnt(4)" ::: "memory");
        __builtin_amdgcn_sched_barrier(0);
#pragma unroll
        for (int fn = 0; fn < 4; ++fn) {
            short8 bf = *(const short8*)&Bs[(w * 128 + fn * 16 + fr) * 32 + kb * 8];
            acc[0][fn] = __builtin_amdgcn_mfma_f32_16x16x32_bf16(afc0, bf, acc[0][fn], 0, 0, 0);
            acc[1][fn] = __builtin_amdgcn_mfma_f32_16x16x32_bf16(afc1, bf, acc[1][fn], 0, 0, 0);
        }
        // B: WAR guard for sub0 ds_reads, then issue Q(i+1)+sub0(i+1)
        asm volatile("s_waitcnt lgkmcnt(0)" ::: "memory");
        __builtin_amdgcn_sched_barrier(0);
        short8 afn0 = *(const short8*)(Qbase + kn);
        short8 afn1 = *(const short8*)(Qbase + 16 * KHMAX + kn);
        STAGE_SUB(0, kn)
        // C: wait sub1(i) (oldest 4), leave Q(i+1)+sub0(i+1)=6 in flight
        asm volatile("s_waitcnt vmcnt(6)" ::: "memory");
        __builtin_amdgcn_sched_barrier(0);
#pragma unroll
        for (int fn = 4; fn < 8; ++fn) {
            short8 bf = *(const short8*)&Bs[(w * 128 + fn * 16 + fr) * 32 + kb * 8];
            acc[0][fn] = __builtin_amdgcn_mfma_f32_16x16x32_bf16(afc0, bf, acc[0][fn], 0, 0, 0);
            acc[1][fn] = __builtin_amdgcn_mfma_f32_16x16x32_bf16(afc1, bf, acc[1][fn], 0, 0, 0);
        }
        // D: WAR guard for sub1 ds_reads, then issue sub1(i+1)
        asm volatile("s_waitcnt lgkmcnt(0)" ::: "memory");
        __builtin_amdgcn_sched_barrier(0);
        STAGE_SUB(1, kn)
        afc0 = afn0;
        afc1 = afn1;
    }
#undef STAGE_SUB

    // ---- phase 2: softmax over key axis ----
    // (first __syncthreads drains vmcnt(0): retires tail prefetch before
    //  any P-write can touch the Bs/Pt union)
#pragma unroll
    for (int fm = 0; fm < 2; ++fm)
#pragma unroll
        for (int j = 0; j < 4; ++j) {
            float mx = -1e30f;
#pragma unroll
            for (int fn = 0; fn < 8; ++fn) mx = fmaxf(mx, acc[fm][fn][j]);
            for (int o = 1; o <= 8; o <<= 1) mx = fmaxf(mx, __shfl_xor(mx, o));
            if (cc == 0) red[w * 32 + fm * 16 + cr * 4 + j] = mx;
        }
    __syncthreads();

    float inv[2][4];
#pragma unroll
    for (int fm = 0; fm < 2; ++fm)
#pragma unroll
        for (int j = 0; j < 4; ++j) {
            int r = fm * 16 + cr * 4 + j;
            float mx = fmaxf(fmaxf(red[r], red[32 + r]), fmaxf(red[64 + r], red[96 + r]));
            float s = 0.f;
#pragma unroll
            for (int fn = 0; fn < 8; ++fn) {
                float e = __expf(acc[fm][fn][j] - mx);
                acc[fm][fn][j] = e;
                s += e;
            }
            for (int o = 1; o <= 8; o <<= 1) s += __shfl_xor(s, o);
            if (cc == 0) red2[w * 32 + r] = s;
        }
    __syncthreads();
#pragma unroll
    for (int fm = 0; fm < 2; ++fm)
#pragma unroll
        for (int j = 0; j < 4; ++j) {
            int r = fm * 16 + cr * 4 + j;
            inv[fm][j] = 1.f / (red2[r] + red2[32 + r] + red2[64 + r] + red2[96 + r]);
        }

    // write P (bf16) into swizzled LDS tile (elem col ^= (row&7)<<3)
#pragma unroll
    for (int fm = 0; fm < 2; ++fm)
#pragma unroll
        for (int fn = 0; fn < 8; ++fn)
#pragma unroll
            for (int j = 0; j < 4; ++j) {
                int row = fm * 16 + cr * 4 + j;
                int col = w * 128 + fn * 16 + cc;
                Pt[row * 512 + (col ^ ((row & 7) << 3))] = f2b(acc[fm][fn][j] * inv[fm][j]);
            }
    __syncthreads();

    // ---- phase 3: attn = P @ V (LDS-staged V^T chunks) ----
    const int wr = w >> 1, wc2 = w & 1;
    f32x4 po[3] = {};
    for (int j0 = 0; j0 < TT; j0 += 32) {
#pragma unroll
        for (int q = 0; q < 2; ++q) {
            int ci = q * 4 + w;
            if (ci < 6) {
                int e = ci * 512 + lane * 8;
                int r = e >> 5, c = e & 31;
                GLDS(Vt + ((long)(bh * ESS + r)) * TT + j0 + c, (char*)Vs + ci * 1024);
            }
        }
        __syncthreads();
        int prow = wr * 16 + fr;
        short8 pa = *(const short8*)&Pt[prow * 512 + ((j0 + kb * 8) ^ ((prow & 7) << 3))];
#pragma unroll
        for (int fn = 0; fn < 3; ++fn) {
            short8 vb = *(const short8*)&Vs[(wc2 * 48 + fn * 16 + fr) * 32 + kb * 8];
            po[fn] = __builtin_amdgcn_mfma_f32_16x16x32_bf16(pa, vb, po[fn], 0, 0, 0);
        }
        __syncthreads();
    }

#pragma unroll
    for (int fn = 0; fn < 3; ++fn)
#pragma unroll
        for (int j = 0; j < 4; ++j) {
            int grow = m0 + wr * 16 + cr * 4 + j;
            int gcol = h * ESS + wc2 * 48 + fn * 16 + cc;
            attn[((long)(b * TT + grow)) * EMBD + gcol] = f2b(po[fn][j]);
        }
}

// ---------------------------------------------------------------------------
__global__ __launch_bounds__(256) void cvt_f2b(
    const float* __restrict__ in, ushort_t* __restrict__ out)
{
    const int i = blockIdx.x * 256 + threadIdx.x;
    float4 v = ((const float4*)in)[i];
    ushort4v o = {f2b(v.x), f2b(v.y), f2b(v.z), f2b(v.w)};
    ((ushort4v*)out)[i] = o;
}

// ---------------------------------------------------------------------------
// Weight conversion. Per-layer contiguous layout (float4/ushort4v units):
//   [wkqv 6912 | wproj 147456 | w1 589824 | w2 589824] = 1334016 per layer
// ---------------------------------------------------------------------------
static __device__ __forceinline__ void cvt_w_one(
    int r, int layer,
    const float* Wkqv, const float* Wproj, const float* w1, const float* w2,
    ushort_t* dst_layer)
{
    const float* src; int base;
    if (r < 6912)        { src = Wkqv  + (long)layer * 27648;   base = 0; }
    else if (r < 154368) { src = Wproj + (long)layer * 589824;  base = 6912; }
    else if (r < 744192) { src = w1    + (long)layer * 2359296; base = 154368; }
    else                 { src = w2    + (long)layer * 2359296; base = 744192; }
    int j = r - base;
    float4 v = ((const float4*)src)[j];
    ushort4v o = {f2b(v.x), f2b(v.y), f2b(v.z), f2b(v.w)};
    ((ushort4v*)dst_layer)[r] = o;
}

__global__ __launch_bounds__(256) void cvt_weights_all(
    const float* __restrict__ Wkqv, const float* __restrict__ Wproj,
    const float* __restrict__ w1, const float* __restrict__ w2,
    ushort_t* __restrict__ dst)      // 6 layers, stride 5336064 ushorts
{
    int i4 = blockIdx.x * 256 + threadIdx.x;    // 0 .. 8004095
    int layer = i4 / 1334016;
    int r = i4 - layer * 1334016;
    cvt_w_one(r, layer, Wkqv, Wproj, w1, w2, dst + (long)layer * 5336064);
}

__global__ __launch_bounds__(256) void cvt_weights_layer(
    const float* __restrict__ Wkqv, const float* __restrict__ Wproj,
    const float* __restrict__ w1, const float* __restrict__ w2,
    ushort_t* __restrict__ dst, int layer)      // one layer into dst
{
    int r = blockIdx.x * 256 + threadIdx.x;     // 0 .. 1334015
    cvt_w_one(r, layer, Wkqv, Wproj, w1, w2, dst);
}

// ---------------------------------------------------------------------------
// x = LayerNorm(x + r0 + r1 (+bias)) * g + b ; r0/r1 are bf16 partials.
// Also emit bf16 copy of x.
// ---------------------------------------------------------------------------
__global__ __launch_bounds__(192) void add_ln(
    float* __restrict__ x, const ushort_t* __restrict__ r0,
    const ushort_t* __restrict__ r1, const float* __restrict__ bias,
    const float* __restrict__ g, const float* __restrict__ bta,
    ushort_t* __restrict__ xb)
{
    const long row = blockIdx.x;
    float4* xr = (float4*)(x + row * EMBD);
    const ushort4v* q0 = (const ushort4v*)(r0 + row * EMBD);
    const ushort4v* q1 = (const ushort4v*)(r1 + row * EMBD);
    __shared__ float sh[4];
    const int tid = threadIdx.x;
    const int lane = tid & 63, w = tid >> 6;

    float4 a = xr[tid];
    ushort4v u0 = q0[tid], u1 = q1[tid];
    float v[4] = {a.x + b2f(u0.x) + b2f(u1.x), a.y + b2f(u0.y) + b2f(u1.y),
                  a.z + b2f(u0.z) + b2f(u1.z), a.w + b2f(u0.w) + b2f(u1.w)};
    if (bias) {
        float4 b4 = ((const float4*)bias)[tid];
        v[0] += b4.x; v[1] += b4.y; v[2] += b4.z; v[3] += b4.w;
    }
    float s = v[0] + v[1] + v[2] + v[3];
    for (int o = 32; o; o >>= 1) s += __shfl_xor(s, o);
    if (lane == 0) sh[w] = s;
    __syncthreads();
    float mu = (sh[0] + sh[1] + sh[2]) * (1.f / EMBD);

    float var = 0.f;
#pragma unroll
    for (int c = 0; c < 4; ++c) { float d = v[c] - mu; var += d * d; }
    for (int o = 32; o; o >>= 1) var += __shfl_xor(var, o);
    __syncthreads();
    if (lane == 0) sh[w] = var;
    __syncthreads();
    var = (sh[0] + sh[1] + sh[2]) * (1.f / EMBD);
    float rstd = rsqrtf(var + 1e-5f);

    const float4 g4 = ((const float4*)g)[tid];
    const float4 b4 = ((const float4*)bta)[tid];
    float o0 = (v[0] - mu) * rstd * g4.x + b4.x;
    float o1 = (v[1] - mu) * rstd * g4.y + b4.y;
    float o2 = (v[2] - mu) * rstd * g4.z + b4.z;
    float o3 = (v[3] - mu) * rstd * g4.w + b4.w;
    float4 ov = {o0, o1, o2, o3};
    xr[tid] = ov;
    ushort4v ob = {f2b(o0), f2b(o1), f2b(o2), f2b(o3)};
    ((ushort4v*)(xb + row * EMBD))[tid] = ob;
}

// ---------------------------------------------------------------------------
extern "C" void kernel_launch(void* const* d_in, const int* in_sizes, int n_in,
                              void* d_out, int out_size, void* d_ws, size_t ws_size,
                              hipStream_t stream) {
    const float* x_in  = (const float*)d_in[0];
    const float* Wkqv  = (const float*)d_in[1];
    const float* Wproj = (const float*)d_in[2];
    const float* ln1_g = (const float*)d_in[3];
    const float* ln1_b = (const float*)d_in[4];
    const float* ln2_g = (const float*)d_in[5];
    const float* ln2_b = (const float*)d_in[6];
    const float* ff_w1 = (const float*)d_in[7];
    const float* ff_b1 = (const float*)d_in[8];
    const float* ff_w2 = (const float*)d_in[9];
    const float* ff_b2 = (const float*)d_in[10];

    float* x = (float*)d_out;
    char* ws = (char*)d_ws;
    ushort_t* Qh     = (ushort_t*)(ws);                   // 37.7 MB
    ushort_t* Kh     = (ushort_t*)(ws + 37748736);        // 37.7 MB
    ushort_t* Vtb    = (ushort_t*)(ws + 75497472);        // 6.3 MB
    ushort_t* res0b  = (ushort_t*)(ws + 75497472);        // 6.3 MB bf16 (union Vtb)
    ushort_t* res1b  = (ushort_t*)(ws + 81788928);        // 6.3 MB bf16
    ushort_t* h1b    = (ushort_t*)(ws + 100663296);       // 25.2 MB
    ushort_t* xb     = (ushort_t*)(ws + 125829120);       // 6.3 MB
    ushort_t* attnb  = (ushort_t*)(ws + 132120576);       // 6.3 MB
    ushort_t* Wall   = (ushort_t*)(ws + 138412032);
    const size_t WLAYER_B = 10672128;          // bytes per layer slot
    const int    WLAYER_E = 5336064;           // ushorts per layer slot
    const int big = (ws_size >= 138412032 + 6 * WLAYER_B) ? 1 : 0;
    const long RES_STRIDE = 3145728;           // res1b - res0b in elements

    hipMemcpyAsync(x, x_in, (size_t)BB * TT * EMBD * sizeof(float),
                   hipMemcpyDeviceToDevice, stream);
    cvt_f2b<<<3072, 256, 0, stream>>>(x_in, xb);
    if (big)
        cvt_weights_all<<<31266, 256, 0, stream>>>(Wkqv, Wproj, ff_w1, ff_w2, Wall);

    const float scale = 0.10206207261596577f;  // 1/sqrt(96)

    for (int l = 0; l < NLAYER; ++l) {
        const float* b1 = ff_b1 + (size_t)l * FFD;
        const float* b2 = ff_b2 + (size_t)l * EMBD;

        ushort_t* Wl = Wall + (big ? (long)l * WLAYER_E : 0);
        if (!big)
            cvt_weights_layer<<<5211, 256, 0, stream>>>(Wkqv, Wproj, ff_w1, ff_w2, Wl, l);
        ushort_t* Wkqvb  = Wl;
        ushort_t* Wprojb = Wl + 27648;
        ushort_t* W1b    = Wl + 617472;
        ushort_t* W2b    = Wl + 2976768;

        // kqv GEMM with direct scatter epilogue: K,Q(scaled) -> history, V -> Vt
        kqv_gemm<<<dim3(3, 256, 1), 256, 0, stream>>>(
            xb, Wkqvb, Kh, Qh, Vtb, l * ESS, scale);

        // fused: S = Qh Kh^T (scale pre-folded, Kd=96*(l+1)); attn = softmax @ V
        fused_attn<<<1024, 256, 0, stream>>>(
            Qh, Kh, Vtb, attnb, ESS * (l + 1));

        // res0/res1 (bf16) = attn @ Wproj^T split-K (Vtb dead)
        gemm_mfma<128, 128, 2, 2, 1, 0, 0, 0><<<dim3(6, 32, 2), 256, 0, stream>>>(
            attnb, EMBD, Wprojb, EMBD, res0b, EMBD, EMBD / 2, 1.f, nullptr,
            1, 384, 0, 384, 0, RES_STRIDE, 0);

        add_ln<<<BB * TT, 192, 0, stream>>>(x, res0b, res1b, nullptr,
            ln1_g + (size_t)l * EMBD, ln1_b + (size_t)l * EMBD, xb);

        // h1 = gelu(xb @ W1^T + b1), fast-gelu epilogue
        gemm_mfma<128, 128, 2, 2, 1, 1, 1, 0><<<dim3(24, 32, 1), 256, 0, stream>>>(
            xb, EMBD, W1b, EMBD, h1b, FFD, EMBD, 1.f, b1,
            1, 0, 0, 0, 0, 0, 0);

        // res0/res1 (bf16) = h1 @ W2^T split-K (b2 applied in ln2)
        gemm_mfma<128, 128, 2, 2, 1, 0, 0, 0><<<dim3(6, 32, 2), 256, 0, stream>>>(
            h1b, FFD, W2b, FFD, res0b, EMBD, FFD / 2, 1.f, nullptr,
            1, 1536, 0, 1536, 0, RES_STRIDE, 0);

        add_ln<<<BB * TT, 192, 0, stream>>>(x, res0b, res1b, b2,
            ln2_g + (size_t)l * EMBD, ln2_b + (size_t)l * EMBD, xb);
    }
}

// Round 14
// 1110.218 us; speedup vs baseline: 1.1438x; 1.0293x over previous
//
#include <hip/hip_runtime.h>
#include <math.h>

#define BB 8
#define TT 512
#define HH 8
#define ESS 96
#define EMBD 768
#define FFD 3072
#define NLAYER 6
#define KHMAX 576   // 96 * 6, history feature pitch

typedef unsigned short ushort_t;
typedef __attribute__((ext_vector_type(8))) short short8;
typedef __attribute__((ext_vector_type(4))) float f32x4;
typedef __attribute__((ext_vector_type(4))) unsigned short ushort4v;

static __device__ __forceinline__ ushort_t f2b(float f) {
    unsigned u = __builtin_bit_cast(unsigned, f);
    unsigned r = (u + 0x7fffu + ((u >> 16) & 1u)) >> 16;
    return (ushort_t)r;
}
static __device__ __forceinline__ float b2f(ushort_t u) {
    return __builtin_bit_cast(float, ((unsigned)u) << 16);
}

#define GLDS(gp, lp) __builtin_amdgcn_global_load_lds( \
    (const __attribute__((address_space(1))) void*)(gp), \
    (__attribute__((address_space(3))) void*)(lp), 16, 0, 0)

// ---------------------------------------------------------------------------
// bf16 MFMA GEMM: C = alpha * A(M,K) * B(N,K)^T (+beta*C) (+bias) (+gelu)
// GELU uses tanh-form (x*sigmoid(1.5958(x+0.044715x^3))), ~3e-4 abs err.
// ---------------------------------------------------------------------------
template<int BM, int BN, int WM, int WN, int OUTBF, int HASBIAS, int GELU, int BETA>
__global__ __launch_bounds__(256) void gemm_mfma(
    const ushort_t* __restrict__ A, int lda,
    const ushort_t* __restrict__ B, int ldb,
    void* __restrict__ Cv, int ldc,
    int K, float alpha,
    const float* __restrict__ bias,
    int bdiv, long sAb, long sAh, long sBb, long sBh, long sCb, long sCh)
{
    constexpr int BK = 32;
    constexpr int WTM = BM / WM;
    constexpr int WTN = BN / WN;
    constexpr int MF = WTM / 16, NF = WTN / 16;
    constexpr int ACH = (BM * BK * 2) / 1024;
    constexpr int BCH = (BN * BK * 2) / 1024;

    const int z = blockIdx.z;
    const int zb = z / bdiv, zh = z % bdiv;
    A += (long)zb * sAb + (long)zh * sAh;
    B += (long)zb * sBb + (long)zh * sBh;
    const long coff = (long)zb * sCb + (long)zh * sCh;

    __shared__ ushort_t As[BM * BK];
    __shared__ ushort_t Bs[BN * BK];

    const int tid = threadIdx.x;
    const int w = tid >> 6, lane = tid & 63;
    const int wr = w / WN, wc = w % WN;
    const int m0 = blockIdx.y * BM;
    const int n0 = blockIdx.x * BN;

    f32x4 acc[MF][NF] = {};

    const int fr = lane & 15;
    const int kb = lane >> 4;

    for (int k0 = 0; k0 < K; k0 += BK) {
#pragma unroll
        for (int q = 0; q < (ACH + 3) / 4; ++q) {
            int ci = q * 4 + w;
            if (ci < ACH) {
                int e = ci * 512 + lane * 8;
                int r = e >> 5, c = e & 31;
                GLDS(A + (long)(m0 + r) * lda + (k0 + c), (char*)As + ci * 1024);
            }
        }
#pragma unroll
        for (int q = 0; q < (BCH + 3) / 4; ++q) {
            int ci = q * 4 + w;
            if (ci < BCH) {
                int e = ci * 512 + lane * 8;
                int r = e >> 5, c = e & 31;
                GLDS(B + (long)(n0 + r) * ldb + (k0 + c), (char*)Bs + ci * 1024);
            }
        }
        __syncthreads();

        short8 af[MF], bfr[NF];
#pragma unroll
        for (int fm = 0; fm < MF; ++fm)
            af[fm] = *(const short8*)&As[(wr * WTM + fm * 16 + fr) * 32 + kb * 8];
#pragma unroll
        for (int fn = 0; fn < NF; ++fn)
            bfr[fn] = *(const short8*)&Bs[(wc * WTN + fn * 16 + fr) * 32 + kb * 8];
#pragma unroll
        for (int fm = 0; fm < MF; ++fm)
#pragma unroll
            for (int fn = 0; fn < NF; ++fn)
                acc[fm][fn] = __builtin_amdgcn_mfma_f32_16x16x32_bf16(
                    af[fm], bfr[fn], acc[fm][fn], 0, 0, 0);
        __syncthreads();
    }

    const int cr = lane >> 4;
    const int cc = lane & 15;
#pragma unroll
    for (int fm = 0; fm < MF; ++fm) {
#pragma unroll
        for (int fn = 0; fn < NF; ++fn) {
#pragma unroll
            for (int j = 0; j < 4; ++j) {
                int gm = m0 + wr * WTM + fm * 16 + cr * 4 + j;
                int gn = n0 + wc * WTN + fn * 16 + cc;
                float v = alpha * acc[fm][fn][j];
                if (HASBIAS) v += bias[gn];
                if (GELU) {
                    float zz = 1.5957691216f * fmaf(0.044715f * v * v, v, v);
                    v = v / (1.f + __expf(-zz));
                }
                long idx = coff + (long)gm * ldc + gn;
                if (BETA) v += ((const float*)Cv)[idx];
                if (OUTBF) ((ushort_t*)Cv)[idx] = f2b(v);
                else       ((float*)Cv)[idx] = v;
            }
        }
    }
}

// ---------------------------------------------------------------------------
// kqv GEMM with scatter epilogue: A = xb (B*T*H, 96), B = Wkqv (288, 96).
// Writes K -> Kh[..,loff+n], Q*scale -> Qh[..,loff+n], V -> Vt[(bh,s),t].
// ---------------------------------------------------------------------------
__global__ __launch_bounds__(256) void kqv_gemm(
    const ushort_t* __restrict__ A,       // xb, lda 96
    const ushort_t* __restrict__ Bw,      // Wkqvb, ldb 96
    ushort_t* __restrict__ Kh, ushort_t* __restrict__ Qh,
    ushort_t* __restrict__ Vt, int loff, float scale)
{
    constexpr int BM = 128, BN = 96, BK = 32;
    __shared__ ushort_t As[BM * BK];
    __shared__ ushort_t Bs[BN * BK];

    const int tid = threadIdx.x;
    const int w = tid >> 6, lane = tid & 63;
    const int m0 = blockIdx.y * BM;
    const int n0 = blockIdx.x * BN;

    f32x4 acc[2][6] = {};
    const int fr = lane & 15;
    const int kb = lane >> 4;

    for (int k0 = 0; k0 < 96; k0 += BK) {
#pragma unroll
        for (int q = 0; q < 2; ++q) {
            int ci = q * 4 + w;
            int e = ci * 512 + lane * 8;
            int r = e >> 5, c = e & 31;
            GLDS(A + (long)(m0 + r) * ESS + (k0 + c), (char*)As + ci * 1024);
        }
        {
            int ci = w;
            int e = ci * 512 + lane * 8;
            int r = e >> 5, c = e & 31;
            GLDS(Bw + (long)(n0 + r) * ESS + (k0 + c), (char*)Bs + ci * 1024);
            if (w < 2) {
                int ci2 = 4 + w;
                int e2 = ci2 * 512 + lane * 8;
                int r2 = e2 >> 5, c2 = e2 & 31;
                GLDS(Bw + (long)(n0 + r2) * ESS + (k0 + c2), (char*)Bs + ci2 * 1024);
            }
        }
        __syncthreads();

        short8 af[2], bfr[6];
#pragma unroll
        for (int fm = 0; fm < 2; ++fm)
            af[fm] = *(const short8*)&As[(w * 32 + fm * 16 + fr) * 32 + kb * 8];
#pragma unroll
        for (int fn = 0; fn < 6; ++fn)
            bfr[fn] = *(const short8*)&Bs[(fn * 16 + fr) * 32 + kb * 8];
#pragma unroll
        for (int fm = 0; fm < 2; ++fm)
#pragma unroll
            for (int fn = 0; fn < 6; ++fn)
                acc[fm][fn] = __builtin_amdgcn_mfma_f32_16x16x32_bf16(
                    af[fm], bfr[fn], acc[fm][fn], 0, 0, 0);
        __syncthreads();
    }

    const int cr = lane >> 4;
    const int cc = lane & 15;
    const int kind = blockIdx.x;      // 0 = K, 1 = Q, 2 = V
#pragma unroll
    for (int fm = 0; fm < 2; ++fm) {
#pragma unroll
        for (int fn = 0; fn < 6; ++fn) {
#pragma unroll
            for (int j = 0; j < 4; ++j) {
                int gm = m0 + w * 32 + fm * 16 + cr * 4 + j;
                int s = fn * 16 + cc;
                float v = acc[fm][fn][j];
                int h = gm & 7;
                int bt = gm >> 3;
                int t = bt & 511, b = bt >> 9;
                int bh = b * HH + h;
                if (kind == 0)
                    Kh[((long)(bh * TT + t)) * KHMAX + loff + s] = f2b(v);
                else if (kind == 1)
                    Qh[((long)(bh * TT + t)) * KHMAX + loff + s] = f2b(v * scale);
                else
                    Vt[((long)(bh * ESS + s)) * TT + t] = f2b(v);
            }
        }
    }
}

// ---------------------------------------------------------------------------
// Fused attention with Q/K-history accumulation (RealFormer carry).
// R12-exact structure (best measured, 75.6us): phase 1 = block-barrier GLDS
// staging. Scale pre-folded into Qh.
// ---------------------------------------------------------------------------
__global__ __launch_bounds__(256) void fused_attn(
    const ushort_t* __restrict__ Qh,    // (B*H, T, 576) bf16, cols [0,Kd)
    const ushort_t* __restrict__ Kh,    // (B*H, T, 576) bf16
    const ushort_t* __restrict__ Vt,    // (B*H, 96, T) bf16
    ushort_t* __restrict__ attn,        // (B,T,EMB) bf16
    int Kd)
{
    __shared__ char lds[40960];
    ushort_t* As = (ushort_t*)lds;              // 2 KiB: Q tile 32x32
    ushort_t* Bs = (ushort_t*)(lds + 2048);     // 32 KiB: K tile 512x32
    ushort_t* Pt = (ushort_t*)(lds + 2048);     // union: P 32x512 bf16 (swizzled)
    ushort_t* Vs = (ushort_t*)(lds + 34816);    // 6 KiB: V^T chunk 96x32
    float* red   = (float*)(lds + 34816);       // 512 B (union w/ Vs)
    float* red2  = (float*)(lds + 35328);       // 512 B

    // XCD swizzle: hw xcd = wg & 7 (round-robin)
    const int wg = blockIdx.x;
    const int xcd = wg & 7;
    const int sub = wg >> 3;          // 0..127, sequential within an XCD
    const int m0 = (sub & 15) * 32;   // m-tile fastest -> same bh consecutive
    const int bh = (sub >> 4) * 8 + xcd;
    const int b = bh >> 3, h = bh & 7;

    const int tid = threadIdx.x;
    const int w = tid >> 6, lane = tid & 63;
    const int fr = lane & 15, kb = lane >> 4;
    const int cr = kb, cc = fr;

    f32x4 acc[2][8] = {};

    // ---- phase 1: S = Q_hist K_hist^T over Kd feature cols ----
    for (int k0 = 0; k0 < Kd; k0 += 32) {
        if (w < 2) {
            int e = w * 512 + lane * 8;
            int r = e >> 5, c = e & 31;
            GLDS(Qh + ((long)(bh * TT + m0 + r)) * KHMAX + k0 + c,
                 (char*)As + w * 1024);
        }
#pragma unroll
        for (int q = 0; q < 8; ++q) {
            int ci = q * 4 + w;
            int e = ci * 512 + lane * 8;
            int r = e >> 5, c = e & 31;
            GLDS(Kh + ((long)(bh * TT + r)) * KHMAX + k0 + c,
                 (char*)Bs + ci * 1024);
        }
        __syncthreads();
        short8 af0 = *(const short8*)&As[fr * 32 + kb * 8];
        short8 af1 = *(const short8*)&As[(16 + fr) * 32 + kb * 8];
#pragma unroll
        for (int fn = 0; fn < 8; ++fn) {
            short8 bf = *(const short8*)&Bs[(w * 128 + fn * 16 + fr) * 32 + kb * 8];
            acc[0][fn] = __builtin_amdgcn_mfma_f32_16x16x32_bf16(af0, bf, acc[0][fn], 0, 0, 0);
            acc[1][fn] = __builtin_amdgcn_mfma_f32_16x16x32_bf16(af1, bf, acc[1][fn], 0, 0, 0);
        }
        __syncthreads();
    }

    // ---- phase 2: softmax over key axis ----
#pragma unroll
    for (int fm = 0; fm < 2; ++fm)
#pragma unroll
        for (int j = 0; j < 4; ++j) {
            float mx = -1e30f;
#pragma unroll
            for (int fn = 0; fn < 8; ++fn) mx = fmaxf(mx, acc[fm][fn][j]);
            for (int o = 1; o <= 8; o <<= 1) mx = fmaxf(mx, __shfl_xor(mx, o));
            if (cc == 0) red[w * 32 + fm * 16 + cr * 4 + j] = mx;
        }
    __syncthreads();

    float inv[2][4];
#pragma unroll
    for (int fm = 0; fm < 2; ++fm)
#pragma unroll
        for (int j = 0; j < 4; ++j) {
            int r = fm * 16 + cr * 4 + j;
            float mx = fmaxf(fmaxf(red[r], red[32 + r]), fmaxf(red[64 + r], red[96 + r]));
            float s = 0.f;
#pragma unroll
            for (int fn = 0; fn < 8; ++fn) {
                float e = __expf(acc[fm][fn][j] - mx);
                acc[fm][fn][j] = e;
                s += e;
            }
            for (int o = 1; o <= 8; o <<= 1) s += __shfl_xor(s, o);
            if (cc == 0) red2[w * 32 + r] = s;
        }
    __syncthreads();
#pragma unroll
    for (int fm = 0; fm < 2; ++fm)
#pragma unroll
        for (int j = 0; j < 4; ++j) {
            int r = fm * 16 + cr * 4 + j;
            inv[fm][j] = 1.f / (red2[r] + red2[32 + r] + red2[64 + r] + red2[96 + r]);
        }

    // write P (bf16) into swizzled LDS tile (elem col ^= (row&7)<<3)
#pragma unroll
    for (int fm = 0; fm < 2; ++fm)
#pragma unroll
        for (int fn = 0; fn < 8; ++fn)
#pragma unroll
            for (int j = 0; j < 4; ++j) {
                int row = fm * 16 + cr * 4 + j;
                int col = w * 128 + fn * 16 + cc;
                Pt[row * 512 + (col ^ ((row & 7) << 3))] = f2b(acc[fm][fn][j] * inv[fm][j]);
            }
    __syncthreads();

    // ---- phase 3: attn = P @ V (LDS-staged V^T chunks) ----
    const int wr = w >> 1, wc2 = w & 1;
    f32x4 po[3] = {};
    for (int j0 = 0; j0 < TT; j0 += 32) {
#pragma unroll
        for (int q = 0; q < 2; ++q) {
            int ci = q * 4 + w;
            if (ci < 6) {
                int e = ci * 512 + lane * 8;
                int r = e >> 5, c = e & 31;
                GLDS(Vt + ((long)(bh * ESS + r)) * TT + j0 + c, (char*)Vs + ci * 1024);
            }
        }
        __syncthreads();
        int prow = wr * 16 + fr;
        short8 pa = *(const short8*)&Pt[prow * 512 + ((j0 + kb * 8) ^ ((prow & 7) << 3))];
#pragma unroll
        for (int fn = 0; fn < 3; ++fn) {
            short8 vb = *(const short8*)&Vs[(wc2 * 48 + fn * 16 + fr) * 32 + kb * 8];
            po[fn] = __builtin_amdgcn_mfma_f32_16x16x32_bf16(pa, vb, po[fn], 0, 0, 0);
        }
        __syncthreads();
    }

#pragma unroll
    for (int fn = 0; fn < 3; ++fn)
#pragma unroll
        for (int j = 0; j < 4; ++j) {
            int grow = m0 + wr * 16 + cr * 4 + j;
            int gcol = h * ESS + wc2 * 48 + fn * 16 + cc;
            attn[((long)(b * TT + grow)) * EMBD + gcol] = f2b(po[fn][j]);
        }
}

// ---------------------------------------------------------------------------
__global__ __launch_bounds__(256) void cvt_f2b(
    const float* __restrict__ in, ushort_t* __restrict__ out)
{
    const int i = blockIdx.x * 256 + threadIdx.x;
    float4 v = ((const float4*)in)[i];
    ushort4v o = {f2b(v.x), f2b(v.y), f2b(v.z), f2b(v.w)};
    ((ushort4v*)out)[i] = o;
}

// ---------------------------------------------------------------------------
// Weight conversion. Per-layer contiguous layout (float4/ushort4v units):
//   [wkqv 6912 | wproj 147456 | w1 589824 | w2 589824] = 1334016 per layer
// ---------------------------------------------------------------------------
static __device__ __forceinline__ void cvt_w_one(
    int r, int layer,
    const float* Wkqv, const float* Wproj, const float* w1, const float* w2,
    ushort_t* dst_layer)
{
    const float* src; int base;
    if (r < 6912)        { src = Wkqv  + (long)layer * 27648;   base = 0; }
    else if (r < 154368) { src = Wproj + (long)layer * 589824;  base = 6912; }
    else if (r < 744192) { src = w1    + (long)layer * 2359296; base = 154368; }
    else                 { src = w2    + (long)layer * 2359296; base = 744192; }
    int j = r - base;
    float4 v = ((const float4*)src)[j];
    ushort4v o = {f2b(v.x), f2b(v.y), f2b(v.z), f2b(v.w)};
    ((ushort4v*)dst_layer)[r] = o;
}

__global__ __launch_bounds__(256) void cvt_weights_all(
    const float* __restrict__ Wkqv, const float* __restrict__ Wproj,
    const float* __restrict__ w1, const float* __restrict__ w2,
    ushort_t* __restrict__ dst)      // 6 layers, stride 5336064 ushorts
{
    int i4 = blockIdx.x * 256 + threadIdx.x;    // 0 .. 8004095
    int layer = i4 / 1334016;
    int r = i4 - layer * 1334016;
    cvt_w_one(r, layer, Wkqv, Wproj, w1, w2, dst + (long)layer * 5336064);
}

__global__ __launch_bounds__(256) void cvt_weights_layer(
    const float* __restrict__ Wkqv, const float* __restrict__ Wproj,
    const float* __restrict__ w1, const float* __restrict__ w2,
    ushort_t* __restrict__ dst, int layer)      // one layer into dst
{
    int r = blockIdx.x * 256 + threadIdx.x;     // 0 .. 1334015
    cvt_w_one(r, layer, Wkqv, Wproj, w1, w2, dst);
}

// ---------------------------------------------------------------------------
// x = LayerNorm(x + sum_{i<NR} res_i (+bias)) * g + b ; res_i bf16 partials
// at stride RSTRIDE. Also emit bf16 copy of x.
// ---------------------------------------------------------------------------
template<int NR>
__global__ __launch_bounds__(192) void add_ln(
    float* __restrict__ x, const ushort_t* __restrict__ res, long rstride,
    const float* __restrict__ bias,
    const float* __restrict__ g, const float* __restrict__ bta,
    ushort_t* __restrict__ xb)
{
    const long row = blockIdx.x;
    float4* xr = (float4*)(x + row * EMBD);
    __shared__ float sh[4];
    const int tid = threadIdx.x;
    const int lane = tid & 63, w = tid >> 6;

    float4 a = xr[tid];
    float v[4] = {a.x, a.y, a.z, a.w};
#pragma unroll
    for (int p = 0; p < NR; ++p) {
        ushort4v u = ((const ushort4v*)(res + p * rstride + row * EMBD))[tid];
        v[0] += b2f(u.x); v[1] += b2f(u.y); v[2] += b2f(u.z); v[3] += b2f(u.w);
    }
    if (bias) {
        float4 b4 = ((const float4*)bias)[tid];
        v[0] += b4.x; v[1] += b4.y; v[2] += b4.z; v[3] += b4.w;
    }
    float s = v[0] + v[1] + v[2] + v[3];
    for (int o = 32; o; o >>= 1) s += __shfl_xor(s, o);
    if (lane == 0) sh[w] = s;
    __syncthreads();
    float mu = (sh[0] + sh[1] + sh[2]) * (1.f / EMBD);

    float var = 0.f;
#pragma unroll
    for (int c = 0; c < 4; ++c) { float d = v[c] - mu; var += d * d; }
    for (int o = 32; o; o >>= 1) var += __shfl_xor(var, o);
    __syncthreads();
    if (lane == 0) sh[w] = var;
    __syncthreads();
    var = (sh[0] + sh[1] + sh[2]) * (1.f / EMBD);
    float rstd = rsqrtf(var + 1e-5f);

    const float4 g4 = ((const float4*)g)[tid];
    const float4 b4 = ((const float4*)bta)[tid];
    float o0 = (v[0] - mu) * rstd * g4.x + b4.x;
    float o1 = (v[1] - mu) * rstd * g4.y + b4.y;
    float o2 = (v[2] - mu) * rstd * g4.z + b4.z;
    float o3 = (v[3] - mu) * rstd * g4.w + b4.w;
    float4 ov = {o0, o1, o2, o3};
    xr[tid] = ov;
    ushort4v ob = {f2b(o0), f2b(o1), f2b(o2), f2b(o3)};
    ((ushort4v*)(xb + row * EMBD))[tid] = ob;
}

// ---------------------------------------------------------------------------
extern "C" void kernel_launch(void* const* d_in, const int* in_sizes, int n_in,
                              void* d_out, int out_size, void* d_ws, size_t ws_size,
                              hipStream_t stream) {
    const float* x_in  = (const float*)d_in[0];
    const float* Wkqv  = (const float*)d_in[1];
    const float* Wproj = (const float*)d_in[2];
    const float* ln1_g = (const float*)d_in[3];
    const float* ln1_b = (const float*)d_in[4];
    const float* ln2_g = (const float*)d_in[5];
    const float* ln2_b = (const float*)d_in[6];
    const float* ff_w1 = (const float*)d_in[7];
    const float* ff_b1 = (const float*)d_in[8];
    const float* ff_w2 = (const float*)d_in[9];
    const float* ff_b2 = (const float*)d_in[10];

    float* x = (float*)d_out;
    char* ws = (char*)d_ws;
    ushort_t* Qh     = (ushort_t*)(ws);                   // 37.7 MB
    ushort_t* Kh     = (ushort_t*)(ws + 37748736);        // 37.7 MB
    ushort_t* Vtb    = (ushort_t*)(ws + 75497472);        // 6.3 MB (union res0)
    ushort_t* resb   = (ushort_t*)(ws + 75497472);        // 4 x 6.3 MB bf16 partials
    ushort_t* h1b    = (ushort_t*)(ws + 100663296);       // 25.2 MB
    ushort_t* xb     = (ushort_t*)(ws + 125829120);       // 6.3 MB
    ushort_t* attnb  = (ushort_t*)(ws + 132120576);       // 6.3 MB
    ushort_t* Wall   = (ushort_t*)(ws + 138412032);
    const size_t WLAYER_B = 10672128;          // bytes per layer slot
    const int    WLAYER_E = 5336064;           // ushorts per layer slot
    const int big = (ws_size >= 138412032 + 6 * WLAYER_B) ? 1 : 0;
    const long RES_STRIDE = 3145728;           // partial stride in elements (6.3 MB)

    hipMemcpyAsync(x, x_in, (size_t)BB * TT * EMBD * sizeof(float),
                   hipMemcpyDeviceToDevice, stream);
    cvt_f2b<<<3072, 256, 0, stream>>>(x_in, xb);
    if (big)
        cvt_weights_all<<<31266, 256, 0, stream>>>(Wkqv, Wproj, ff_w1, ff_w2, Wall);

    const float scale = 0.10206207261596577f;  // 1/sqrt(96)

    for (int l = 0; l < NLAYER; ++l) {
        const float* b1 = ff_b1 + (size_t)l * FFD;
        const float* b2 = ff_b2 + (size_t)l * EMBD;

        ushort_t* Wl = Wall + (big ? (long)l * WLAYER_E : 0);
        if (!big)
            cvt_weights_layer<<<5211, 256, 0, stream>>>(Wkqv, Wproj, ff_w1, ff_w2, Wl, l);
        ushort_t* Wkqvb  = Wl;
        ushort_t* Wprojb = Wl + 27648;
        ushort_t* W1b    = Wl + 617472;
        ushort_t* W2b    = Wl + 2976768;

        // kqv GEMM with direct scatter epilogue: K,Q(scaled) -> history, V -> Vt
        kqv_gemm<<<dim3(3, 256, 1), 256, 0, stream>>>(
            xb, Wkqvb, Kh, Qh, Vtb, l * ESS, scale);

        // fused: S = Qh Kh^T (scale pre-folded, Kd=96*(l+1)); attn = softmax @ V
        fused_attn<<<1024, 256, 0, stream>>>(
            Qh, Kh, Vtb, attnb, ESS * (l + 1));

        // res partials (bf16) = attn @ Wproj^T split-K2 (Vtb dead)
        gemm_mfma<128, 128, 2, 2, 1, 0, 0, 0><<<dim3(6, 32, 2), 256, 0, stream>>>(
            attnb, EMBD, Wprojb, EMBD, resb, EMBD, EMBD / 2, 1.f, nullptr,
            1, 384, 0, 384, 0, RES_STRIDE, 0);

        add_ln<2><<<BB * TT, 192, 0, stream>>>(x, resb, RES_STRIDE, nullptr,
            ln1_g + (size_t)l * EMBD, ln1_b + (size_t)l * EMBD, xb);

        // h1 = gelu(xb @ W1^T + b1), fast-gelu epilogue
        gemm_mfma<128, 128, 2, 2, 1, 1, 1, 0><<<dim3(24, 32, 1), 256, 0, stream>>>(
            xb, EMBD, W1b, EMBD, h1b, FFD, EMBD, 1.f, b1,
            1, 0, 0, 0, 0, 0, 0);

        // res partials (bf16) = h1 @ W2^T split-K4 (b2 applied in ln2)
        gemm_mfma<128, 128, 2, 2, 1, 0, 0, 0><<<dim3(6, 32, 4), 256, 0, stream>>>(
            h1b, FFD, W2b, FFD, resb, EMBD, FFD / 4, 1.f, nullptr,
            1, 768, 0, 768, 0, RES_STRIDE, 0);

        add_ln<4><<<BB * TT, 192, 0, stream>>>(x, resb, RES_STRIDE, b2,
            ln2_g + (size_t)l * EMBD, ln2_b + (size_t)l * EMBD, xb);
    }
}

// Round 15
// 1073.633 us; speedup vs baseline: 1.1828x; 1.0341x over previous
//
#include <hip/hip_runtime.h>
#include <math.h>

#define BB 8
#define TT 512
#define HH 8
#define ESS 96
#define EMBD 768
#define FFD 3072
#define NLAYER 6
#define KHMAX 576   // 96 * 6, history feature pitch

typedef unsigned short ushort_t;
typedef __attribute__((ext_vector_type(8))) short short8;
typedef __attribute__((ext_vector_type(4))) float f32x4;
typedef __attribute__((ext_vector_type(4))) unsigned short ushort4v;

static __device__ __forceinline__ ushort_t f2b(float f) {
    unsigned u = __builtin_bit_cast(unsigned, f);
    unsigned r = (u + 0x7fffu + ((u >> 16) & 1u)) >> 16;
    return (ushort_t)r;
}
static __device__ __forceinline__ float b2f(ushort_t u) {
    return __builtin_bit_cast(float, ((unsigned)u) << 16);
}

#define GLDS(gp, lp) __builtin_amdgcn_global_load_lds( \
    (const __attribute__((address_space(1))) void*)(gp), \
    (__attribute__((address_space(3))) void*)(lp), 16, 0, 0)

// ---------------------------------------------------------------------------
// bf16 MFMA GEMM: C = alpha * A(M,K) * B(N,K)^T (+beta*C) (+bias) (+gelu)
// GELU uses tanh-form (x*sigmoid(1.5958(x+0.044715x^3))), ~3e-4 abs err.
// ---------------------------------------------------------------------------
template<int BM, int BN, int WM, int WN, int OUTBF, int HASBIAS, int GELU, int BETA>
__global__ __launch_bounds__(256) void gemm_mfma(
    const ushort_t* __restrict__ A, int lda,
    const ushort_t* __restrict__ B, int ldb,
    void* __restrict__ Cv, int ldc,
    int K, float alpha,
    const float* __restrict__ bias,
    int bdiv, long sAb, long sAh, long sBb, long sBh, long sCb, long sCh)
{
    constexpr int BK = 32;
    constexpr int WTM = BM / WM;
    constexpr int WTN = BN / WN;
    constexpr int MF = WTM / 16, NF = WTN / 16;
    constexpr int ACH = (BM * BK * 2) / 1024;
    constexpr int BCH = (BN * BK * 2) / 1024;

    const int z = blockIdx.z;
    const int zb = z / bdiv, zh = z % bdiv;
    A += (long)zb * sAb + (long)zh * sAh;
    B += (long)zb * sBb + (long)zh * sBh;
    const long coff = (long)zb * sCb + (long)zh * sCh;

    __shared__ ushort_t As[BM * BK];
    __shared__ ushort_t Bs[BN * BK];

    const int tid = threadIdx.x;
    const int w = tid >> 6, lane = tid & 63;
    const int wr = w / WN, wc = w % WN;
    const int m0 = blockIdx.y * BM;
    const int n0 = blockIdx.x * BN;

    f32x4 acc[MF][NF] = {};

    const int fr = lane & 15;
    const int kb = lane >> 4;

    for (int k0 = 0; k0 < K; k0 += BK) {
#pragma unroll
        for (int q = 0; q < (ACH + 3) / 4; ++q) {
            int ci = q * 4 + w;
            if (ci < ACH) {
                int e = ci * 512 + lane * 8;
                int r = e >> 5, c = e & 31;
                GLDS(A + (long)(m0 + r) * lda + (k0 + c), (char*)As + ci * 1024);
            }
        }
#pragma unroll
        for (int q = 0; q < (BCH + 3) / 4; ++q) {
            int ci = q * 4 + w;
            if (ci < BCH) {
                int e = ci * 512 + lane * 8;
                int r = e >> 5, c = e & 31;
                GLDS(B + (long)(n0 + r) * ldb + (k0 + c), (char*)Bs + ci * 1024);
            }
        }
        __syncthreads();

        short8 af[MF], bfr[NF];
#pragma unroll
        for (int fm = 0; fm < MF; ++fm)
            af[fm] = *(const short8*)&As[(wr * WTM + fm * 16 + fr) * 32 + kb * 8];
#pragma unroll
        for (int fn = 0; fn < NF; ++fn)
            bfr[fn] = *(const short8*)&Bs[(wc * WTN + fn * 16 + fr) * 32 + kb * 8];
#pragma unroll
        for (int fm = 0; fm < MF; ++fm)
#pragma unroll
            for (int fn = 0; fn < NF; ++fn)
                acc[fm][fn] = __builtin_amdgcn_mfma_f32_16x16x32_bf16(
                    af[fm], bfr[fn], acc[fm][fn], 0, 0, 0);
        __syncthreads();
    }

    const int cr = lane >> 4;
    const int cc = lane & 15;
#pragma unroll
    for (int fm = 0; fm < MF; ++fm) {
#pragma unroll
        for (int fn = 0; fn < NF; ++fn) {
#pragma unroll
            for (int j = 0; j < 4; ++j) {
                int gm = m0 + wr * WTM + fm * 16 + cr * 4 + j;
                int gn = n0 + wc * WTN + fn * 16 + cc;
                float v = alpha * acc[fm][fn][j];
                if (HASBIAS) v += bias[gn];
                if (GELU) {
                    float zz = 1.5957691216f * fmaf(0.044715f * v * v, v, v);
                    v = v / (1.f + __expf(-zz));
                }
                long idx = coff + (long)gm * ldc + gn;
                if (BETA) v += ((const float*)Cv)[idx];
                if (OUTBF) ((ushort_t*)Cv)[idx] = f2b(v);
                else       ((float*)Cv)[idx] = v;
            }
        }
    }
}

// ---------------------------------------------------------------------------
// kqv GEMM with scatter epilogue: A = xb (B*T*H, 96), B = Wkqv (288, 96).
// Writes K -> Kh[..,loff+n], Q*scale -> Qh[..,loff+n], V -> Vt[(bh,s),t].
// ---------------------------------------------------------------------------
__global__ __launch_bounds__(256) void kqv_gemm(
    const ushort_t* __restrict__ A,       // xb, lda 96
    const ushort_t* __restrict__ Bw,      // Wkqvb, ldb 96
    ushort_t* __restrict__ Kh, ushort_t* __restrict__ Qh,
    ushort_t* __restrict__ Vt, int loff, float scale)
{
    constexpr int BM = 128, BN = 96, BK = 32;
    __shared__ ushort_t As[BM * BK];
    __shared__ ushort_t Bs[BN * BK];

    const int tid = threadIdx.x;
    const int w = tid >> 6, lane = tid & 63;
    const int m0 = blockIdx.y * BM;
    const int n0 = blockIdx.x * BN;

    f32x4 acc[2][6] = {};
    const int fr = lane & 15;
    const int kb = lane >> 4;

    for (int k0 = 0; k0 < 96; k0 += BK) {
#pragma unroll
        for (int q = 0; q < 2; ++q) {
            int ci = q * 4 + w;
            int e = ci * 512 + lane * 8;
            int r = e >> 5, c = e & 31;
            GLDS(A + (long)(m0 + r) * ESS + (k0 + c), (char*)As + ci * 1024);
        }
        {
            int ci = w;
            int e = ci * 512 + lane * 8;
            int r = e >> 5, c = e & 31;
            GLDS(Bw + (long)(n0 + r) * ESS + (k0 + c), (char*)Bs + ci * 1024);
            if (w < 2) {
                int ci2 = 4 + w;
                int e2 = ci2 * 512 + lane * 8;
                int r2 = e2 >> 5, c2 = e2 & 31;
                GLDS(Bw + (long)(n0 + r2) * ESS + (k0 + c2), (char*)Bs + ci2 * 1024);
            }
        }
        __syncthreads();

        short8 af[2], bfr[6];
#pragma unroll
        for (int fm = 0; fm < 2; ++fm)
            af[fm] = *(const short8*)&As[(w * 32 + fm * 16 + fr) * 32 + kb * 8];
#pragma unroll
        for (int fn = 0; fn < 6; ++fn)
            bfr[fn] = *(const short8*)&Bs[(fn * 16 + fr) * 32 + kb * 8];
#pragma unroll
        for (int fm = 0; fm < 2; ++fm)
#pragma unroll
            for (int fn = 0; fn < 6; ++fn)
                acc[fm][fn] = __builtin_amdgcn_mfma_f32_16x16x32_bf16(
                    af[fm], bfr[fn], acc[fm][fn], 0, 0, 0);
        __syncthreads();
    }

    const int cr = lane >> 4;
    const int cc = lane & 15;
    const int kind = blockIdx.x;      // 0 = K, 1 = Q, 2 = V
#pragma unroll
    for (int fm = 0; fm < 2; ++fm) {
#pragma unroll
        for (int fn = 0; fn < 6; ++fn) {
#pragma unroll
            for (int j = 0; j < 4; ++j) {
                int gm = m0 + w * 32 + fm * 16 + cr * 4 + j;
                int s = fn * 16 + cc;
                float v = acc[fm][fn][j];
                int h = gm & 7;
                int bt = gm >> 3;
                int t = bt & 511, b = bt >> 9;
                int bh = b * HH + h;
                if (kind == 0)
                    Kh[((long)(bh * TT + t)) * KHMAX + loff + s] = f2b(v);
                else if (kind == 1)
                    Qh[((long)(bh * TT + t)) * KHMAX + loff + s] = f2b(v * scale);
                else
                    Vt[((long)(bh * ESS + s)) * TT + t] = f2b(v);
            }
        }
    }
}

// ---------------------------------------------------------------------------
// Fused attention with Q/K-history accumulation (RealFormer carry).
// R12-exact structure (best measured, 75.6us): phase 1 = block-barrier GLDS
// staging. Scale pre-folded into Qh.
// ---------------------------------------------------------------------------
__global__ __launch_bounds__(256) void fused_attn(
    const ushort_t* __restrict__ Qh,    // (B*H, T, 576) bf16, cols [0,Kd)
    const ushort_t* __restrict__ Kh,    // (B*H, T, 576) bf16
    const ushort_t* __restrict__ Vt,    // (B*H, 96, T) bf16
    ushort_t* __restrict__ attn,        // (B,T,EMB) bf16
    int Kd)
{
    __shared__ char lds[40960];
    ushort_t* As = (ushort_t*)lds;              // 2 KiB: Q tile 32x32
    ushort_t* Bs = (ushort_t*)(lds + 2048);     // 32 KiB: K tile 512x32
    ushort_t* Pt = (ushort_t*)(lds + 2048);     // union: P 32x512 bf16 (swizzled)
    ushort_t* Vs = (ushort_t*)(lds + 34816);    // 6 KiB: V^T chunk 96x32
    float* red   = (float*)(lds + 34816);       // 512 B (union w/ Vs)
    float* red2  = (float*)(lds + 35328);       // 512 B

    // XCD swizzle: hw xcd = wg & 7 (round-robin)
    const int wg = blockIdx.x;
    const int xcd = wg & 7;
    const int sub = wg >> 3;          // 0..127, sequential within an XCD
    const int m0 = (sub & 15) * 32;   // m-tile fastest -> same bh consecutive
    const int bh = (sub >> 4) * 8 + xcd;
    const int b = bh >> 3, h = bh & 7;

    const int tid = threadIdx.x;
    const int w = tid >> 6, lane = tid & 63;
    const int fr = lane & 15, kb = lane >> 4;
    const int cr = kb, cc = fr;

    f32x4 acc[2][8] = {};

    // ---- phase 1: S = Q_hist K_hist^T over Kd feature cols ----
    for (int k0 = 0; k0 < Kd; k0 += 32) {
        if (w < 2) {
            int e = w * 512 + lane * 8;
            int r = e >> 5, c = e & 31;
            GLDS(Qh + ((long)(bh * TT + m0 + r)) * KHMAX + k0 + c,
                 (char*)As + w * 1024);
        }
#pragma unroll
        for (int q = 0; q < 8; ++q) {
            int ci = q * 4 + w;
            int e = ci * 512 + lane * 8;
            int r = e >> 5, c = e & 31;
            GLDS(Kh + ((long)(bh * TT + r)) * KHMAX + k0 + c,
                 (char*)Bs + ci * 1024);
        }
        __syncthreads();
        short8 af0 = *(const short8*)&As[fr * 32 + kb * 8];
        short8 af1 = *(const short8*)&As[(16 + fr) * 32 + kb * 8];
#pragma unroll
        for (int fn = 0; fn < 8; ++fn) {
            short8 bf = *(const short8*)&Bs[(w * 128 + fn * 16 + fr) * 32 + kb * 8];
            acc[0][fn] = __builtin_amdgcn_mfma_f32_16x16x32_bf16(af0, bf, acc[0][fn], 0, 0, 0);
            acc[1][fn] = __builtin_amdgcn_mfma_f32_16x16x32_bf16(af1, bf, acc[1][fn], 0, 0, 0);
        }
        __syncthreads();
    }

    // ---- phase 2: softmax over key axis ----
#pragma unroll
    for (int fm = 0; fm < 2; ++fm)
#pragma unroll
        for (int j = 0; j < 4; ++j) {
            float mx = -1e30f;
#pragma unroll
            for (int fn = 0; fn < 8; ++fn) mx = fmaxf(mx, acc[fm][fn][j]);
            for (int o = 1; o <= 8; o <<= 1) mx = fmaxf(mx, __shfl_xor(mx, o));
            if (cc == 0) red[w * 32 + fm * 16 + cr * 4 + j] = mx;
        }
    __syncthreads();

    float inv[2][4];
#pragma unroll
    for (int fm = 0; fm < 2; ++fm)
#pragma unroll
        for (int j = 0; j < 4; ++j) {
            int r = fm * 16 + cr * 4 + j;
            float mx = fmaxf(fmaxf(red[r], red[32 + r]), fmaxf(red[64 + r], red[96 + r]));
            float s = 0.f;
#pragma unroll
            for (int fn = 0; fn < 8; ++fn) {
                float e = __expf(acc[fm][fn][j] - mx);
                acc[fm][fn][j] = e;
                s += e;
            }
            for (int o = 1; o <= 8; o <<= 1) s += __shfl_xor(s, o);
            if (cc == 0) red2[w * 32 + r] = s;
        }
    __syncthreads();
#pragma unroll
    for (int fm = 0; fm < 2; ++fm)
#pragma unroll
        for (int j = 0; j < 4; ++j) {
            int r = fm * 16 + cr * 4 + j;
            inv[fm][j] = 1.f / (red2[r] + red2[32 + r] + red2[64 + r] + red2[96 + r]);
        }

    // write P (bf16) into swizzled LDS tile (elem col ^= (row&7)<<3)
#pragma unroll
    for (int fm = 0; fm < 2; ++fm)
#pragma unroll
        for (int fn = 0; fn < 8; ++fn)
#pragma unroll
            for (int j = 0; j < 4; ++j) {
                int row = fm * 16 + cr * 4 + j;
                int col = w * 128 + fn * 16 + cc;
                Pt[row * 512 + (col ^ ((row & 7) << 3))] = f2b(acc[fm][fn][j] * inv[fm][j]);
            }
    __syncthreads();

    // ---- phase 3: attn = P @ V (LDS-staged V^T chunks) ----
    const int wr = w >> 1, wc2 = w & 1;
    f32x4 po[3] = {};
    for (int j0 = 0; j0 < TT; j0 += 32) {
#pragma unroll
        for (int q = 0; q < 2; ++q) {
            int ci = q * 4 + w;
            if (ci < 6) {
                int e = ci * 512 + lane * 8;
                int r = e >> 5, c = e & 31;
                GLDS(Vt + ((long)(bh * ESS + r)) * TT + j0 + c, (char*)Vs + ci * 1024);
            }
        }
        __syncthreads();
        int prow = wr * 16 + fr;
        short8 pa = *(const short8*)&Pt[prow * 512 + ((j0 + kb * 8) ^ ((prow & 7) << 3))];
#pragma unroll
        for (int fn = 0; fn < 3; ++fn) {
            short8 vb = *(const short8*)&Vs[(wc2 * 48 + fn * 16 + fr) * 32 + kb * 8];
            po[fn] = __builtin_amdgcn_mfma_f32_16x16x32_bf16(pa, vb, po[fn], 0, 0, 0);
        }
        __syncthreads();
    }

#pragma unroll
    for (int fn = 0; fn < 3; ++fn)
#pragma unroll
        for (int j = 0; j < 4; ++j) {
            int grow = m0 + wr * 16 + cr * 4 + j;
            int gcol = h * ESS + wc2 * 48 + fn * 16 + cc;
            attn[((long)(b * TT + grow)) * EMBD + gcol] = f2b(po[fn][j]);
        }
}

// ---------------------------------------------------------------------------
__global__ __launch_bounds__(256) void cvt_f2b(
    const float* __restrict__ in, ushort_t* __restrict__ out)
{
    const int i = blockIdx.x * 256 + threadIdx.x;
    float4 v = ((const float4*)in)[i];
    ushort4v o = {f2b(v.x), f2b(v.y), f2b(v.z), f2b(v.w)};
    ((ushort4v*)out)[i] = o;
}

// ---------------------------------------------------------------------------
// Weight conversion. Per-layer contiguous layout (float4/ushort4v units):
//   [wkqv 6912 | wproj 147456 | w1 589824 | w2 589824] = 1334016 per layer
// ---------------------------------------------------------------------------
static __device__ __forceinline__ void cvt_w_one(
    int r, int layer,
    const float* Wkqv, const float* Wproj, const float* w1, const float* w2,
    ushort_t* dst_layer)
{
    const float* src; int base;
    if (r < 6912)        { src = Wkqv  + (long)layer * 27648;   base = 0; }
    else if (r < 154368) { src = Wproj + (long)layer * 589824;  base = 6912; }
    else if (r < 744192) { src = w1    + (long)layer * 2359296; base = 154368; }
    else                 { src = w2    + (long)layer * 2359296; base = 744192; }
    int j = r - base;
    float4 v = ((const float4*)src)[j];
    ushort4v o = {f2b(v.x), f2b(v.y), f2b(v.z), f2b(v.w)};
    ((ushort4v*)dst_layer)[r] = o;
}

__global__ __launch_bounds__(256) void cvt_weights_all(
    const float* __restrict__ Wkqv, const float* __restrict__ Wproj,
    const float* __restrict__ w1, const float* __restrict__ w2,
    ushort_t* __restrict__ dst)      // 6 layers, stride 5336064 ushorts
{
    int i4 = blockIdx.x * 256 + threadIdx.x;    // 0 .. 8004095
    int layer = i4 / 1334016;
    int r = i4 - layer * 1334016;
    cvt_w_one(r, layer, Wkqv, Wproj, w1, w2, dst + (long)layer * 5336064);
}

__global__ __launch_bounds__(256) void cvt_weights_layer(
    const float* __restrict__ Wkqv, const float* __restrict__ Wproj,
    const float* __restrict__ w1, const float* __restrict__ w2,
    ushort_t* __restrict__ dst, int layer)      // one layer into dst
{
    int r = blockIdx.x * 256 + threadIdx.x;     // 0 .. 1334015
    cvt_w_one(r, layer, Wkqv, Wproj, w1, w2, dst);
}

// ---------------------------------------------------------------------------
// Residual stream lives in bf16 (xio). LN computes in fp32:
//   xnew = LayerNorm(xio + sum_{i<NR} res_i (+bias)) * g + b -> bf16 xio
// FINAL variant also writes fp32 to xf (the harness output buffer).
// ---------------------------------------------------------------------------
template<int NR, int FINAL>
__global__ __launch_bounds__(192) void add_ln(
    ushort_t* __restrict__ xio, const ushort_t* __restrict__ res, long rstride,
    const float* __restrict__ bias,
    const float* __restrict__ g, const float* __restrict__ bta,
    float* __restrict__ xf)
{
    const long row = blockIdx.x;
    ushort4v* xr = (ushort4v*)(xio + row * EMBD);
    __shared__ float sh[4];
    const int tid = threadIdx.x;
    const int lane = tid & 63, w = tid >> 6;

    ushort4v xu = xr[tid];
    float v[4] = {b2f(xu.x), b2f(xu.y), b2f(xu.z), b2f(xu.w)};
#pragma unroll
    for (int p = 0; p < NR; ++p) {
        ushort4v u = ((const ushort4v*)(res + p * rstride + row * EMBD))[tid];
        v[0] += b2f(u.x); v[1] += b2f(u.y); v[2] += b2f(u.z); v[3] += b2f(u.w);
    }
    if (bias) {
        float4 b4 = ((const float4*)bias)[tid];
        v[0] += b4.x; v[1] += b4.y; v[2] += b4.z; v[3] += b4.w;
    }
    float s = v[0] + v[1] + v[2] + v[3];
    for (int o = 32; o; o >>= 1) s += __shfl_xor(s, o);
    if (lane == 0) sh[w] = s;
    __syncthreads();
    float mu = (sh[0] + sh[1] + sh[2]) * (1.f / EMBD);

    float var = 0.f;
#pragma unroll
    for (int c = 0; c < 4; ++c) { float d = v[c] - mu; var += d * d; }
    for (int o = 32; o; o >>= 1) var += __shfl_xor(var, o);
    __syncthreads();
    if (lane == 0) sh[w] = var;
    __syncthreads();
    var = (sh[0] + sh[1] + sh[2]) * (1.f / EMBD);
    float rstd = rsqrtf(var + 1e-5f);

    const float4 g4 = ((const float4*)g)[tid];
    const float4 b4 = ((const float4*)bta)[tid];
    float o0 = (v[0] - mu) * rstd * g4.x + b4.x;
    float o1 = (v[1] - mu) * rstd * g4.y + b4.y;
    float o2 = (v[2] - mu) * rstd * g4.z + b4.z;
    float o3 = (v[3] - mu) * rstd * g4.w + b4.w;
    ushort4v ob = {f2b(o0), f2b(o1), f2b(o2), f2b(o3)};
    xr[tid] = ob;
    if (FINAL) {
        float4 ov = {o0, o1, o2, o3};
        ((float4*)(xf + row * EMBD))[tid] = ov;
    }
}

// ---------------------------------------------------------------------------
extern "C" void kernel_launch(void* const* d_in, const int* in_sizes, int n_in,
                              void* d_out, int out_size, void* d_ws, size_t ws_size,
                              hipStream_t stream) {
    const float* x_in  = (const float*)d_in[0];
    const float* Wkqv  = (const float*)d_in[1];
    const float* Wproj = (const float*)d_in[2];
    const float* ln1_g = (const float*)d_in[3];
    const float* ln1_b = (const float*)d_in[4];
    const float* ln2_g = (const float*)d_in[5];
    const float* ln2_b = (const float*)d_in[6];
    const float* ff_w1 = (const float*)d_in[7];
    const float* ff_b1 = (const float*)d_in[8];
    const float* ff_w2 = (const float*)d_in[9];
    const float* ff_b2 = (const float*)d_in[10];

    float* xout = (float*)d_out;                          // written by final LN only
    char* ws = (char*)d_ws;
    ushort_t* Qh     = (ushort_t*)(ws);                   // 37.7 MB
    ushort_t* Kh     = (ushort_t*)(ws + 37748736);        // 37.7 MB
    ushort_t* Vtb    = (ushort_t*)(ws + 75497472);        // 6.3 MB (union res0)
    ushort_t* resb   = (ushort_t*)(ws + 75497472);        // 4 x 6.3 MB bf16 partials
    ushort_t* h1b    = (ushort_t*)(ws + 100663296);       // 25.2 MB
    ushort_t* xb     = (ushort_t*)(ws + 125829120);       // 6.3 MB bf16 residual stream
    ushort_t* attnb  = (ushort_t*)(ws + 132120576);       // 6.3 MB
    ushort_t* Wall   = (ushort_t*)(ws + 138412032);
    const size_t WLAYER_B = 10672128;          // bytes per layer slot
    const int    WLAYER_E = 5336064;           // ushorts per layer slot
    const int big = (ws_size >= 138412032 + 6 * WLAYER_B) ? 1 : 0;
    const long RES_STRIDE = 3145728;           // partial stride in elements (6.3 MB)

    cvt_f2b<<<3072, 256, 0, stream>>>(x_in, xb);
    if (big)
        cvt_weights_all<<<31266, 256, 0, stream>>>(Wkqv, Wproj, ff_w1, ff_w2, Wall);

    const float scale = 0.10206207261596577f;  // 1/sqrt(96)

    for (int l = 0; l < NLAYER; ++l) {
        const float* b1 = ff_b1 + (size_t)l * FFD;
        const float* b2 = ff_b2 + (size_t)l * EMBD;

        ushort_t* Wl = Wall + (big ? (long)l * WLAYER_E : 0);
        if (!big)
            cvt_weights_layer<<<5211, 256, 0, stream>>>(Wkqv, Wproj, ff_w1, ff_w2, Wl, l);
        ushort_t* Wkqvb  = Wl;
        ushort_t* Wprojb = Wl + 27648;
        ushort_t* W1b    = Wl + 617472;
        ushort_t* W2b    = Wl + 2976768;

        // kqv GEMM with direct scatter epilogue: K,Q(scaled) -> history, V -> Vt
        kqv_gemm<<<dim3(3, 256, 1), 256, 0, stream>>>(
            xb, Wkqvb, Kh, Qh, Vtb, l * ESS, scale);

        // fused: S = Qh Kh^T (scale pre-folded, Kd=96*(l+1)); attn = softmax @ V
        fused_attn<<<1024, 256, 0, stream>>>(
            Qh, Kh, Vtb, attnb, ESS * (l + 1));

        // res partials (bf16) = attn @ Wproj^T split-K2 (Vtb dead)
        gemm_mfma<128, 128, 2, 2, 1, 0, 0, 0><<<dim3(6, 32, 2), 256, 0, stream>>>(
            attnb, EMBD, Wprojb, EMBD, resb, EMBD, EMBD / 2, 1.f, nullptr,
            1, 384, 0, 384, 0, RES_STRIDE, 0);

        add_ln<2, 0><<<BB * TT, 192, 0, stream>>>(xb, resb, RES_STRIDE, nullptr,
            ln1_g + (size_t)l * EMBD, ln1_b + (size_t)l * EMBD, nullptr);

        // h1 = gelu(xb @ W1^T + b1), fast-gelu epilogue
        gemm_mfma<128, 128, 2, 2, 1, 1, 1, 0><<<dim3(24, 32, 1), 256, 0, stream>>>(
            xb, EMBD, W1b, EMBD, h1b, FFD, EMBD, 1.f, b1,
            1, 0, 0, 0, 0, 0, 0);

        // res partials (bf16) = h1 @ W2^T split-K4 (b2 applied in ln2)
        gemm_mfma<128, 128, 2, 2, 1, 0, 0, 0><<<dim3(6, 32, 4), 256, 0, stream>>>(
            h1b, FFD, W2b, FFD, resb, EMBD, FFD / 4, 1.f, nullptr,
            1, 768, 0, 768, 0, RES_STRIDE, 0);

        if (l == NLAYER - 1)
            add_ln<4, 1><<<BB * TT, 192, 0, stream>>>(xb, resb, RES_STRIDE, b2,
                ln2_g + (size_t)l * EMBD, ln2_b + (size_t)l * EMBD, xout);
        else
            add_ln<4, 0><<<BB * TT, 192, 0, stream>>>(xb, resb, RES_STRIDE, b2,
                ln2_g + (size_t)l * EMBD, ln2_b + (size_t)l * EMBD, nullptr);
    }
}

// Round 16
// 949.404 us; speedup vs baseline: 1.3375x; 1.1308x over previous
//
#include <hip/hip_runtime.h>
#include <math.h>

#define BB 8
#define TT 512
#define HH 8
#define ESS 96
#define EMBD 768
#define FFD 3072
#define NLAYER 6
#define KHMAX 576   // 96 * 6, history feature pitch

typedef unsigned short ushort_t;
typedef __attribute__((ext_vector_type(8))) short short8;
typedef __attribute__((ext_vector_type(4))) float f32x4;
typedef __attribute__((ext_vector_type(4))) unsigned short ushort4v;

static __device__ __forceinline__ ushort_t f2b(float f) {
    unsigned u = __builtin_bit_cast(unsigned, f);
    unsigned r = (u + 0x7fffu + ((u >> 16) & 1u)) >> 16;
    return (ushort_t)r;
}
static __device__ __forceinline__ float b2f(ushort_t u) {
    return __builtin_bit_cast(float, ((unsigned)u) << 16);
}

#define GLDS(gp, lp) __builtin_amdgcn_global_load_lds( \
    (const __attribute__((address_space(1))) void*)(gp), \
    (__attribute__((address_space(3))) void*)(lp), 16, 0, 0)

// ---------------------------------------------------------------------------
// bf16 MFMA GEMM: C = alpha * A(M,K) * B(N,K)^T (+beta*C) (+bias) (+gelu)
// GELU uses tanh-form (x*sigmoid(1.5958(x+0.044715x^3))), ~3e-4 abs err.
// ---------------------------------------------------------------------------
template<int BM, int BN, int WM, int WN, int OUTBF, int HASBIAS, int GELU, int BETA>
__global__ __launch_bounds__(256) void gemm_mfma(
    const ushort_t* __restrict__ A, int lda,
    const ushort_t* __restrict__ B, int ldb,
    void* __restrict__ Cv, int ldc,
    int K, float alpha,
    const float* __restrict__ bias,
    int bdiv, long sAb, long sAh, long sBb, long sBh, long sCb, long sCh)
{
    constexpr int BK = 32;
    constexpr int WTM = BM / WM;
    constexpr int WTN = BN / WN;
    constexpr int MF = WTM / 16, NF = WTN / 16;
    constexpr int ACH = (BM * BK * 2) / 1024;
    constexpr int BCH = (BN * BK * 2) / 1024;

    const int z = blockIdx.z;
    const int zb = z / bdiv, zh = z % bdiv;
    A += (long)zb * sAb + (long)zh * sAh;
    B += (long)zb * sBb + (long)zh * sBh;
    const long coff = (long)zb * sCb + (long)zh * sCh;

    __shared__ ushort_t As[BM * BK];
    __shared__ ushort_t Bs[BN * BK];

    const int tid = threadIdx.x;
    const int w = tid >> 6, lane = tid & 63;
    const int wr = w / WN, wc = w % WN;
    const int m0 = blockIdx.y * BM;
    const int n0 = blockIdx.x * BN;

    f32x4 acc[MF][NF] = {};

    const int fr = lane & 15;
    const int kb = lane >> 4;

    for (int k0 = 0; k0 < K; k0 += BK) {
#pragma unroll
        for (int q = 0; q < (ACH + 3) / 4; ++q) {
            int ci = q * 4 + w;
            if (ci < ACH) {
                int e = ci * 512 + lane * 8;
                int r = e >> 5, c = e & 31;
                GLDS(A + (long)(m0 + r) * lda + (k0 + c), (char*)As + ci * 1024);
            }
        }
#pragma unroll
        for (int q = 0; q < (BCH + 3) / 4; ++q) {
            int ci = q * 4 + w;
            if (ci < BCH) {
                int e = ci * 512 + lane * 8;
                int r = e >> 5, c = e & 31;
                GLDS(B + (long)(n0 + r) * ldb + (k0 + c), (char*)Bs + ci * 1024);
            }
        }
        __syncthreads();

        short8 af[MF], bfr[NF];
#pragma unroll
        for (int fm = 0; fm < MF; ++fm)
            af[fm] = *(const short8*)&As[(wr * WTM + fm * 16 + fr) * 32 + kb * 8];
#pragma unroll
        for (int fn = 0; fn < NF; ++fn)
            bfr[fn] = *(const short8*)&Bs[(wc * WTN + fn * 16 + fr) * 32 + kb * 8];
#pragma unroll
        for (int fm = 0; fm < MF; ++fm)
#pragma unroll
            for (int fn = 0; fn < NF; ++fn)
                acc[fm][fn] = __builtin_amdgcn_mfma_f32_16x16x32_bf16(
                    af[fm], bfr[fn], acc[fm][fn], 0, 0, 0);
        __syncthreads();
    }

    const int cr = lane >> 4;
    const int cc = lane & 15;
#pragma unroll
    for (int fm = 0; fm < MF; ++fm) {
#pragma unroll
        for (int fn = 0; fn < NF; ++fn) {
#pragma unroll
            for (int j = 0; j < 4; ++j) {
                int gm = m0 + wr * WTM + fm * 16 + cr * 4 + j;
                int gn = n0 + wc * WTN + fn * 16 + cc;
                float v = alpha * acc[fm][fn][j];
                if (HASBIAS) v += bias[gn];
                if (GELU) {
                    float zz = 1.5957691216f * fmaf(0.044715f * v * v, v, v);
                    v = v / (1.f + __expf(-zz));
                }
                long idx = coff + (long)gm * ldc + gn;
                if (BETA) v += ((const float*)Cv)[idx];
                if (OUTBF) ((ushort_t*)Cv)[idx] = f2b(v);
                else       ((float*)Cv)[idx] = v;
            }
        }
    }
}

// ---------------------------------------------------------------------------
// kqv GEMM with scatter epilogue: A = xb (B*T*H, 96), B = Wkqv (288, 96).
// Writes K -> Kh[..,loff+n], Q*scale -> Qh[..,loff+n], V -> Vt[(bh,s),t].
// ---------------------------------------------------------------------------
__global__ __launch_bounds__(256) void kqv_gemm(
    const ushort_t* __restrict__ A,       // xb, lda 96
    const ushort_t* __restrict__ Bw,      // Wkqvb, ldb 96
    ushort_t* __restrict__ Kh, ushort_t* __restrict__ Qh,
    ushort_t* __restrict__ Vt, int loff, float scale)
{
    constexpr int BM = 128, BN = 96, BK = 32;
    __shared__ ushort_t As[BM * BK];
    __shared__ ushort_t Bs[BN * BK];

    const int tid = threadIdx.x;
    const int w = tid >> 6, lane = tid & 63;
    const int m0 = blockIdx.y * BM;
    const int n0 = blockIdx.x * BN;

    f32x4 acc[2][6] = {};
    const int fr = lane & 15;
    const int kb = lane >> 4;

    for (int k0 = 0; k0 < 96; k0 += BK) {
#pragma unroll
        for (int q = 0; q < 2; ++q) {
            int ci = q * 4 + w;
            int e = ci * 512 + lane * 8;
            int r = e >> 5, c = e & 31;
            GLDS(A + (long)(m0 + r) * ESS + (k0 + c), (char*)As + ci * 1024);
        }
        {
            int ci = w;
            int e = ci * 512 + lane * 8;
            int r = e >> 5, c = e & 31;
            GLDS(Bw + (long)(n0 + r) * ESS + (k0 + c), (char*)Bs + ci * 1024);
            if (w < 2) {
                int ci2 = 4 + w;
                int e2 = ci2 * 512 + lane * 8;
                int r2 = e2 >> 5, c2 = e2 & 31;
                GLDS(Bw + (long)(n0 + r2) * ESS + (k0 + c2), (char*)Bs + ci2 * 1024);
            }
        }
        __syncthreads();

        short8 af[2], bfr[6];
#pragma unroll
        for (int fm = 0; fm < 2; ++fm)
            af[fm] = *(const short8*)&As[(w * 32 + fm * 16 + fr) * 32 + kb * 8];
#pragma unroll
        for (int fn = 0; fn < 6; ++fn)
            bfr[fn] = *(const short8*)&Bs[(fn * 16 + fr) * 32 + kb * 8];
#pragma unroll
        for (int fm = 0; fm < 2; ++fm)
#pragma unroll
            for (int fn = 0; fn < 6; ++fn)
                acc[fm][fn] = __builtin_amdgcn_mfma_f32_16x16x32_bf16(
                    af[fm], bfr[fn], acc[fm][fn], 0, 0, 0);
        __syncthreads();
    }

    const int cr = lane >> 4;
    const int cc = lane & 15;
    const int kind = blockIdx.x;      // 0 = K, 1 = Q, 2 = V
#pragma unroll
    for (int fm = 0; fm < 2; ++fm) {
#pragma unroll
        for (int fn = 0; fn < 6; ++fn) {
#pragma unroll
            for (int j = 0; j < 4; ++j) {
                int gm = m0 + w * 32 + fm * 16 + cr * 4 + j;
                int s = fn * 16 + cc;
                float v = acc[fm][fn][j];
                int h = gm & 7;
                int bt = gm >> 3;
                int t = bt & 511, b = bt >> 9;
                int bh = b * HH + h;
                if (kind == 0)
                    Kh[((long)(bh * TT + t)) * KHMAX + loff + s] = f2b(v);
                else if (kind == 1)
                    Qh[((long)(bh * TT + t)) * KHMAX + loff + s] = f2b(v * scale);
                else
                    Vt[((long)(bh * ESS + s)) * TT + t] = f2b(v);
            }
        }
    }
}

// ---------------------------------------------------------------------------
// Fused attention with Q/K-history accumulation (RealFormer carry).
// 64 Q-rows per block, 8 waves (512 thr), 512 blocks: K-tile staging is
// amortized over 2x rows and V staged once per 64 rows (halves per-CU
// staging volume vs the 32-row version). 2 blocks/CU x 8 waves = 16
// waves/CU (same as before). LDS 70KB (gfx950 allows >64KB static).
// Scale pre-folded into Qh.
// ---------------------------------------------------------------------------
__global__ __launch_bounds__(512) void fused_attn(
    const ushort_t* __restrict__ Qh,    // (B*H, T, 576) bf16, cols [0,Kd)
    const ushort_t* __restrict__ Kh,    // (B*H, T, 576) bf16
    const ushort_t* __restrict__ Vt,    // (B*H, 96, T) bf16
    ushort_t* __restrict__ attn,        // (B,T,EMB) bf16
    int Kd)
{
    __shared__ char lds[71680];
    ushort_t* Pt = (ushort_t*)lds;              // 64 KiB: P 64x512 bf16 (swizzled)
    ushort_t* Bs = (ushort_t*)lds;              // union: K tile 512x32 (32 KiB)
    ushort_t* As = (ushort_t*)(lds + 32768);    // union: Q tile 64x32 (4 KiB)
    ushort_t* Vs = (ushort_t*)(lds + 65536);    // 6 KiB: V^T chunk 96x32 (phase 3)
    float* red   = (float*)(lds + 65536);       // 1 KiB (union w/ Vs, barrier-ordered)
    float* red2  = (float*)(lds + 66560);       // 1 KiB

    // XCD swizzle: hw xcd = wg & 7 (round-robin)
    const int wg = blockIdx.x;
    const int xcd = wg & 7;
    const int sub = wg >> 3;          // 0..63, sequential within an XCD
    const int m0 = (sub & 7) * 64;    // m-tile fastest -> same bh consecutive
    const int bh = (sub >> 3) * 8 + xcd;
    const int b = bh >> 3, h = bh & 7;

    const int tid = threadIdx.x;
    const int w = tid >> 6, lane = tid & 63;
    const int g = w >> 2;             // row group: 0 = rows m0..31, 1 = +32..63
    const int wg4 = w & 3;            // role within group
    const int fr = lane & 15, kb = lane >> 4;
    const int cr = kb, cc = fr;

    f32x4 acc[2][8] = {};

    // ---- phase 1: S = Q_hist K_hist^T over Kd feature cols ----
    for (int k0 = 0; k0 < Kd; k0 += 32) {
        if (w < 4) {                  // Q tile 64x32 = 4 chunks
            int e = w * 512 + lane * 8;
            int r = e >> 5, c = e & 31;
            GLDS(Qh + ((long)(bh * TT + m0 + r)) * KHMAX + k0 + c,
                 (char*)As + w * 1024);
        }
#pragma unroll
        for (int q = 0; q < 4; ++q) { // K tile 512x32 = 32 chunks, 4 per wave
            int ci = q * 8 + w;
            int e = ci * 512 + lane * 8;
            int r = e >> 5, c = e & 31;
            GLDS(Kh + ((long)(bh * TT + r)) * KHMAX + k0 + c,
                 (char*)Bs + ci * 1024);
        }
        __syncthreads();
        short8 af0 = *(const short8*)&As[(g * 32 + fr) * 32 + kb * 8];
        short8 af1 = *(const short8*)&As[(g * 32 + 16 + fr) * 32 + kb * 8];
#pragma unroll
        for (int fn = 0; fn < 8; ++fn) {
            short8 bf = *(const short8*)&Bs[(wg4 * 128 + fn * 16 + fr) * 32 + kb * 8];
            acc[0][fn] = __builtin_amdgcn_mfma_f32_16x16x32_bf16(af0, bf, acc[0][fn], 0, 0, 0);
            acc[1][fn] = __builtin_amdgcn_mfma_f32_16x16x32_bf16(af1, bf, acc[1][fn], 0, 0, 0);
        }
        __syncthreads();
    }

    // ---- phase 2: softmax over key axis (per 32-row group) ----
#pragma unroll
    for (int fm = 0; fm < 2; ++fm)
#pragma unroll
        for (int j = 0; j < 4; ++j) {
            float mx = -1e30f;
#pragma unroll
            for (int fn = 0; fn < 8; ++fn) mx = fmaxf(mx, acc[fm][fn][j]);
            for (int o = 1; o <= 8; o <<= 1) mx = fmaxf(mx, __shfl_xor(mx, o));
            if (cc == 0) red[g * 128 + wg4 * 32 + fm * 16 + cr * 4 + j] = mx;
        }
    __syncthreads();

    float inv[2][4];
#pragma unroll
    for (int fm = 0; fm < 2; ++fm)
#pragma unroll
        for (int j = 0; j < 4; ++j) {
            int r = fm * 16 + cr * 4 + j;
            const float* rg = red + g * 128;
            float mx = fmaxf(fmaxf(rg[r], rg[32 + r]), fmaxf(rg[64 + r], rg[96 + r]));
            float s = 0.f;
#pragma unroll
            for (int fn = 0; fn < 8; ++fn) {
                float e = __expf(acc[fm][fn][j] - mx);
                acc[fm][fn][j] = e;
                s += e;
            }
            for (int o = 1; o <= 8; o <<= 1) s += __shfl_xor(s, o);
            if (cc == 0) red2[g * 128 + wg4 * 32 + r] = s;
        }
    __syncthreads();
#pragma unroll
    for (int fm = 0; fm < 2; ++fm)
#pragma unroll
        for (int j = 0; j < 4; ++j) {
            int r = fm * 16 + cr * 4 + j;
            const float* rg = red2 + g * 128;
            inv[fm][j] = 1.f / (rg[r] + rg[32 + r] + rg[64 + r] + rg[96 + r]);
        }
    __syncthreads();   // red2 fully read before Pt overwrites the Bs/As union

    // write P (bf16) into swizzled LDS tile (elem col ^= (row&7)<<3)
#pragma unroll
    for (int fm = 0; fm < 2; ++fm)
#pragma unroll
        for (int fn = 0; fn < 8; ++fn)
#pragma unroll
            for (int j = 0; j < 4; ++j) {
                int row = g * 32 + fm * 16 + cr * 4 + j;
                int col = wg4 * 128 + fn * 16 + cc;
                Pt[row * 512 + (col ^ ((row & 7) << 3))] = f2b(acc[fm][fn][j] * inv[fm][j]);
            }
    __syncthreads();

    // ---- phase 3: attn = P @ V (LDS-staged V^T chunks) ----
    const int wr = w >> 1, wc2 = w & 1;   // wr 0..3: 16-row slices of 64
    f32x4 po[3] = {};
    for (int j0 = 0; j0 < TT; j0 += 32) {
        if (w < 6) {                  // V^T chunk 96x32 = 6 chunks
            int e = w * 512 + lane * 8;
            int r = e >> 5, c = e & 31;
            GLDS(Vt + ((long)(bh * ESS + r)) * TT + j0 + c, (char*)Vs + w * 1024);
        }
        __syncthreads();
        int prow = wr * 16 + fr;
        short8 pa = *(const short8*)&Pt[prow * 512 + ((j0 + kb * 8) ^ ((prow & 7) << 3))];
#pragma unroll
        for (int fn = 0; fn < 3; ++fn) {
            short8 vb = *(const short8*)&Vs[(wc2 * 48 + fn * 16 + fr) * 32 + kb * 8];
            po[fn] = __builtin_amdgcn_mfma_f32_16x16x32_bf16(pa, vb, po[fn], 0, 0, 0);
        }
        __syncthreads();
    }

#pragma unroll
    for (int fn = 0; fn < 3; ++fn)
#pragma unroll
        for (int j = 0; j < 4; ++j) {
            int grow = m0 + wr * 16 + cr * 4 + j;
            int gcol = h * ESS + wc2 * 48 + fn * 16 + cc;
            attn[((long)(b * TT + grow)) * EMBD + gcol] = f2b(po[fn][j]);
        }
}

// ---------------------------------------------------------------------------
__global__ __launch_bounds__(256) void cvt_f2b(
    const float* __restrict__ in, ushort_t* __restrict__ out)
{
    const int i = blockIdx.x * 256 + threadIdx.x;
    float4 v = ((const float4*)in)[i];
    ushort4v o = {f2b(v.x), f2b(v.y), f2b(v.z), f2b(v.w)};
    ((ushort4v*)out)[i] = o;
}

// ---------------------------------------------------------------------------
// Weight conversion. Per-layer contiguous layout (float4/ushort4v units):
//   [wkqv 6912 | wproj 147456 | w1 589824 | w2 589824] = 1334016 per layer
// ---------------------------------------------------------------------------
static __device__ __forceinline__ void cvt_w_one(
    int r, int layer,
    const float* Wkqv, const float* Wproj, const float* w1, const float* w2,
    ushort_t* dst_layer)
{
    const float* src; int base;
    if (r < 6912)        { src = Wkqv  + (long)layer * 27648;   base = 0; }
    else if (r < 154368) { src = Wproj + (long)layer * 589824;  base = 6912; }
    else if (r < 744192) { src = w1    + (long)layer * 2359296; base = 154368; }
    else                 { src = w2    + (long)layer * 2359296; base = 744192; }
    int j = r - base;
    float4 v = ((const float4*)src)[j];
    ushort4v o = {f2b(v.x), f2b(v.y), f2b(v.z), f2b(v.w)};
    ((ushort4v*)dst_layer)[r] = o;
}

__global__ __launch_bounds__(256) void cvt_weights_all(
    const float* __restrict__ Wkqv, const float* __restrict__ Wproj,
    const float* __restrict__ w1, const float* __restrict__ w2,
    ushort_t* __restrict__ dst)      // 6 layers, stride 5336064 ushorts
{
    int i4 = blockIdx.x * 256 + threadIdx.x;    // 0 .. 8004095
    int layer = i4 / 1334016;
    int r = i4 - layer * 1334016;
    cvt_w_one(r, layer, Wkqv, Wproj, w1, w2, dst + (long)layer * 5336064);
}

__global__ __launch_bounds__(256) void cvt_weights_layer(
    const float* __restrict__ Wkqv, const float* __restrict__ Wproj,
    const float* __restrict__ w1, const float* __restrict__ w2,
    ushort_t* __restrict__ dst, int layer)      // one layer into dst
{
    int r = blockIdx.x * 256 + threadIdx.x;     // 0 .. 1334015
    cvt_w_one(r, layer, Wkqv, Wproj, w1, w2, dst);
}

// ---------------------------------------------------------------------------
// Residual stream lives in bf16 (xio). LN computes in fp32:
//   xnew = LayerNorm(xio + sum_{i<NR} res_i (+bias)) * g + b -> bf16 xio
// FINAL variant also writes fp32 to xf (the harness output buffer).
// ---------------------------------------------------------------------------
template<int NR, int FINAL>
__global__ __launch_bounds__(192) void add_ln(
    ushort_t* __restrict__ xio, const ushort_t* __restrict__ res, long rstride,
    const float* __restrict__ bias,
    const float* __restrict__ g, const float* __restrict__ bta,
    float* __restrict__ xf)
{
    const long row = blockIdx.x;
    ushort4v* xr = (ushort4v*)(xio + row * EMBD);
    __shared__ float sh[4];
    const int tid = threadIdx.x;
    const int lane = tid & 63, w = tid >> 6;

    ushort4v xu = xr[tid];
    float v[4] = {b2f(xu.x), b2f(xu.y), b2f(xu.z), b2f(xu.w)};
#pragma unroll
    for (int p = 0; p < NR; ++p) {
        ushort4v u = ((const ushort4v*)(res + p * rstride + row * EMBD))[tid];
        v[0] += b2f(u.x); v[1] += b2f(u.y); v[2] += b2f(u.z); v[3] += b2f(u.w);
    }
    if (bias) {
        float4 b4 = ((const float4*)bias)[tid];
        v[0] += b4.x; v[1] += b4.y; v[2] += b4.z; v[3] += b4.w;
    }
    float s = v[0] + v[1] + v[2] + v[3];
    for (int o = 32; o; o >>= 1) s += __shfl_xor(s, o);
    if (lane == 0) sh[w] = s;
    __syncthreads();
    float mu = (sh[0] + sh[1] + sh[2]) * (1.f / EMBD);

    float var = 0.f;
#pragma unroll
    for (int c = 0; c < 4; ++c) { float d = v[c] - mu; var += d * d; }
    for (int o = 32; o; o >>= 1) var += __shfl_xor(var, o);
    __syncthreads();
    if (lane == 0) sh[w] = var;
    __syncthreads();
    var = (sh[0] + sh[1] + sh[2]) * (1.f / EMBD);
    float rstd = rsqrtf(var + 1e-5f);

    const float4 g4 = ((const float4*)g)[tid];
    const float4 b4 = ((const float4*)bta)[tid];
    float o0 = (v[0] - mu) * rstd * g4.x + b4.x;
    float o1 = (v[1] - mu) * rstd * g4.y + b4.y;
    float o2 = (v[2] - mu) * rstd * g4.z + b4.z;
    float o3 = (v[3] - mu) * rstd * g4.w + b4.w;
    ushort4v ob = {f2b(o0), f2b(o1), f2b(o2), f2b(o3)};
    xr[tid] = ob;
    if (FINAL) {
        float4 ov = {o0, o1, o2, o3};
        ((float4*)(xf + row * EMBD))[tid] = ov;
    }
}

// ---------------------------------------------------------------------------
extern "C" void kernel_launch(void* const* d_in, const int* in_sizes, int n_in,
                              void* d_out, int out_size, void* d_ws, size_t ws_size,
                              hipStream_t stream) {
    const float* x_in  = (const float*)d_in[0];
    const float* Wkqv  = (const float*)d_in[1];
    const float* Wproj = (const float*)d_in[2];
    const float* ln1_g = (const float*)d_in[3];
    const float* ln1_b = (const float*)d_in[4];
    const float* ln2_g = (const float*)d_in[5];
    const float* ln2_b = (const float*)d_in[6];
    const float* ff_w1 = (const float*)d_in[7];
    const float* ff_b1 = (const float*)d_in[8];
    const float* ff_w2 = (const float*)d_in[9];
    const float* ff_b2 = (const float*)d_in[10];

    float* xout = (float*)d_out;                          // written by final LN only
    char* ws = (char*)d_ws;
    ushort_t* Qh     = (ushort_t*)(ws);                   // 37.7 MB
    ushort_t* Kh     = (ushort_t*)(ws + 37748736);        // 37.7 MB
    ushort_t* Vtb    = (ushort_t*)(ws + 75497472);        // 6.3 MB (union res0)
    ushort_t* resb   = (ushort_t*)(ws + 75497472);        // 4 x 6.3 MB bf16 partials
    ushort_t* h1b    = (ushort_t*)(ws + 100663296);       // 25.2 MB
    ushort_t* xb     = (ushort_t*)(ws + 125829120);       // 6.3 MB bf16 residual stream
    ushort_t* attnb  = (ushort_t*)(ws + 132120576);       // 6.3 MB
    ushort_t* Wall   = (ushort_t*)(ws + 138412032);
    const size_t WLAYER_B = 10672128;          // bytes per layer slot
    const int    WLAYER_E = 5336064;           // ushorts per layer slot
    const int big = (ws_size >= 138412032 + 6 * WLAYER_B) ? 1 : 0;
    const long RES_STRIDE = 3145728;           // partial stride in elements (6.3 MB)

    cvt_f2b<<<3072, 256, 0, stream>>>(x_in, xb);
    if (big)
        cvt_weights_all<<<31266, 256, 0, stream>>>(Wkqv, Wproj, ff_w1, ff_w2, Wall);

    const float scale = 0.10206207261596577f;  // 1/sqrt(96)

    for (int l = 0; l < NLAYER; ++l) {
        const float* b1 = ff_b1 + (size_t)l * FFD;
        const float* b2 = ff_b2 + (size_t)l * EMBD;

        ushort_t* Wl = Wall + (big ? (long)l * WLAYER_E : 0);
        if (!big)
            cvt_weights_layer<<<5211, 256, 0, stream>>>(Wkqv, Wproj, ff_w1, ff_w2, Wl, l);
        ushort_t* Wkqvb  = Wl;
        ushort_t* Wprojb = Wl + 27648;
        ushort_t* W1b    = Wl + 617472;
        ushort_t* W2b    = Wl + 2976768;

        // kqv GEMM with direct scatter epilogue: K,Q(scaled) -> history, V -> Vt
        kqv_gemm<<<dim3(3, 256, 1), 256, 0, stream>>>(
            xb, Wkqvb, Kh, Qh, Vtb, l * ESS, scale);

        // fused: S = Qh Kh^T (scale pre-folded, Kd=96*(l+1)); attn = softmax @ V
        fused_attn<<<512, 512, 0, stream>>>(
            Qh, Kh, Vtb, attnb, ESS * (l + 1));

        // res partials (bf16) = attn @ Wproj^T split-K2 (Vtb dead)
        gemm_mfma<128, 128, 2, 2, 1, 0, 0, 0><<<dim3(6, 32, 2), 256, 0, stream>>>(
            attnb, EMBD, Wprojb, EMBD, resb, EMBD, EMBD / 2, 1.f, nullptr,
            1, 384, 0, 384, 0, RES_STRIDE, 0);

        add_ln<2, 0><<<BB * TT, 192, 0, stream>>>(xb, resb, RES_STRIDE, nullptr,
            ln1_g + (size_t)l * EMBD, ln1_b + (size_t)l * EMBD, nullptr);

        // h1 = gelu(xb @ W1^T + b1), fast-gelu epilogue
        gemm_mfma<128, 128, 2, 2, 1, 1, 1, 0><<<dim3(24, 32, 1), 256, 0, stream>>>(
            xb, EMBD, W1b, EMBD, h1b, FFD, EMBD, 1.f, b1,
            1, 0, 0, 0, 0, 0, 0);

        // res partials (bf16) = h1 @ W2^T split-K4 (b2 applied in ln2)
        gemm_mfma<128, 128, 2, 2, 1, 0, 0, 0><<<dim3(6, 32, 4), 256, 0, stream>>>(
            h1b, FFD, W2b, FFD, resb, EMBD, FFD / 4, 1.f, nullptr,
            1, 768, 0, 768, 0, RES_STRIDE, 0);

        if (l == NLAYER - 1)
            add_ln<4, 1><<<BB * TT, 192, 0, stream>>>(xb, resb, RES_STRIDE, b2,
                ln2_g + (size_t)l * EMBD, ln2_b + (size_t)l * EMBD, xout);
        else
            add_ln<4, 0><<<BB * TT, 192, 0, stream>>>(xb, resb, RES_STRIDE, b2,
                ln2_g + (size_t)l * EMBD, ln2_b + (size_t)l * EMBD, nullptr);
    }
}

// Round 17
// 948.390 us; speedup vs baseline: 1.3390x; 1.0011x over previous
//
#include <hip/hip_runtime.h>
#include <math.h>

#define BB 8
#define TT 512
#define HH 8
#define ESS 96
#define EMBD 768
#define FFD 3072
#define NLAYER 6
#define KHMAX 576   // 96 * 6, history feature pitch

typedef unsigned short ushort_t;
typedef __attribute__((ext_vector_type(8))) short short8;
typedef __attribute__((ext_vector_type(4))) float f32x4;
typedef __attribute__((ext_vector_type(4))) unsigned short ushort4v;

static __device__ __forceinline__ ushort_t f2b(float f) {
    unsigned u = __builtin_bit_cast(unsigned, f);
    unsigned r = (u + 0x7fffu + ((u >> 16) & 1u)) >> 16;
    return (ushort_t)r;
}
static __device__ __forceinline__ float b2f(ushort_t u) {
    return __builtin_bit_cast(float, ((unsigned)u) << 16);
}

#define GLDS(gp, lp) __builtin_amdgcn_global_load_lds( \
    (const __attribute__((address_space(1))) void*)(gp), \
    (__attribute__((address_space(3))) void*)(lp), 16, 0, 0)

// ---------------------------------------------------------------------------
// bf16 MFMA GEMM: C = alpha * A(M,K) * B(N,K)^T (+beta*C) (+bias) (+gelu)
// GELU uses tanh-form (x*sigmoid(1.5958(x+0.044715x^3))), ~3e-4 abs err.
// ---------------------------------------------------------------------------
template<int BM, int BN, int WM, int WN, int OUTBF, int HASBIAS, int GELU, int BETA>
__global__ __launch_bounds__(256) void gemm_mfma(
    const ushort_t* __restrict__ A, int lda,
    const ushort_t* __restrict__ B, int ldb,
    void* __restrict__ Cv, int ldc,
    int K, float alpha,
    const float* __restrict__ bias,
    int bdiv, long sAb, long sAh, long sBb, long sBh, long sCb, long sCh)
{
    constexpr int BK = 32;
    constexpr int WTM = BM / WM;
    constexpr int WTN = BN / WN;
    constexpr int MF = WTM / 16, NF = WTN / 16;
    constexpr int ACH = (BM * BK * 2) / 1024;
    constexpr int BCH = (BN * BK * 2) / 1024;

    const int z = blockIdx.z;
    const int zb = z / bdiv, zh = z % bdiv;
    A += (long)zb * sAb + (long)zh * sAh;
    B += (long)zb * sBb + (long)zh * sBh;
    const long coff = (long)zb * sCb + (long)zh * sCh;

    __shared__ ushort_t As[BM * BK];
    __shared__ ushort_t Bs[BN * BK];

    const int tid = threadIdx.x;
    const int w = tid >> 6, lane = tid & 63;
    const int wr = w / WN, wc = w % WN;
    const int m0 = blockIdx.y * BM;
    const int n0 = blockIdx.x * BN;

    f32x4 acc[MF][NF] = {};

    const int fr = lane & 15;
    const int kb = lane >> 4;

    for (int k0 = 0; k0 < K; k0 += BK) {
#pragma unroll
        for (int q = 0; q < (ACH + 3) / 4; ++q) {
            int ci = q * 4 + w;
            if (ci < ACH) {
                int e = ci * 512 + lane * 8;
                int r = e >> 5, c = e & 31;
                GLDS(A + (long)(m0 + r) * lda + (k0 + c), (char*)As + ci * 1024);
            }
        }
#pragma unroll
        for (int q = 0; q < (BCH + 3) / 4; ++q) {
            int ci = q * 4 + w;
            if (ci < BCH) {
                int e = ci * 512 + lane * 8;
                int r = e >> 5, c = e & 31;
                GLDS(B + (long)(n0 + r) * ldb + (k0 + c), (char*)Bs + ci * 1024);
            }
        }
        __syncthreads();

        short8 af[MF], bfr[NF];
#pragma unroll
        for (int fm = 0; fm < MF; ++fm)
            af[fm] = *(const short8*)&As[(wr * WTM + fm * 16 + fr) * 32 + kb * 8];
#pragma unroll
        for (int fn = 0; fn < NF; ++fn)
            bfr[fn] = *(const short8*)&Bs[(wc * WTN + fn * 16 + fr) * 32 + kb * 8];
#pragma unroll
        for (int fm = 0; fm < MF; ++fm)
#pragma unroll
            for (int fn = 0; fn < NF; ++fn)
                acc[fm][fn] = __builtin_amdgcn_mfma_f32_16x16x32_bf16(
                    af[fm], bfr[fn], acc[fm][fn], 0, 0, 0);
        __syncthreads();
    }

    const int cr = lane >> 4;
    const int cc = lane & 15;
#pragma unroll
    for (int fm = 0; fm < MF; ++fm) {
#pragma unroll
        for (int fn = 0; fn < NF; ++fn) {
#pragma unroll
            for (int j = 0; j < 4; ++j) {
                int gm = m0 + wr * WTM + fm * 16 + cr * 4 + j;
                int gn = n0 + wc * WTN + fn * 16 + cc;
                float v = alpha * acc[fm][fn][j];
                if (HASBIAS) v += bias[gn];
                if (GELU) {
                    float zz = 1.5957691216f * fmaf(0.044715f * v * v, v, v);
                    v = v / (1.f + __expf(-zz));
                }
                long idx = coff + (long)gm * ldc + gn;
                if (BETA) v += ((const float*)Cv)[idx];
                if (OUTBF) ((ushort_t*)Cv)[idx] = f2b(v);
                else       ((float*)Cv)[idx] = v;
            }
        }
    }
}

// ---------------------------------------------------------------------------
// kqv GEMM with scatter epilogue: A = xb (B*T*H, 96), B = Wkqv (288, 96).
// Writes K -> Kh[..,loff+n], Q*scale -> Qh[..,loff+n], V -> Vt[(bh,s),t].
// ---------------------------------------------------------------------------
__global__ __launch_bounds__(256) void kqv_gemm(
    const ushort_t* __restrict__ A,       // xb, lda 96
    const ushort_t* __restrict__ Bw,      // Wkqvb, ldb 96
    ushort_t* __restrict__ Kh, ushort_t* __restrict__ Qh,
    ushort_t* __restrict__ Vt, int loff, float scale)
{
    constexpr int BM = 128, BN = 96, BK = 32;
    __shared__ ushort_t As[BM * BK];
    __shared__ ushort_t Bs[BN * BK];

    const int tid = threadIdx.x;
    const int w = tid >> 6, lane = tid & 63;
    const int m0 = blockIdx.y * BM;
    const int n0 = blockIdx.x * BN;

    f32x4 acc[2][6] = {};
    const int fr = lane & 15;
    const int kb = lane >> 4;

    for (int k0 = 0; k0 < 96; k0 += BK) {
#pragma unroll
        for (int q = 0; q < 2; ++q) {
            int ci = q * 4 + w;
            int e = ci * 512 + lane * 8;
            int r = e >> 5, c = e & 31;
            GLDS(A + (long)(m0 + r) * ESS + (k0 + c), (char*)As + ci * 1024);
        }
        {
            int ci = w;
            int e = ci * 512 + lane * 8;
            int r = e >> 5, c = e & 31;
            GLDS(Bw + (long)(n0 + r) * ESS + (k0 + c), (char*)Bs + ci * 1024);
            if (w < 2) {
                int ci2 = 4 + w;
                int e2 = ci2 * 512 + lane * 8;
                int r2 = e2 >> 5, c2 = e2 & 31;
                GLDS(Bw + (long)(n0 + r2) * ESS + (k0 + c2), (char*)Bs + ci2 * 1024);
            }
        }
        __syncthreads();

        short8 af[2], bfr[6];
#pragma unroll
        for (int fm = 0; fm < 2; ++fm)
            af[fm] = *(const short8*)&As[(w * 32 + fm * 16 + fr) * 32 + kb * 8];
#pragma unroll
        for (int fn = 0; fn < 6; ++fn)
            bfr[fn] = *(const short8*)&Bs[(fn * 16 + fr) * 32 + kb * 8];
#pragma unroll
        for (int fm = 0; fm < 2; ++fm)
#pragma unroll
            for (int fn = 0; fn < 6; ++fn)
                acc[fm][fn] = __builtin_amdgcn_mfma_f32_16x16x32_bf16(
                    af[fm], bfr[fn], acc[fm][fn], 0, 0, 0);
        __syncthreads();
    }

    const int cr = lane >> 4;
    const int cc = lane & 15;
    const int kind = blockIdx.x;      // 0 = K, 1 = Q, 2 = V
#pragma unroll
    for (int fm = 0; fm < 2; ++fm) {
#pragma unroll
        for (int fn = 0; fn < 6; ++fn) {
#pragma unroll
            for (int j = 0; j < 4; ++j) {
                int gm = m0 + w * 32 + fm * 16 + cr * 4 + j;
                int s = fn * 16 + cc;
                float v = acc[fm][fn][j];
                int h = gm & 7;
                int bt = gm >> 3;
                int t = bt & 511, b = bt >> 9;
                int bh = b * HH + h;
                if (kind == 0)
                    Kh[((long)(bh * TT + t)) * KHMAX + loff + s] = f2b(v);
                else if (kind == 1)
                    Qh[((long)(bh * TT + t)) * KHMAX + loff + s] = f2b(v * scale);
                else
                    Vt[((long)(bh * ESS + s)) * TT + t] = f2b(v);
            }
        }
    }
}

// ---------------------------------------------------------------------------
// Fused attention with Q/K-history accumulation (RealFormer carry).
// 64 Q-rows per block, 8 waves (512 thr), 512 blocks: K-tile staging is
// amortized over 2x rows and V staged once per 64 rows (halves per-CU
// staging volume vs the 32-row version). 2 blocks/CU x 8 waves = 16
// waves/CU (same as before). LDS 70KB (gfx950 allows >64KB static).
// Scale pre-folded into Qh.
// ---------------------------------------------------------------------------
__global__ __launch_bounds__(512) void fused_attn(
    const ushort_t* __restrict__ Qh,    // (B*H, T, 576) bf16, cols [0,Kd)
    const ushort_t* __restrict__ Kh,    // (B*H, T, 576) bf16
    const ushort_t* __restrict__ Vt,    // (B*H, 96, T) bf16
    ushort_t* __restrict__ attn,        // (B,T,EMB) bf16
    int Kd)
{
    __shared__ char lds[71680];
    ushort_t* Pt = (ushort_t*)lds;              // 64 KiB: P 64x512 bf16 (swizzled)
    ushort_t* Bs = (ushort_t*)lds;              // union: K tile 512x32 (32 KiB)
    ushort_t* As = (ushort_t*)(lds + 32768);    // union: Q tile 64x32 (4 KiB)
    ushort_t* Vs = (ushort_t*)(lds + 65536);    // 6 KiB: V^T chunk 96x32 (phase 3)
    float* red   = (float*)(lds + 65536);       // 1 KiB (union w/ Vs, barrier-ordered)
    float* red2  = (float*)(lds + 66560);       // 1 KiB

    // XCD swizzle: hw xcd = wg & 7 (round-robin)
    const int wg = blockIdx.x;
    const int xcd = wg & 7;
    const int sub = wg >> 3;          // 0..63, sequential within an XCD
    const int m0 = (sub & 7) * 64;    // m-tile fastest -> same bh consecutive
    const int bh = (sub >> 3) * 8 + xcd;
    const int b = bh >> 3, h = bh & 7;

    const int tid = threadIdx.x;
    const int w = tid >> 6, lane = tid & 63;
    const int g = w >> 2;             // row group: 0 = rows m0..31, 1 = +32..63
    const int wg4 = w & 3;            // role within group
    const int fr = lane & 15, kb = lane >> 4;
    const int cr = kb, cc = fr;

    f32x4 acc[2][8] = {};

    // ---- phase 1: S = Q_hist K_hist^T over Kd feature cols ----
    for (int k0 = 0; k0 < Kd; k0 += 32) {
        if (w < 4) {                  // Q tile 64x32 = 4 chunks
            int e = w * 512 + lane * 8;
            int r = e >> 5, c = e & 31;
            GLDS(Qh + ((long)(bh * TT + m0 + r)) * KHMAX + k0 + c,
                 (char*)As + w * 1024);
        }
#pragma unroll
        for (int q = 0; q < 4; ++q) { // K tile 512x32 = 32 chunks, 4 per wave
            int ci = q * 8 + w;
            int e = ci * 512 + lane * 8;
            int r = e >> 5, c = e & 31;
            GLDS(Kh + ((long)(bh * TT + r)) * KHMAX + k0 + c,
                 (char*)Bs + ci * 1024);
        }
        __syncthreads();
        short8 af0 = *(const short8*)&As[(g * 32 + fr) * 32 + kb * 8];
        short8 af1 = *(const short8*)&As[(g * 32 + 16 + fr) * 32 + kb * 8];
#pragma unroll
        for (int fn = 0; fn < 8; ++fn) {
            short8 bf = *(const short8*)&Bs[(wg4 * 128 + fn * 16 + fr) * 32 + kb * 8];
            acc[0][fn] = __builtin_amdgcn_mfma_f32_16x16x32_bf16(af0, bf, acc[0][fn], 0, 0, 0);
            acc[1][fn] = __builtin_amdgcn_mfma_f32_16x16x32_bf16(af1, bf, acc[1][fn], 0, 0, 0);
        }
        __syncthreads();
    }

    // ---- phase 2: softmax over key axis (per 32-row group) ----
#pragma unroll
    for (int fm = 0; fm < 2; ++fm)
#pragma unroll
        for (int j = 0; j < 4; ++j) {
            float mx = -1e30f;
#pragma unroll
            for (int fn = 0; fn < 8; ++fn) mx = fmaxf(mx, acc[fm][fn][j]);
            for (int o = 1; o <= 8; o <<= 1) mx = fmaxf(mx, __shfl_xor(mx, o));
            if (cc == 0) red[g * 128 + wg4 * 32 + fm * 16 + cr * 4 + j] = mx;
        }
    __syncthreads();

    float inv[2][4];
#pragma unroll
    for (int fm = 0; fm < 2; ++fm)
#pragma unroll
        for (int j = 0; j < 4; ++j) {
            int r = fm * 16 + cr * 4 + j;
            const float* rg = red + g * 128;
            float mx = fmaxf(fmaxf(rg[r], rg[32 + r]), fmaxf(rg[64 + r], rg[96 + r]));
            float s = 0.f;
#pragma unroll
            for (int fn = 0; fn < 8; ++fn) {
                float e = __expf(acc[fm][fn][j] - mx);
                acc[fm][fn][j] = e;
                s += e;
            }
            for (int o = 1; o <= 8; o <<= 1) s += __shfl_xor(s, o);
            if (cc == 0) red2[g * 128 + wg4 * 32 + r] = s;
        }
    __syncthreads();
#pragma unroll
    for (int fm = 0; fm < 2; ++fm)
#pragma unroll
        for (int j = 0; j < 4; ++j) {
            int r = fm * 16 + cr * 4 + j;
            const float* rg = red2 + g * 128;
            inv[fm][j] = 1.f / (rg[r] + rg[32 + r] + rg[64 + r] + rg[96 + r]);
        }
    __syncthreads();   // red2 fully read before Pt overwrites the Bs/As union

    // write P (bf16) into swizzled LDS tile (elem col ^= (row&7)<<3)
#pragma unroll
    for (int fm = 0; fm < 2; ++fm)
#pragma unroll
        for (int fn = 0; fn < 8; ++fn)
#pragma unroll
            for (int j = 0; j < 4; ++j) {
                int row = g * 32 + fm * 16 + cr * 4 + j;
                int col = wg4 * 128 + fn * 16 + cc;
                Pt[row * 512 + (col ^ ((row & 7) << 3))] = f2b(acc[fm][fn][j] * inv[fm][j]);
            }
    __syncthreads();

    // ---- phase 3: attn = P @ V (LDS-staged V^T chunks) ----
    const int wr = w >> 1, wc2 = w & 1;   // wr 0..3: 16-row slices of 64
    f32x4 po[3] = {};
    for (int j0 = 0; j0 < TT; j0 += 32) {
        if (w < 6) {                  // V^T chunk 96x32 = 6 chunks
            int e = w * 512 + lane * 8;
            int r = e >> 5, c = e & 31;
            GLDS(Vt + ((long)(bh * ESS + r)) * TT + j0 + c, (char*)Vs + w * 1024);
        }
        __syncthreads();
        int prow = wr * 16 + fr;
        short8 pa = *(const short8*)&Pt[prow * 512 + ((j0 + kb * 8) ^ ((prow & 7) << 3))];
#pragma unroll
        for (int fn = 0; fn < 3; ++fn) {
            short8 vb = *(const short8*)&Vs[(wc2 * 48 + fn * 16 + fr) * 32 + kb * 8];
            po[fn] = __builtin_amdgcn_mfma_f32_16x16x32_bf16(pa, vb, po[fn], 0, 0, 0);
        }
        __syncthreads();
    }

#pragma unroll
    for (int fn = 0; fn < 3; ++fn)
#pragma unroll
        for (int j = 0; j < 4; ++j) {
            int grow = m0 + wr * 16 + cr * 4 + j;
            int gcol = h * ESS + wc2 * 48 + fn * 16 + cc;
            attn[((long)(b * TT + grow)) * EMBD + gcol] = f2b(po[fn][j]);
        }
}

// ---------------------------------------------------------------------------
__global__ __launch_bounds__(256) void cvt_f2b(
    const float* __restrict__ in, ushort_t* __restrict__ out)
{
    const int i = blockIdx.x * 256 + threadIdx.x;
    float4 v = ((const float4*)in)[i];
    ushort4v o = {f2b(v.x), f2b(v.y), f2b(v.z), f2b(v.w)};
    ((ushort4v*)out)[i] = o;
}

// ---------------------------------------------------------------------------
// Weight conversion. Per-layer contiguous layout (float4/ushort4v units):
//   [wkqv 6912 | wproj 147456 | w1 589824 | w2 589824] = 1334016 per layer
// ---------------------------------------------------------------------------
static __device__ __forceinline__ void cvt_w_one(
    int r, int layer,
    const float* Wkqv, const float* Wproj, const float* w1, const float* w2,
    ushort_t* dst_layer)
{
    const float* src; int base;
    if (r < 6912)        { src = Wkqv  + (long)layer * 27648;   base = 0; }
    else if (r < 154368) { src = Wproj + (long)layer * 589824;  base = 6912; }
    else if (r < 744192) { src = w1    + (long)layer * 2359296; base = 154368; }
    else                 { src = w2    + (long)layer * 2359296; base = 744192; }
    int j = r - base;
    float4 v = ((const float4*)src)[j];
    ushort4v o = {f2b(v.x), f2b(v.y), f2b(v.z), f2b(v.w)};
    ((ushort4v*)dst_layer)[r] = o;
}

__global__ __launch_bounds__(256) void cvt_weights_all(
    const float* __restrict__ Wkqv, const float* __restrict__ Wproj,
    const float* __restrict__ w1, const float* __restrict__ w2,
    ushort_t* __restrict__ dst)      // 6 layers, stride 5336064 ushorts
{
    int i4 = blockIdx.x * 256 + threadIdx.x;    // 0 .. 8004095
    int layer = i4 / 1334016;
    int r = i4 - layer * 1334016;
    cvt_w_one(r, layer, Wkqv, Wproj, w1, w2, dst + (long)layer * 5336064);
}

__global__ __launch_bounds__(256) void cvt_weights_layer(
    const float* __restrict__ Wkqv, const float* __restrict__ Wproj,
    const float* __restrict__ w1, const float* __restrict__ w2,
    ushort_t* __restrict__ dst, int layer)      // one layer into dst
{
    int r = blockIdx.x * 256 + threadIdx.x;     // 0 .. 1334015
    cvt_w_one(r, layer, Wkqv, Wproj, w1, w2, dst);
}

// ---------------------------------------------------------------------------
// Residual stream lives in bf16 (xio). LN computes in fp32:
//   xnew = LayerNorm(xio + sum_{i<NR} res_i (+bias)) * g + b -> bf16 xio
// FINAL variant also writes fp32 to xf (the harness output buffer).
// ---------------------------------------------------------------------------
template<int NR, int FINAL>
__global__ __launch_bounds__(192) void add_ln(
    ushort_t* __restrict__ xio, const ushort_t* __restrict__ res, long rstride,
    const float* __restrict__ bias,
    const float* __restrict__ g, const float* __restrict__ bta,
    float* __restrict__ xf)
{
    const long row = blockIdx.x;
    ushort4v* xr = (ushort4v*)(xio + row * EMBD);
    __shared__ float sh[4];
    const int tid = threadIdx.x;
    const int lane = tid & 63, w = tid >> 6;

    ushort4v xu = xr[tid];
    float v[4] = {b2f(xu.x), b2f(xu.y), b2f(xu.z), b2f(xu.w)};
#pragma unroll
    for (int p = 0; p < NR; ++p) {
        ushort4v u = ((const ushort4v*)(res + p * rstride + row * EMBD))[tid];
        v[0] += b2f(u.x); v[1] += b2f(u.y); v[2] += b2f(u.z); v[3] += b2f(u.w);
    }
    if (bias) {
        float4 b4 = ((const float4*)bias)[tid];
        v[0] += b4.x; v[1] += b4.y; v[2] += b4.z; v[3] += b4.w;
    }
    float s = v[0] + v[1] + v[2] + v[3];
    for (int o = 32; o; o >>= 1) s += __shfl_xor(s, o);
    if (lane == 0) sh[w] = s;
    __syncthreads();
    float mu = (sh[0] + sh[1] + sh[2]) * (1.f / EMBD);

    float var = 0.f;
#pragma unroll
    for (int c = 0; c < 4; ++c) { float d = v[c] - mu; var += d * d; }
    for (int o = 32; o; o >>= 1) var += __shfl_xor(var, o);
    __syncthreads();
    if (lane == 0) sh[w] = var;
    __syncthreads();
    var = (sh[0] + sh[1] + sh[2]) * (1.f / EMBD);
    float rstd = rsqrtf(var + 1e-5f);

    const float4 g4 = ((const float4*)g)[tid];
    const float4 b4 = ((const float4*)bta)[tid];
    float o0 = (v[0] - mu) * rstd * g4.x + b4.x;
    float o1 = (v[1] - mu) * rstd * g4.y + b4.y;
    float o2 = (v[2] - mu) * rstd * g4.z + b4.z;
    float o3 = (v[3] - mu) * rstd * g4.w + b4.w;
    ushort4v ob = {f2b(o0), f2b(o1), f2b(o2), f2b(o3)};
    xr[tid] = ob;
    if (FINAL) {
        float4 ov = {o0, o1, o2, o3};
        ((float4*)(xf + row * EMBD))[tid] = ov;
    }
}

// ---------------------------------------------------------------------------
extern "C" void kernel_launch(void* const* d_in, const int* in_sizes, int n_in,
                              void* d_out, int out_size, void* d_ws, size_t ws_size,
                              hipStream_t stream) {
    const float* x_in  = (const float*)d_in[0];
    const float* Wkqv  = (const float*)d_in[1];
    const float* Wproj = (const float*)d_in[2];
    const float* ln1_g = (const float*)d_in[3];
    const float* ln1_b = (const float*)d_in[4];
    const float* ln2_g = (const float*)d_in[5];
    const float* ln2_b = (const float*)d_in[6];
    const float* ff_w1 = (const float*)d_in[7];
    const float* ff_b1 = (const float*)d_in[8];
    const float* ff_w2 = (const float*)d_in[9];
    const float* ff_b2 = (const float*)d_in[10];

    float* xout = (float*)d_out;                          // written by final LN only
    char* ws = (char*)d_ws;
    ushort_t* Qh     = (ushort_t*)(ws);                   // 37.7 MB
    ushort_t* Kh     = (ushort_t*)(ws + 37748736);        // 37.7 MB
    ushort_t* Vtb    = (ushort_t*)(ws + 75497472);        // 6.3 MB (union res0)
    ushort_t* resb   = (ushort_t*)(ws + 75497472);        // 4 x 6.3 MB bf16 partials
    ushort_t* h1b    = (ushort_t*)(ws + 100663296);       // 25.2 MB
    ushort_t* xb     = (ushort_t*)(ws + 125829120);       // 6.3 MB bf16 residual stream
    ushort_t* attnb  = (ushort_t*)(ws + 132120576);       // 6.3 MB
    ushort_t* Wall   = (ushort_t*)(ws + 138412032);
    const size_t WLAYER_B = 10672128;          // bytes per layer slot
    const int    WLAYER_E = 5336064;           // ushorts per layer slot
    const int big = (ws_size >= 138412032 + 6 * WLAYER_B) ? 1 : 0;
    const long RES_STRIDE = 3145728;           // partial stride in elements (6.3 MB)

    cvt_f2b<<<3072, 256, 0, stream>>>(x_in, xb);
    if (big)
        cvt_weights_all<<<31266, 256, 0, stream>>>(Wkqv, Wproj, ff_w1, ff_w2, Wall);

    const float scale = 0.10206207261596577f;  // 1/sqrt(96)

    for (int l = 0; l < NLAYER; ++l) {
        const float* b1 = ff_b1 + (size_t)l * FFD;
        const float* b2 = ff_b2 + (size_t)l * EMBD;

        ushort_t* Wl = Wall + (big ? (long)l * WLAYER_E : 0);
        if (!big)
            cvt_weights_layer<<<5211, 256, 0, stream>>>(Wkqv, Wproj, ff_w1, ff_w2, Wl, l);
        ushort_t* Wkqvb  = Wl;
        ushort_t* Wprojb = Wl + 27648;
        ushort_t* W1b    = Wl + 617472;
        ushort_t* W2b    = Wl + 2976768;

        // kqv GEMM with direct scatter epilogue: K,Q(scaled) -> history, V -> Vt
        kqv_gemm<<<dim3(3, 256, 1), 256, 0, stream>>>(
            xb, Wkqvb, Kh, Qh, Vtb, l * ESS, scale);

        // fused: S = Qh Kh^T (scale pre-folded, Kd=96*(l+1)); attn = softmax @ V
        fused_attn<<<512, 512, 0, stream>>>(
            Qh, Kh, Vtb, attnb, ESS * (l + 1));

        // res partials (bf16) = attn @ Wproj^T split-K2 (Vtb dead)
        gemm_mfma<128, 128, 2, 2, 1, 0, 0, 0><<<dim3(6, 32, 2), 256, 0, stream>>>(
            attnb, EMBD, Wprojb, EMBD, resb, EMBD, EMBD / 2, 1.f, nullptr,
            1, 384, 0, 384, 0, RES_STRIDE, 0);

        add_ln<2, 0><<<BB * TT, 192, 0, stream>>>(xb, resb, RES_STRIDE, nullptr,
            ln1_g + (size_t)l * EMBD, ln1_b + (size_t)l * EMBD, nullptr);

        // h1 = gelu(xb @ W1^T + b1), fast-gelu epilogue
        gemm_mfma<128, 128, 2, 2, 1, 1, 1, 0><<<dim3(24, 32, 1), 256, 0, stream>>>(
            xb, EMBD, W1b, EMBD, h1b, FFD, EMBD, 1.f, b1,
            1, 0, 0, 0, 0, 0, 0);

        // res partials (bf16) = h1 @ W2^T split-K4 (b2 applied in ln2)
        gemm_mfma<128, 128, 2, 2, 1, 0, 0, 0><<<dim3(6, 32, 4), 256, 0, stream>>>(
            h1b, FFD, W2b, FFD, resb, EMBD, FFD / 4, 1.f, nullptr,
            1, 768, 0, 768, 0, RES_STRIDE, 0);

        if (l == NLAYER - 1)
            add_ln<4, 1><<<BB * TT, 192, 0, stream>>>(xb, resb, RES_STRIDE, b2,
                ln2_g + (size_t)l * EMBD, ln2_b + (size_t)l * EMBD, xout);
        else
            add_ln<4, 0><<<BB * TT, 192, 0, stream>>>(xb, resb, RES_STRIDE, b2,
                ln2_g + (size_t)l * EMBD, ln2_b + (size_t)l * EMBD, nullptr);
    }
}

// Round 18
// 940.503 us; speedup vs baseline: 1.3502x; 1.0084x over previous
//
#include <hip/hip_runtime.h>
#include <math.h>

#define BB 8
#define TT 512
#define HH 8
#define ESS 96
#define EMBD 768
#define FFD 3072
#define NLAYER 6
#define KHMAX 576   // 96 * 6, history feature pitch

typedef unsigned short ushort_t;
typedef __attribute__((ext_vector_type(8))) short short8;
typedef __attribute__((ext_vector_type(4))) float f32x4;
typedef __attribute__((ext_vector_type(4))) unsigned short ushort4v;

static __device__ __forceinline__ ushort_t f2b(float f) {
    unsigned u = __builtin_bit_cast(unsigned, f);
    unsigned r = (u + 0x7fffu + ((u >> 16) & 1u)) >> 16;
    return (ushort_t)r;
}
static __device__ __forceinline__ float b2f(ushort_t u) {
    return __builtin_bit_cast(float, ((unsigned)u) << 16);
}

#define GLDS(gp, lp) __builtin_amdgcn_global_load_lds( \
    (const __attribute__((address_space(1))) void*)(gp), \
    (__attribute__((address_space(3))) void*)(lp), 16, 0, 0)

// ---------------------------------------------------------------------------
// bf16 MFMA GEMM: C = alpha * A(M,K) * B(N,K)^T (+beta*C) (+bias) (+gelu)
// GELU uses tanh-form (x*sigmoid(1.5958(x+0.044715x^3))), ~3e-4 abs err.
// ---------------------------------------------------------------------------
template<int BM, int BN, int WM, int WN, int OUTBF, int HASBIAS, int GELU, int BETA>
__global__ __launch_bounds__(256) void gemm_mfma(
    const ushort_t* __restrict__ A, int lda,
    const ushort_t* __restrict__ B, int ldb,
    void* __restrict__ Cv, int ldc,
    int K, float alpha,
    const float* __restrict__ bias,
    int bdiv, long sAb, long sAh, long sBb, long sBh, long sCb, long sCh)
{
    constexpr int BK = 32;
    constexpr int WTM = BM / WM;
    constexpr int WTN = BN / WN;
    constexpr int MF = WTM / 16, NF = WTN / 16;
    constexpr int ACH = (BM * BK * 2) / 1024;
    constexpr int BCH = (BN * BK * 2) / 1024;

    const int z = blockIdx.z;
    const int zb = z / bdiv, zh = z % bdiv;
    A += (long)zb * sAb + (long)zh * sAh;
    B += (long)zb * sBb + (long)zh * sBh;
    const long coff = (long)zb * sCb + (long)zh * sCh;

    __shared__ ushort_t As[BM * BK];
    __shared__ ushort_t Bs[BN * BK];

    const int tid = threadIdx.x;
    const int w = tid >> 6, lane = tid & 63;
    const int wr = w / WN, wc = w % WN;
    const int m0 = blockIdx.y * BM;
    const int n0 = blockIdx.x * BN;

    f32x4 acc[MF][NF] = {};

    const int fr = lane & 15;
    const int kb = lane >> 4;

    for (int k0 = 0; k0 < K; k0 += BK) {
#pragma unroll
        for (int q = 0; q < (ACH + 3) / 4; ++q) {
            int ci = q * 4 + w;
            if (ci < ACH) {
                int e = ci * 512 + lane * 8;
                int r = e >> 5, c = e & 31;
                GLDS(A + (long)(m0 + r) * lda + (k0 + c), (char*)As + ci * 1024);
            }
        }
#pragma unroll
        for (int q = 0; q < (BCH + 3) / 4; ++q) {
            int ci = q * 4 + w;
            if (ci < BCH) {
                int e = ci * 512 + lane * 8;
                int r = e >> 5, c = e & 31;
                GLDS(B + (long)(n0 + r) * ldb + (k0 + c), (char*)Bs + ci * 1024);
            }
        }
        __syncthreads();

        short8 af[MF], bfr[NF];
#pragma unroll
        for (int fm = 0; fm < MF; ++fm)
            af[fm] = *(const short8*)&As[(wr * WTM + fm * 16 + fr) * 32 + kb * 8];
#pragma unroll
        for (int fn = 0; fn < NF; ++fn)
            bfr[fn] = *(const short8*)&Bs[(wc * WTN + fn * 16 + fr) * 32 + kb * 8];
#pragma unroll
        for (int fm = 0; fm < MF; ++fm)
#pragma unroll
            for (int fn = 0; fn < NF; ++fn)
                acc[fm][fn] = __builtin_amdgcn_mfma_f32_16x16x32_bf16(
                    af[fm], bfr[fn], acc[fm][fn], 0, 0, 0);
        __syncthreads();
    }

    const int cr = lane >> 4;
    const int cc = lane & 15;
#pragma unroll
    for (int fm = 0; fm < MF; ++fm) {
#pragma unroll
        for (int fn = 0; fn < NF; ++fn) {
#pragma unroll
            for (int j = 0; j < 4; ++j) {
                int gm = m0 + wr * WTM + fm * 16 + cr * 4 + j;
                int gn = n0 + wc * WTN + fn * 16 + cc;
                float v = alpha * acc[fm][fn][j];
                if (HASBIAS) v += bias[gn];
                if (GELU) {
                    float zz = 1.5957691216f * fmaf(0.044715f * v * v, v, v);
                    v = v / (1.f + __expf(-zz));
                }
                long idx = coff + (long)gm * ldc + gn;
                if (BETA) v += ((const float*)Cv)[idx];
                if (OUTBF) ((ushort_t*)Cv)[idx] = f2b(v);
                else       ((float*)Cv)[idx] = v;
            }
        }
    }
}

// ---------------------------------------------------------------------------
// kqv GEMM with scatter epilogue: A = xb (B*T*H, 96), B = Wkqv (288, 96).
// Writes K -> Kh[..,loff+n], Q*scale -> Qh[..,loff+n], V -> Vt[(bh,s),t].
// ---------------------------------------------------------------------------
__global__ __launch_bounds__(256) void kqv_gemm(
    const ushort_t* __restrict__ A,       // xb, lda 96
    const ushort_t* __restrict__ Bw,      // Wkqvb, ldb 96
    ushort_t* __restrict__ Kh, ushort_t* __restrict__ Qh,
    ushort_t* __restrict__ Vt, int loff, float scale)
{
    constexpr int BM = 128, BN = 96, BK = 32;
    __shared__ ushort_t As[BM * BK];
    __shared__ ushort_t Bs[BN * BK];

    const int tid = threadIdx.x;
    const int w = tid >> 6, lane = tid & 63;
    const int m0 = blockIdx.y * BM;
    const int n0 = blockIdx.x * BN;

    f32x4 acc[2][6] = {};
    const int fr = lane & 15;
    const int kb = lane >> 4;

    for (int k0 = 0; k0 < 96; k0 += BK) {
#pragma unroll
        for (int q = 0; q < 2; ++q) {
            int ci = q * 4 + w;
            int e = ci * 512 + lane * 8;
            int r = e >> 5, c = e & 31;
            GLDS(A + (long)(m0 + r) * ESS + (k0 + c), (char*)As + ci * 1024);
        }
        {
            int ci = w;
            int e = ci * 512 + lane * 8;
            int r = e >> 5, c = e & 31;
            GLDS(Bw + (long)(n0 + r) * ESS + (k0 + c), (char*)Bs + ci * 1024);
            if (w < 2) {
                int ci2 = 4 + w;
                int e2 = ci2 * 512 + lane * 8;
                int r2 = e2 >> 5, c2 = e2 & 31;
                GLDS(Bw + (long)(n0 + r2) * ESS + (k0 + c2), (char*)Bs + ci2 * 1024);
            }
        }
        __syncthreads();

        short8 af[2], bfr[6];
#pragma unroll
        for (int fm = 0; fm < 2; ++fm)
            af[fm] = *(const short8*)&As[(w * 32 + fm * 16 + fr) * 32 + kb * 8];
#pragma unroll
        for (int fn = 0; fn < 6; ++fn)
            bfr[fn] = *(const short8*)&Bs[(fn * 16 + fr) * 32 + kb * 8];
#pragma unroll
        for (int fm = 0; fm < 2; ++fm)
#pragma unroll
            for (int fn = 0; fn < 6; ++fn)
                acc[fm][fn] = __builtin_amdgcn_mfma_f32_16x16x32_bf16(
                    af[fm], bfr[fn], acc[fm][fn], 0, 0, 0);
        __syncthreads();
    }

    const int cr = lane >> 4;
    const int cc = lane & 15;
    const int kind = blockIdx.x;      // 0 = K, 1 = Q, 2 = V
#pragma unroll
    for (int fm = 0; fm < 2; ++fm) {
#pragma unroll
        for (int fn = 0; fn < 6; ++fn) {
#pragma unroll
            for (int j = 0; j < 4; ++j) {
                int gm = m0 + w * 32 + fm * 16 + cr * 4 + j;
                int s = fn * 16 + cc;
                float v = acc[fm][fn][j];
                int h = gm & 7;
                int bt = gm >> 3;
                int t = bt & 511, b = bt >> 9;
                int bh = b * HH + h;
                if (kind == 0)
                    Kh[((long)(bh * TT + t)) * KHMAX + loff + s] = f2b(v);
                else if (kind == 1)
                    Qh[((long)(bh * TT + t)) * KHMAX + loff + s] = f2b(v * scale);
                else
                    Vt[((long)(bh * ESS + s)) * TT + t] = f2b(v);
            }
        }
    }
}

// ---------------------------------------------------------------------------
// Fused attention with Q/K-history accumulation (RealFormer carry).
// 64 Q-rows per block, 8 waves (512 thr), 512 blocks, 2 blocks/CU.
// Phase 3 V staging is double-buffered: one barrier per j-step (16 vs 32),
// V(0) prefetch issued under the phase-2 publish barrier.
// Scale pre-folded into Qh.
// ---------------------------------------------------------------------------
__global__ __launch_bounds__(512) void fused_attn(
    const ushort_t* __restrict__ Qh,    // (B*H, T, 576) bf16, cols [0,Kd)
    const ushort_t* __restrict__ Kh,    // (B*H, T, 576) bf16
    const ushort_t* __restrict__ Vt,    // (B*H, 96, T) bf16
    ushort_t* __restrict__ attn,        // (B,T,EMB) bf16
    int Kd)
{
    __shared__ char lds[79872];
    ushort_t* Pt  = (ushort_t*)lds;             // 64 KiB: P 64x512 bf16 (swizzled)
    ushort_t* Bs  = (ushort_t*)lds;             // union: K tile 512x32 (32 KiB)
    ushort_t* As  = (ushort_t*)(lds + 32768);   // union: Q tile 64x32 (4 KiB)
    ushort_t* Vs0 = (ushort_t*)(lds + 65536);   // 6 KiB: V^T chunk buf 0
    ushort_t* Vs1 = (ushort_t*)(lds + 71680);   // 6 KiB: V^T chunk buf 1
    float* red    = (float*)(lds + 77824);      // 1 KiB
    float* red2   = (float*)(lds + 78848);      // 1 KiB

    // XCD swizzle: hw xcd = wg & 7 (round-robin)
    const int wg = blockIdx.x;
    const int xcd = wg & 7;
    const int sub = wg >> 3;          // 0..63, sequential within an XCD
    const int m0 = (sub & 7) * 64;    // m-tile fastest -> same bh consecutive
    const int bh = (sub >> 3) * 8 + xcd;
    const int b = bh >> 3, h = bh & 7;

    const int tid = threadIdx.x;
    const int w = tid >> 6, lane = tid & 63;
    const int g = w >> 2;             // row group: 0 = rows m0..31, 1 = +32..63
    const int wg4 = w & 3;            // role within group
    const int fr = lane & 15, kb = lane >> 4;
    const int cr = kb, cc = fr;

    f32x4 acc[2][8] = {};

    // ---- phase 1: S = Q_hist K_hist^T over Kd feature cols ----
    for (int k0 = 0; k0 < Kd; k0 += 32) {
        if (w < 4) {                  // Q tile 64x32 = 4 chunks
            int e = w * 512 + lane * 8;
            int r = e >> 5, c = e & 31;
            GLDS(Qh + ((long)(bh * TT + m0 + r)) * KHMAX + k0 + c,
                 (char*)As + w * 1024);
        }
#pragma unroll
        for (int q = 0; q < 4; ++q) { // K tile 512x32 = 32 chunks, 4 per wave
            int ci = q * 8 + w;
            int e = ci * 512 + lane * 8;
            int r = e >> 5, c = e & 31;
            GLDS(Kh + ((long)(bh * TT + r)) * KHMAX + k0 + c,
                 (char*)Bs + ci * 1024);
        }
        __syncthreads();
        short8 af0 = *(const short8*)&As[(g * 32 + fr) * 32 + kb * 8];
        short8 af1 = *(const short8*)&As[(g * 32 + 16 + fr) * 32 + kb * 8];
#pragma unroll
        for (int fn = 0; fn < 8; ++fn) {
            short8 bf = *(const short8*)&Bs[(wg4 * 128 + fn * 16 + fr) * 32 + kb * 8];
            acc[0][fn] = __builtin_amdgcn_mfma_f32_16x16x32_bf16(af0, bf, acc[0][fn], 0, 0, 0);
            acc[1][fn] = __builtin_amdgcn_mfma_f32_16x16x32_bf16(af1, bf, acc[1][fn], 0, 0, 0);
        }
        __syncthreads();
    }

    // ---- phase 2: softmax over key axis (per 32-row group) ----
#pragma unroll
    for (int fm = 0; fm < 2; ++fm)
#pragma unroll
        for (int j = 0; j < 4; ++j) {
            float mx = -1e30f;
#pragma unroll
            for (int fn = 0; fn < 8; ++fn) mx = fmaxf(mx, acc[fm][fn][j]);
            for (int o = 1; o <= 8; o <<= 1) mx = fmaxf(mx, __shfl_xor(mx, o));
            if (cc == 0) red[g * 128 + wg4 * 32 + fm * 16 + cr * 4 + j] = mx;
        }
    __syncthreads();

    float inv[2][4];
#pragma unroll
    for (int fm = 0; fm < 2; ++fm)
#pragma unroll
        for (int j = 0; j < 4; ++j) {
            int r = fm * 16 + cr * 4 + j;
            const float* rg = red + g * 128;
            float mx = fmaxf(fmaxf(rg[r], rg[32 + r]), fmaxf(rg[64 + r], rg[96 + r]));
            float s = 0.f;
#pragma unroll
            for (int fn = 0; fn < 8; ++fn) {
                float e = __expf(acc[fm][fn][j] - mx);
                acc[fm][fn][j] = e;
                s += e;
            }
            for (int o = 1; o <= 8; o <<= 1) s += __shfl_xor(s, o);
            if (cc == 0) red2[g * 128 + wg4 * 32 + r] = s;
        }
    __syncthreads();
#pragma unroll
    for (int fm = 0; fm < 2; ++fm)
#pragma unroll
        for (int j = 0; j < 4; ++j) {
            int r = fm * 16 + cr * 4 + j;
            const float* rg = red2 + g * 128;
            inv[fm][j] = 1.f / (rg[r] + rg[32 + r] + rg[64 + r] + rg[96 + r]);
        }
    __syncthreads();   // acc scaled; Pt (Bs/As union) free to overwrite

    // write P (bf16) into swizzled LDS tile (elem col ^= (row&7)<<3)
#pragma unroll
    for (int fm = 0; fm < 2; ++fm)
#pragma unroll
        for (int fn = 0; fn < 8; ++fn)
#pragma unroll
            for (int j = 0; j < 4; ++j) {
                int row = g * 32 + fm * 16 + cr * 4 + j;
                int col = wg4 * 128 + fn * 16 + cc;
                Pt[row * 512 + (col ^ ((row & 7) << 3))] = f2b(acc[fm][fn][j] * inv[fm][j]);
            }

    // prefetch V(0) into Vs0 under the publish barrier
    if (w < 6) {
        int e = w * 512 + lane * 8;
        int r = e >> 5, c = e & 31;
        GLDS(Vt + ((long)(bh * ESS + r)) * TT + c, (char*)Vs0 + w * 1024);
    }
    __syncthreads();   // P visible AND V(0) loaded (barrier drains vmcnt)

    // ---- phase 3: attn = P @ V, double-buffered V, 1 barrier/step ----
    const int wr = w >> 1, wc2 = w & 1;   // wr 0..3: 16-row slices of 64
    const int prow = wr * 16 + fr;
    f32x4 po[3] = {};
#pragma unroll
    for (int step = 0; step < 16; ++step) {
        const int j0 = step * 32;
        ushort_t* cur = (step & 1) ? Vs1 : Vs0;
        ushort_t* nxt = (step & 1) ? Vs0 : Vs1;
        if (step + 1 < 16 && w < 6) {
            int e = w * 512 + lane * 8;
            int r = e >> 5, c = e & 31;
            GLDS(Vt + ((long)(bh * ESS + r)) * TT + j0 + 32 + c, (char*)nxt + w * 1024);
        }
        short8 pa = *(const short8*)&Pt[prow * 512 + ((j0 + kb * 8) ^ ((prow & 7) << 3))];
#pragma unroll
        for (int fn = 0; fn < 3; ++fn) {
            short8 vb = *(const short8*)&cur[(wc2 * 48 + fn * 16 + fr) * 32 + kb * 8];
            po[fn] = __builtin_amdgcn_mfma_f32_16x16x32_bf16(pa, vb, po[fn], 0, 0, 0);
        }
        __syncthreads();   // publishes nxt, frees cur for step+1's staging
    }

#pragma unroll
    for (int fn = 0; fn < 3; ++fn)
#pragma unroll
        for (int j = 0; j < 4; ++j) {
            int grow = m0 + wr * 16 + cr * 4 + j;
            int gcol = h * ESS + wc2 * 48 + fn * 16 + cc;
            attn[((long)(b * TT + grow)) * EMBD + gcol] = f2b(po[fn][j]);
        }
}

// ---------------------------------------------------------------------------
__global__ __launch_bounds__(256) void cvt_f2b(
    const float* __restrict__ in, ushort_t* __restrict__ out)
{
    const int i = blockIdx.x * 256 + threadIdx.x;
    float4 v = ((const float4*)in)[i];
    ushort4v o = {f2b(v.x), f2b(v.y), f2b(v.z), f2b(v.w)};
    ((ushort4v*)out)[i] = o;
}

// ---------------------------------------------------------------------------
// Weight conversion. Per-layer contiguous layout (float4/ushort4v units):
//   [wkqv 6912 | wproj 147456 | w1 589824 | w2 589824] = 1334016 per layer
// ---------------------------------------------------------------------------
static __device__ __forceinline__ void cvt_w_one(
    int r, int layer,
    const float* Wkqv, const float* Wproj, const float* w1, const float* w2,
    ushort_t* dst_layer)
{
    const float* src; int base;
    if (r < 6912)        { src = Wkqv  + (long)layer * 27648;   base = 0; }
    else if (r < 154368) { src = Wproj + (long)layer * 589824;  base = 6912; }
    else if (r < 744192) { src = w1    + (long)layer * 2359296; base = 154368; }
    else                 { src = w2    + (long)layer * 2359296; base = 744192; }
    int j = r - base;
    float4 v = ((const float4*)src)[j];
    ushort4v o = {f2b(v.x), f2b(v.y), f2b(v.z), f2b(v.w)};
    ((ushort4v*)dst_layer)[r] = o;
}

__global__ __launch_bounds__(256) void cvt_weights_all(
    const float* __restrict__ Wkqv, const float* __restrict__ Wproj,
    const float* __restrict__ w1, const float* __restrict__ w2,
    ushort_t* __restrict__ dst)      // 6 layers, stride 5336064 ushorts
{
#pragma unroll
    for (int q = 0; q < 2; ++q) {
        int i4 = blockIdx.x * 512 + q * 256 + threadIdx.x;   // 0 .. 8004095
        int layer = i4 / 1334016;
        int r = i4 - layer * 1334016;
        cvt_w_one(r, layer, Wkqv, Wproj, w1, w2, dst + (long)layer * 5336064);
    }
}

__global__ __launch_bounds__(256) void cvt_weights_layer(
    const float* __restrict__ Wkqv, const float* __restrict__ Wproj,
    const float* __restrict__ w1, const float* __restrict__ w2,
    ushort_t* __restrict__ dst, int layer)      // one layer into dst
{
    int r = blockIdx.x * 256 + threadIdx.x;     // 0 .. 1334015
    cvt_w_one(r, layer, Wkqv, Wproj, w1, w2, dst);
}

// ---------------------------------------------------------------------------
// Residual stream lives in bf16 (xio). LN computes in fp32:
//   xnew = LayerNorm(xio + sum_{i<NR} res_i (+bias)) * g + b -> bf16 xio
// FINAL variant also writes fp32 to xf (the harness output buffer).
// ---------------------------------------------------------------------------
template<int NR, int FINAL>
__global__ __launch_bounds__(192) void add_ln(
    ushort_t* __restrict__ xio, const ushort_t* __restrict__ res, long rstride,
    const float* __restrict__ bias,
    const float* __restrict__ g, const float* __restrict__ bta,
    float* __restrict__ xf)
{
    const long row = blockIdx.x;
    ushort4v* xr = (ushort4v*)(xio + row * EMBD);
    __shared__ float sh[4];
    const int tid = threadIdx.x;
    const int lane = tid & 63, w = tid >> 6;

    ushort4v xu = xr[tid];
    float v[4] = {b2f(xu.x), b2f(xu.y), b2f(xu.z), b2f(xu.w)};
#pragma unroll
    for (int p = 0; p < NR; ++p) {
        ushort4v u = ((const ushort4v*)(res + p * rstride + row * EMBD))[tid];
        v[0] += b2f(u.x); v[1] += b2f(u.y); v[2] += b2f(u.z); v[3] += b2f(u.w);
    }
    if (bias) {
        float4 b4 = ((const float4*)bias)[tid];
        v[0] += b4.x; v[1] += b4.y; v[2] += b4.z; v[3] += b4.w;
    }
    float s = v[0] + v[1] + v[2] + v[3];
    for (int o = 32; o; o >>= 1) s += __shfl_xor(s, o);
    if (lane == 0) sh[w] = s;
    __syncthreads();
    float mu = (sh[0] + sh[1] + sh[2]) * (1.f / EMBD);

    float var = 0.f;
#pragma unroll
    for (int c = 0; c < 4; ++c) { float d = v[c] - mu; var += d * d; }
    for (int o = 32; o; o >>= 1) var += __shfl_xor(var, o);
    __syncthreads();
    if (lane == 0) sh[w] = var;
    __syncthreads();
    var = (sh[0] + sh[1] + sh[2]) * (1.f / EMBD);
    float rstd = rsqrtf(var + 1e-5f);

    const float4 g4 = ((const float4*)g)[tid];
    const float4 b4 = ((const float4*)bta)[tid];
    float o0 = (v[0] - mu) * rstd * g4.x + b4.x;
    float o1 = (v[1] - mu) * rstd * g4.y + b4.y;
    float o2 = (v[2] - mu) * rstd * g4.z + b4.z;
    float o3 = (v[3] - mu) * rstd * g4.w + b4.w;
    ushort4v ob = {f2b(o0), f2b(o1), f2b(o2), f2b(o3)};
    xr[tid] = ob;
    if (FINAL) {
        float4 ov = {o0, o1, o2, o3};
        ((float4*)(xf + row * EMBD))[tid] = ov;
    }
}

// ---------------------------------------------------------------------------
extern "C" void kernel_launch(void* const* d_in, const int* in_sizes, int n_in,
                              void* d_out, int out_size, void* d_ws, size_t ws_size,
                              hipStream_t stream) {
    const float* x_in  = (const float*)d_in[0];
    const float* Wkqv  = (const float*)d_in[1];
    const float* Wproj = (const float*)d_in[2];
    const float* ln1_g = (const float*)d_in[3];
    const float* ln1_b = (const float*)d_in[4];
    const float* ln2_g = (const float*)d_in[5];
    const float* ln2_b = (const float*)d_in[6];
    const float* ff_w1 = (const float*)d_in[7];
    const float* ff_b1 = (const float*)d_in[8];
    const float* ff_w2 = (const float*)d_in[9];
    const float* ff_b2 = (const float*)d_in[10];

    float* xout = (float*)d_out;                          // written by final LN only
    char* ws = (char*)d_ws;
    ushort_t* Qh     = (ushort_t*)(ws);                   // 37.7 MB
    ushort_t* Kh     = (ushort_t*)(ws + 37748736);        // 37.7 MB
    ushort_t* Vtb    = (ushort_t*)(ws + 75497472);        // 6.3 MB (union res0)
    ushort_t* resb   = (ushort_t*)(ws + 75497472);        // 4 x 6.3 MB bf16 partials
    ushort_t* h1b    = (ushort_t*)(ws + 100663296);       // 25.2 MB
    ushort_t* xb     = (ushort_t*)(ws + 125829120);       // 6.3 MB bf16 residual stream
    ushort_t* attnb  = (ushort_t*)(ws + 132120576);       // 6.3 MB
    ushort_t* Wall   = (ushort_t*)(ws + 138412032);
    const size_t WLAYER_B = 10672128;          // bytes per layer slot
    const int    WLAYER_E = 5336064;           // ushorts per layer slot
    const int big = (ws_size >= 138412032 + 6 * WLAYER_B) ? 1 : 0;
    const long RES_STRIDE = 3145728;           // partial stride in elements (6.3 MB)

    cvt_f2b<<<3072, 256, 0, stream>>>(x_in, xb);
    if (big)
        cvt_weights_all<<<15633, 256, 0, stream>>>(Wkqv, Wproj, ff_w1, ff_w2, Wall);

    const float scale = 0.10206207261596577f;  // 1/sqrt(96)

    for (int l = 0; l < NLAYER; ++l) {
        const float* b1 = ff_b1 + (size_t)l * FFD;
        const float* b2 = ff_b2 + (size_t)l * EMBD;

        ushort_t* Wl = Wall + (big ? (long)l * WLAYER_E : 0);
        if (!big)
            cvt_weights_layer<<<5211, 256, 0, stream>>>(Wkqv, Wproj, ff_w1, ff_w2, Wl, l);
        ushort_t* Wkqvb  = Wl;
        ushort_t* Wprojb = Wl + 27648;
        ushort_t* W1b    = Wl + 617472;
        ushort_t* W2b    = Wl + 2976768;

        // kqv GEMM with direct scatter epilogue: K,Q(scaled) -> history, V -> Vt
        kqv_gemm<<<dim3(3, 256, 1), 256, 0, stream>>>(
            xb, Wkqvb, Kh, Qh, Vtb, l * ESS, scale);

        // fused: S = Qh Kh^T (scale pre-folded, Kd=96*(l+1)); attn = softmax @ V
        fused_attn<<<512, 512, 0, stream>>>(
            Qh, Kh, Vtb, attnb, ESS * (l + 1));

        // res partials (bf16) = attn @ Wproj^T split-K2 (Vtb dead)
        gemm_mfma<128, 128, 2, 2, 1, 0, 0, 0><<<dim3(6, 32, 2), 256, 0, stream>>>(
            attnb, EMBD, Wprojb, EMBD, resb, EMBD, EMBD / 2, 1.f, nullptr,
            1, 384, 0, 384, 0, RES_STRIDE, 0);

        add_ln<2, 0><<<BB * TT, 192, 0, stream>>>(xb, resb, RES_STRIDE, nullptr,
            ln1_g + (size_t)l * EMBD, ln1_b + (size_t)l * EMBD, nullptr);

        // h1 = gelu(xb @ W1^T + b1), fast-gelu epilogue
        gemm_mfma<128, 128, 2, 2, 1, 1, 1, 0><<<dim3(24, 32, 1), 256, 0, stream>>>(
            xb, EMBD, W1b, EMBD, h1b, FFD, EMBD, 1.f, b1,
            1, 0, 0, 0, 0, 0, 0);

        // res partials (bf16) = h1 @ W2^T split-K4 (b2 applied in ln2)
        gemm_mfma<128, 128, 2, 2, 1, 0, 0, 0><<<dim3(6, 32, 4), 256, 0, stream>>>(
            h1b, FFD, W2b, FFD, resb, EMBD, FFD / 4, 1.f, nullptr,
            1, 768, 0, 768, 0, RES_STRIDE, 0);

        if (l == NLAYER - 1)
            add_ln<4, 1><<<BB * TT, 192, 0, stream>>>(xb, resb, RES_STRIDE, b2,
                ln2_g + (size_t)l * EMBD, ln2_b + (size_t)l * EMBD, xout);
        else
            add_ln<4, 0><<<BB * TT, 192, 0, stream>>>(xb, resb, RES_STRIDE, b2,
                ln2_g + (size_t)l * EMBD, ln2_b + (size_t)l * EMBD, nullptr);
    }
}

// Round 20
// 937.741 us; speedup vs baseline: 1.3542x; 1.0029x over previous
//
#include <hip/hip_runtime.h>
#include <math.h>

#define BB 8
#define TT 512
#define HH 8
#define ESS 96
#define EMBD 768
#define FFD 3072
#define NLAYER 6
#define KHMAX 576   // 96 * 6, history feature pitch

typedef unsigned short ushort_t;
typedef __attribute__((ext_vector_type(8))) short short8;
typedef __attribute__((ext_vector_type(4))) float f32x4;
typedef __attribute__((ext_vector_type(4))) unsigned short ushort4v;
typedef __attribute__((ext_vector_type(8))) unsigned short ushort8v;

static __device__ __forceinline__ ushort_t f2b(float f) {
    unsigned u = __builtin_bit_cast(unsigned, f);
    unsigned r = (u + 0x7fffu + ((u >> 16) & 1u)) >> 16;
    return (ushort_t)r;
}
static __device__ __forceinline__ float b2f(ushort_t u) {
    return __builtin_bit_cast(float, ((unsigned)u) << 16);
}

#define GLDS(gp, lp) __builtin_amdgcn_global_load_lds( \
    (const __attribute__((address_space(1))) void*)(gp), \
    (__attribute__((address_space(3))) void*)(lp), 16, 0, 0)

// ---------------------------------------------------------------------------
// bf16 MFMA GEMM: C = alpha * A(M,K) * B(N,K)^T (+beta*C) (+bias) (+gelu)
// GELU uses tanh-form (x*sigmoid(1.5958(x+0.044715x^3))), ~3e-4 abs err.
// ---------------------------------------------------------------------------
template<int BM, int BN, int WM, int WN, int OUTBF, int HASBIAS, int GELU, int BETA>
__global__ __launch_bounds__(256) void gemm_mfma(
    const ushort_t* __restrict__ A, int lda,
    const ushort_t* __restrict__ B, int ldb,
    void* __restrict__ Cv, int ldc,
    int K, float alpha,
    const float* __restrict__ bias,
    int bdiv, long sAb, long sAh, long sBb, long sBh, long sCb, long sCh)
{
    constexpr int BK = 32;
    constexpr int WTM = BM / WM;
    constexpr int WTN = BN / WN;
    constexpr int MF = WTM / 16, NF = WTN / 16;
    constexpr int ACH = (BM * BK * 2) / 1024;
    constexpr int BCH = (BN * BK * 2) / 1024;

    const int z = blockIdx.z;
    const int zb = z / bdiv, zh = z % bdiv;
    A += (long)zb * sAb + (long)zh * sAh;
    B += (long)zb * sBb + (long)zh * sBh;
    const long coff = (long)zb * sCb + (long)zh * sCh;

    __shared__ ushort_t As[BM * BK];
    __shared__ ushort_t Bs[BN * BK];

    const int tid = threadIdx.x;
    const int w = tid >> 6, lane = tid & 63;
    const int wr = w / WN, wc = w % WN;
    const int m0 = blockIdx.y * BM;
    const int n0 = blockIdx.x * BN;

    f32x4 acc[MF][NF] = {};

    const int fr = lane & 15;
    const int kb = lane >> 4;

    for (int k0 = 0; k0 < K; k0 += BK) {
#pragma unroll
        for (int q = 0; q < (ACH + 3) / 4; ++q) {
            int ci = q * 4 + w;
            if (ci < ACH) {
                int e = ci * 512 + lane * 8;
                int r = e >> 5, c = e & 31;
                GLDS(A + (long)(m0 + r) * lda + (k0 + c), (char*)As + ci * 1024);
            }
        }
#pragma unroll
        for (int q = 0; q < (BCH + 3) / 4; ++q) {
            int ci = q * 4 + w;
            if (ci < BCH) {
                int e = ci * 512 + lane * 8;
                int r = e >> 5, c = e & 31;
                GLDS(B + (long)(n0 + r) * ldb + (k0 + c), (char*)Bs + ci * 1024);
            }
        }
        __syncthreads();

        short8 af[MF], bfr[NF];
#pragma unroll
        for (int fm = 0; fm < MF; ++fm)
            af[fm] = *(const short8*)&As[(wr * WTM + fm * 16 + fr) * 32 + kb * 8];
#pragma unroll
        for (int fn = 0; fn < NF; ++fn)
            bfr[fn] = *(const short8*)&Bs[(wc * WTN + fn * 16 + fr) * 32 + kb * 8];
#pragma unroll
        for (int fm = 0; fm < MF; ++fm)
#pragma unroll
            for (int fn = 0; fn < NF; ++fn)
                acc[fm][fn] = __builtin_amdgcn_mfma_f32_16x16x32_bf16(
                    af[fm], bfr[fn], acc[fm][fn], 0, 0, 0);
        __syncthreads();
    }

    const int cr = lane >> 4;
    const int cc = lane & 15;
#pragma unroll
    for (int fm = 0; fm < MF; ++fm) {
#pragma unroll
        for (int fn = 0; fn < NF; ++fn) {
#pragma unroll
            for (int j = 0; j < 4; ++j) {
                int gm = m0 + wr * WTM + fm * 16 + cr * 4 + j;
                int gn = n0 + wc * WTN + fn * 16 + cc;
                float v = alpha * acc[fm][fn][j];
                if (HASBIAS) v += bias[gn];
                if (GELU) {
                    float zz = 1.5957691216f * fmaf(0.044715f * v * v, v, v);
                    v = v / (1.f + __expf(-zz));
                }
                long idx = coff + (long)gm * ldc + gn;
                if (BETA) v += ((const float*)Cv)[idx];
                if (OUTBF) ((ushort_t*)Cv)[idx] = f2b(v);
                else       ((float*)Cv)[idx] = v;
            }
        }
    }
}

// ---------------------------------------------------------------------------
// kqv GEMM with scatter epilogue: A = xb (B*T*H, 96), B = Wkqv (288, 96).
// Writes K -> Kh[..,loff+n], Q*scale -> Qh[..,loff+n], V -> Vt[(bh,s),t].
// ---------------------------------------------------------------------------
__global__ __launch_bounds__(256) void kqv_gemm(
    const ushort_t* __restrict__ A,       // xb, lda 96
    const ushort_t* __restrict__ Bw,      // Wkqvb, ldb 96
    ushort_t* __restrict__ Kh, ushort_t* __restrict__ Qh,
    ushort_t* __restrict__ Vt, int loff, float scale)
{
    constexpr int BM = 128, BN = 96, BK = 32;
    __shared__ ushort_t As[BM * BK];
    __shared__ ushort_t Bs[BN * BK];

    const int tid = threadIdx.x;
    const int w = tid >> 6, lane = tid & 63;
    const int m0 = blockIdx.y * BM;
    const int n0 = blockIdx.x * BN;

    f32x4 acc[2][6] = {};
    const int fr = lane & 15;
    const int kb = lane >> 4;

    for (int k0 = 0; k0 < 96; k0 += BK) {
#pragma unroll
        for (int q = 0; q < 2; ++q) {
            int ci = q * 4 + w;
            int e = ci * 512 + lane * 8;
            int r = e >> 5, c = e & 31;
            GLDS(A + (long)(m0 + r) * ESS + (k0 + c), (char*)As + ci * 1024);
        }
        {
            int ci = w;
            int e = ci * 512 + lane * 8;
            int r = e >> 5, c = e & 31;
            GLDS(Bw + (long)(n0 + r) * ESS + (k0 + c), (char*)Bs + ci * 1024);
            if (w < 2) {
                int ci2 = 4 + w;
                int e2 = ci2 * 512 + lane * 8;
                int r2 = e2 >> 5, c2 = e2 & 31;
                GLDS(Bw + (long)(n0 + r2) * ESS + (k0 + c2), (char*)Bs + ci2 * 1024);
            }
        }
        __syncthreads();

        short8 af[2], bfr[6];
#pragma unroll
        for (int fm = 0; fm < 2; ++fm)
            af[fm] = *(const short8*)&As[(w * 32 + fm * 16 + fr) * 32 + kb * 8];
#pragma unroll
        for (int fn = 0; fn < 6; ++fn)
            bfr[fn] = *(const short8*)&Bs[(fn * 16 + fr) * 32 + kb * 8];
#pragma unroll
        for (int fm = 0; fm < 2; ++fm)
#pragma unroll
            for (int fn = 0; fn < 6; ++fn)
                acc[fm][fn] = __builtin_amdgcn_mfma_f32_16x16x32_bf16(
                    af[fm], bfr[fn], acc[fm][fn], 0, 0, 0);
        __syncthreads();
    }

    const int cr = lane >> 4;
    const int cc = lane & 15;
    const int kind = blockIdx.x;      // 0 = K, 1 = Q, 2 = V
#pragma unroll
    for (int fm = 0; fm < 2; ++fm) {
#pragma unroll
        for (int fn = 0; fn < 6; ++fn) {
#pragma unroll
            for (int j = 0; j < 4; ++j) {
                int gm = m0 + w * 32 + fm * 16 + cr * 4 + j;
                int s = fn * 16 + cc;
                float v = acc[fm][fn][j];
                int h = gm & 7;
                int bt = gm >> 3;
                int t = bt & 511, b = bt >> 9;
                int bh = b * HH + h;
                if (kind == 0)
                    Kh[((long)(bh * TT + t)) * KHMAX + loff + s] = f2b(v);
                else if (kind == 1)
                    Qh[((long)(bh * TT + t)) * KHMAX + loff + s] = f2b(v * scale);
                else
                    Vt[((long)(bh * ESS + s)) * TT + t] = f2b(v);
            }
        }
    }
}

// ---------------------------------------------------------------------------
// Fused attention with Q/K-history accumulation (RealFormer carry).
// 64 Q-rows per block, 8 waves, 512 blocks, 2 blocks/CU.
// K/Q/V staged tiles use a 32-col-safe XOR swizzle: LDS dest stays linear
// (global_load_lds requirement), the global SOURCE column group is permuted
// by ((row>>1)&3)  — i.e. c ^= (((row>>1)&3)<<3), staying inside the 32-col
// k-block — and every fragment ds_read applies the same XOR. This spreads a
// kb-group's 16 lanes over all 8 16B-slots of the 128B bank frame (2 lanes
// per slot = conflict-free) instead of 2 slots (8-way conflict).
// Phase-3 V double-buffered (1 barrier/step). Scale pre-folded into Qh.
// ---------------------------------------------------------------------------
__global__ __launch_bounds__(512) void fused_attn(
    const ushort_t* __restrict__ Qh,    // (B*H, T, 576) bf16, cols [0,Kd)
    const ushort_t* __restrict__ Kh,    // (B*H, T, 576) bf16
    const ushort_t* __restrict__ Vt,    // (B*H, 96, T) bf16
    ushort_t* __restrict__ attn,        // (B,T,EMB) bf16
    int Kd)
{
    __shared__ char lds[79872];
    ushort_t* Pt  = (ushort_t*)lds;             // 64 KiB: P 64x512 bf16 (swizzled)
    ushort_t* Bs  = (ushort_t*)lds;             // union: K tile 512x32 (32 KiB)
    ushort_t* As  = (ushort_t*)(lds + 32768);   // union: Q tile 64x32 (4 KiB)
    ushort_t* Vs0 = (ushort_t*)(lds + 65536);   // 6 KiB: V^T chunk buf 0
    ushort_t* Vs1 = (ushort_t*)(lds + 71680);   // 6 KiB: V^T chunk buf 1
    float* red    = (float*)(lds + 77824);      // 1 KiB
    float* red2   = (float*)(lds + 78848);      // 1 KiB

    // XCD swizzle: hw xcd = wg & 7 (round-robin)
    const int wg = blockIdx.x;
    const int xcd = wg & 7;
    const int sub = wg >> 3;          // 0..63, sequential within an XCD
    const int m0 = (sub & 7) * 64;    // m-tile fastest -> same bh consecutive
    const int bh = (sub >> 3) * 8 + xcd;
    const int b = bh >> 3, h = bh & 7;

    const int tid = threadIdx.x;
    const int w = tid >> 6, lane = tid & 63;
    const int g = w >> 2;             // row group: 0 = rows m0..31, 1 = +32..63
    const int wg4 = w & 3;            // role within group
    const int fr = lane & 15, kb = lane >> 4;
    const int cr = kb, cc = fr;
    // fragment-read XOR: ((row>>1)&3)<<3 ; all fragment rows ≡ fr mod 8-rows
    const int swz = ((fr >> 1) & 3) << 3;

    // staging source permutation: lane loads row rl, col cl (pre-swizzled,
    // stays within the 32-col block)
    const int rl = lane >> 2;                        // 0..15 within chunk
    const int cl = ((lane & 3) * 8) ^ (((rl >> 1) & 3) << 3);

    f32x4 acc[2][8] = {};

    // ---- phase 1: S = Q_hist K_hist^T over Kd feature cols ----
    for (int k0 = 0; k0 < Kd; k0 += 32) {
        if (w < 4) {                  // Q tile 64x32 = 4 chunks
            int r = w * 16 + rl;
            GLDS(Qh + ((long)(bh * TT + m0 + r)) * KHMAX + k0 + cl,
                 (char*)As + w * 1024);
        }
#pragma unroll
        for (int q = 0; q < 4; ++q) { // K tile 512x32 = 32 chunks, 4 per wave
            int ci = q * 8 + w;
            int r = ci * 16 + rl;
            GLDS(Kh + ((long)(bh * TT + r)) * KHMAX + k0 + cl,
                 (char*)Bs + ci * 1024);
        }
        __syncthreads();
        short8 af0 = *(const short8*)&As[(g * 32 + fr) * 32 + (kb * 8 ^ swz)];
        short8 af1 = *(const short8*)&As[(g * 32 + 16 + fr) * 32 + (kb * 8 ^ swz)];
#pragma unroll
        for (int fn = 0; fn < 8; ++fn) {
            short8 bf = *(const short8*)&Bs[(wg4 * 128 + fn * 16 + fr) * 32 + (kb * 8 ^ swz)];
            acc[0][fn] = __builtin_amdgcn_mfma_f32_16x16x32_bf16(af0, bf, acc[0][fn], 0, 0, 0);
            acc[1][fn] = __builtin_amdgcn_mfma_f32_16x16x32_bf16(af1, bf, acc[1][fn], 0, 0, 0);
        }
        __syncthreads();
    }

    // ---- phase 2: softmax over key axis (per 32-row group) ----
#pragma unroll
    for (int fm = 0; fm < 2; ++fm)
#pragma unroll
        for (int j = 0; j < 4; ++j) {
            float mx = -1e30f;
#pragma unroll
            for (int fn = 0; fn < 8; ++fn) mx = fmaxf(mx, acc[fm][fn][j]);
            for (int o = 1; o <= 8; o <<= 1) mx = fmaxf(mx, __shfl_xor(mx, o));
            if (cc == 0) red[g * 128 + wg4 * 32 + fm * 16 + cr * 4 + j] = mx;
        }
    __syncthreads();

    float inv[2][4];
#pragma unroll
    for (int fm = 0; fm < 2; ++fm)
#pragma unroll
        for (int j = 0; j < 4; ++j) {
            int r = fm * 16 + cr * 4 + j;
            const float* rg = red + g * 128;
            float mx = fmaxf(fmaxf(rg[r], rg[32 + r]), fmaxf(rg[64 + r], rg[96 + r]));
            float s = 0.f;
#pragma unroll
            for (int fn = 0; fn < 8; ++fn) {
                float e = __expf(acc[fm][fn][j] - mx);
                acc[fm][fn][j] = e;
                s += e;
            }
            for (int o = 1; o <= 8; o <<= 1) s += __shfl_xor(s, o);
            if (cc == 0) red2[g * 128 + wg4 * 32 + r] = s;
        }
    __syncthreads();
#pragma unroll
    for (int fm = 0; fm < 2; ++fm)
#pragma unroll
        for (int j = 0; j < 4; ++j) {
            int r = fm * 16 + cr * 4 + j;
            const float* rg = red2 + g * 128;
            inv[fm][j] = 1.f / (rg[r] + rg[32 + r] + rg[64 + r] + rg[96 + r]);
        }
    __syncthreads();   // acc scaled; Pt (Bs/As union) free to overwrite

    // write P (bf16) into swizzled LDS tile (512-wide rows: col ^= (row&7)<<3)
#pragma unroll
    for (int fm = 0; fm < 2; ++fm)
#pragma unroll
        for (int fn = 0; fn < 8; ++fn)
#pragma unroll
            for (int j = 0; j < 4; ++j) {
                int row = g * 32 + fm * 16 + cr * 4 + j;
                int col = wg4 * 128 + fn * 16 + cc;
                Pt[row * 512 + (col ^ ((row & 7) << 3))] = f2b(acc[fm][fn][j] * inv[fm][j]);
            }

    // prefetch V(0) into Vs0 under the publish barrier (pre-swizzled source)
    if (w < 6) {
        int r = w * 16 + rl;
        GLDS(Vt + ((long)(bh * ESS + r)) * TT + cl, (char*)Vs0 + w * 1024);
    }
    __syncthreads();   // P visible AND V(0) loaded (barrier drains vmcnt)

    // ---- phase 3: attn = P @ V, double-buffered V, 1 barrier/step ----
    const int wr = w >> 1, wc2 = w & 1;   // wr 0..3: 16-row slices of 64
    const int prow = wr * 16 + fr;
    f32x4 po[3] = {};
#pragma unroll
    for (int step = 0; step < 16; ++step) {
        const int j0 = step * 32;
        ushort_t* cur = (step & 1) ? Vs1 : Vs0;
        ushort_t* nxt = (step & 1) ? Vs0 : Vs1;
        if (step + 1 < 16 && w < 6) {
            int r = w * 16 + rl;
            GLDS(Vt + ((long)(bh * ESS + r)) * TT + j0 + 32 + cl, (char*)nxt + w * 1024);
        }
        short8 pa = *(const short8*)&Pt[prow * 512 + ((j0 + kb * 8) ^ ((prow & 7) << 3))];
#pragma unroll
        for (int fn = 0; fn < 3; ++fn) {
            short8 vb = *(const short8*)&cur[(wc2 * 48 + fn * 16 + fr) * 32 + (kb * 8 ^ swz)];
            po[fn] = __builtin_amdgcn_mfma_f32_16x16x32_bf16(pa, vb, po[fn], 0, 0, 0);
        }
        __syncthreads();   // publishes nxt, frees cur for step+1's staging
    }

#pragma unroll
    for (int fn = 0; fn < 3; ++fn)
#pragma unroll
        for (int j = 0; j < 4; ++j) {
            int grow = m0 + wr * 16 + cr * 4 + j;
            int gcol = h * ESS + wc2 * 48 + fn * 16 + cc;
            attn[((long)(b * TT + grow)) * EMBD + gcol] = f2b(po[fn][j]);
        }
}

// ---------------------------------------------------------------------------
__global__ __launch_bounds__(256) void cvt_f2b(
    const float* __restrict__ in, ushort_t* __restrict__ out)
{
    const int i = blockIdx.x * 256 + threadIdx.x;
    float4 v = ((const float4*)in)[i];
    ushort4v o = {f2b(v.x), f2b(v.y), f2b(v.z), f2b(v.w)};
    ((ushort4v*)out)[i] = o;
}

// ---------------------------------------------------------------------------
// Weight conversion, 8 floats/thread -> one 16B store.
// Per-layer layout in 8-float units: [wkqv 3456 | wproj 73728 | w1 294912 |
// w2 294912] = 667008 per layer.
// ---------------------------------------------------------------------------
static __device__ __forceinline__ void cvt_w_one8(
    int r8, int layer,
    const float* Wkqv, const float* Wproj, const float* w1, const float* w2,
    ushort_t* dst_layer)
{
    const float* src; int base;
    if (r8 < 3456)        { src = Wkqv  + (long)layer * 27648;   base = 0; }
    else if (r8 < 77184)  { src = Wproj + (long)layer * 589824;  base = 3456; }
    else if (r8 < 372096) { src = w1    + (long)layer * 2359296; base = 77184; }
    else                  { src = w2    + (long)layer * 2359296; base = 372096; }
    int j = r8 - base;
    float4 v0 = ((const float4*)src)[j * 2];
    float4 v1 = ((const float4*)src)[j * 2 + 1];
    ushort8v o = {f2b(v0.x), f2b(v0.y), f2b(v0.z), f2b(v0.w),
                  f2b(v1.x), f2b(v1.y), f2b(v1.z), f2b(v1.w)};
    ((ushort8v*)dst_layer)[r8] = o;
}

__global__ __launch_bounds__(256) void cvt_weights_all(
    const float* __restrict__ Wkqv, const float* __restrict__ Wproj,
    const float* __restrict__ w1, const float* __restrict__ w2,
    ushort_t* __restrict__ dst)      // 6 layers, stride 5336064 ushorts
{
    int i8 = blockIdx.x * 256 + threadIdx.x;    // 0 .. 4002047
    int layer = i8 / 667008;
    int r8 = i8 - layer * 667008;
    cvt_w_one8(r8, layer, Wkqv, Wproj, w1, w2, dst + (long)layer * 5336064);
}

__global__ __launch_bounds__(256) void cvt_weights_layer(
    const float* __restrict__ Wkqv, const float* __restrict__ Wproj,
    const float* __restrict__ w1, const float* __restrict__ w2,
    ushort_t* __restrict__ dst, int layer)      // one layer into dst
{
    int r8 = blockIdx.x * 256 + threadIdx.x;    // 0 .. 667007
    cvt_w_one8(r8, layer, Wkqv, Wproj, w1, w2, dst);
}

// ---------------------------------------------------------------------------
// Residual stream lives in bf16 (xio). LN computes in fp32:
//   xnew = LayerNorm(xio + sum_{i<NR} res_i (+bias)) * g + b -> bf16 xio
// FINAL variant also writes fp32 to xf (the harness output buffer).
// ---------------------------------------------------------------------------
template<int NR, int FINAL>
__global__ __launch_bounds__(192) void add_ln(
    ushort_t* __restrict__ xio, const ushort_t* __restrict__ res, long rstride,
    const float* __restrict__ bias,
    const float* __restrict__ g, const float* __restrict__ bta,
    float* __restrict__ xf)
{
    const long row = blockIdx.x;
    ushort4v* xr = (ushort4v*)(xio + row * EMBD);
    __shared__ float sh[4];
    const int tid = threadIdx.x;
    const int lane = tid & 63, w = tid >> 6;

    ushort4v xu = xr[tid];
    float v[4] = {b2f(xu.x), b2f(xu.y), b2f(xu.z), b2f(xu.w)};
#pragma unroll
    for (int p = 0; p < NR; ++p) {
        ushort4v u = ((const ushort4v*)(res + p * rstride + row * EMBD))[tid];
        v[0] += b2f(u.x); v[1] += b2f(u.y); v[2] += b2f(u.z); v[3] += b2f(u.w);
    }
    if (bias) {
        float4 b4 = ((const float4*)bias)[tid];
        v[0] += b4.x; v[1] += b4.y; v[2] += b4.z; v[3] += b4.w;
    }
    float s = v[0] + v[1] + v[2] + v[3];
    for (int o = 32; o; o >>= 1) s += __shfl_xor(s, o);
    if (lane == 0) sh[w] = s;
    __syncthreads();
    float mu = (sh[0] + sh[1] + sh[2]) * (1.f / EMBD);

    float var = 0.f;
#pragma unroll
    for (int c = 0; c < 4; ++c) { float d = v[c] - mu; var += d * d; }
    for (int o = 32; o; o >>= 1) var += __shfl_xor(var, o);
    __syncthreads();
    if (lane == 0) sh[w] = var;
    __syncthreads();
    var = (sh[0] + sh[1] + sh[2]) * (1.f / EMBD);
    float rstd = rsqrtf(var + 1e-5f);

    const float4 g4 = ((const float4*)g)[tid];
    const float4 b4 = ((const float4*)bta)[tid];
    float o0 = (v[0] - mu) * rstd * g4.x + b4.x;
    float o1 = (v[1] - mu) * rstd * g4.y + b4.y;
    float o2 = (v[2] - mu) * rstd * g4.z + b4.z;
    float o3 = (v[3] - mu) * rstd * g4.w + b4.w;
    ushort4v ob = {f2b(o0), f2b(o1), f2b(o2), f2b(o3)};
    xr[tid] = ob;
    if (FINAL) {
        float4 ov = {o0, o1, o2, o3};
        ((float4*)(xf + row * EMBD))[tid] = ov;
    }
}

// ---------------------------------------------------------------------------
extern "C" void kernel_launch(void* const* d_in, const int* in_sizes, int n_in,
                              void* d_out, int out_size, void* d_ws, size_t ws_size,
                              hipStream_t stream) {
    const float* x_in  = (const float*)d_in[0];
    const float* Wkqv  = (const float*)d_in[1];
    const float* Wproj = (const float*)d_in[2];
    const float* ln1_g = (const float*)d_in[3];
    const float* ln1_b = (const float*)d_in[4];
    const float* ln2_g = (const float*)d_in[5];
    const float* ln2_b = (const float*)d_in[6];
    const float* ff_w1 = (const float*)d_in[7];
    const float* ff_b1 = (const float*)d_in[8];
    const float* ff_w2 = (const float*)d_in[9];
    const float* ff_b2 = (const float*)d_in[10];

    float* xout = (float*)d_out;                          // written by final LN only
    char* ws = (char*)d_ws;
    ushort_t* Qh     = (ushort_t*)(ws);                   // 37.7 MB
    ushort_t* Kh     = (ushort_t*)(ws + 37748736);        // 37.7 MB
    ushort_t* Vtb    = (ushort_t*)(ws + 75497472);        // 6.3 MB (union res0)
    ushort_t* resb   = (ushort_t*)(ws + 75497472);        // 4 x 6.3 MB bf16 partials
    ushort_t* h1b    = (ushort_t*)(ws + 100663296);       // 25.2 MB
    ushort_t* xb     = (ushort_t*)(ws + 125829120);       // 6.3 MB bf16 residual stream
    ushort_t* attnb  = (ushort_t*)(ws + 132120576);       // 6.3 MB
    ushort_t* Wall   = (ushort_t*)(ws + 138412032);
    const size_t WLAYER_B = 10672128;          // bytes per layer slot
    const int    WLAYER_E = 5336064;           // ushorts per layer slot
    const int big = (ws_size >= 138412032 + 6 * WLAYER_B) ? 1 : 0;
    const long RES_STRIDE = 3145728;           // partial stride in elements (6.3 MB)

    cvt_f2b<<<3072, 256, 0, stream>>>(x_in, xb);
    if (big)
        cvt_weights_all<<<15633, 256, 0, stream>>>(Wkqv, Wproj, ff_w1, ff_w2, Wall);

    const float scale = 0.10206207261596577f;  // 1/sqrt(96)

    for (int l = 0; l < NLAYER; ++l) {
        const float* b1 = ff_b1 + (size_t)l * FFD;
        const float* b2 = ff_b2 + (size_t)l * EMBD;

        ushort_t* Wl = Wall + (big ? (long)l * WLAYER_E : 0);
        if (!big)
            cvt_weights_layer<<<2606, 256, 0, stream>>>(Wkqv, Wproj, ff_w1, ff_w2, Wl, l);
        ushort_t* Wkqvb  = Wl;
        ushort_t* Wprojb = Wl + 27648;
        ushort_t* W1b    = Wl + 617472;
        ushort_t* W2b    = Wl + 2976768;

        // kqv GEMM with direct scatter epilogue: K,Q(scaled) -> history, V -> Vt
        kqv_gemm<<<dim3(3, 256, 1), 256, 0, stream>>>(
            xb, Wkqvb, Kh, Qh, Vtb, l * ESS, scale);

        // fused: S = Qh Kh^T (scale pre-folded, Kd=96*(l+1)); attn = softmax @ V
        fused_attn<<<512, 512, 0, stream>>>(
            Qh, Kh, Vtb, attnb, ESS * (l + 1));

        // res partials (bf16) = attn @ Wproj^T split-K2 (Vtb dead)
        gemm_mfma<128, 128, 2, 2, 1, 0, 0, 0><<<dim3(6, 32, 2), 256, 0, stream>>>(
            attnb, EMBD, Wprojb, EMBD, resb, EMBD, EMBD / 2, 1.f, nullptr,
            1, 384, 0, 384, 0, RES_STRIDE, 0);

        add_ln<2, 0><<<BB * TT, 192, 0, stream>>>(xb, resb, RES_STRIDE, nullptr,
            ln1_g + (size_t)l * EMBD, ln1_b + (size_t)l * EMBD, nullptr);

        // h1 = gelu(xb @ W1^T + b1), fast-gelu epilogue
        gemm_mfma<128, 128, 2, 2, 1, 1, 1, 0><<<dim3(24, 32, 1), 256, 0, stream>>>(
            xb, EMBD, W1b, EMBD, h1b, FFD, EMBD, 1.f, b1,
            1, 0, 0, 0, 0, 0, 0);

        // res partials (bf16) = h1 @ W2^T split-K4 (b2 applied in ln2)
        gemm_mfma<128, 128, 2, 2, 1, 0, 0, 0><<<dim3(6, 32, 4), 256, 0, stream>>>(
            h1b, FFD, W2b, FFD, resb, EMBD, FFD / 4, 1.f, nullptr,
            1, 768, 0, 768, 0, RES_STRIDE, 0);

        if (l == NLAYER - 1)
            add_ln<4, 1><<<BB * TT, 192, 0, stream>>>(xb, resb, RES_STRIDE, b2,
                ln2_g + (size_t)l * EMBD, ln2_b + (size_t)l * EMBD, xout);
        else
            add_ln<4, 0><<<BB * TT, 192, 0, stream>>>(xb, resb, RES_STRIDE, b2,
                ln2_g + (size_t)l * EMBD, ln2_b + (size_t)l * EMBD, nullptr);
    }
}

// Round 21
// 925.084 us; speedup vs baseline: 1.3727x; 1.0137x over previous
//
#include <hip/hip_runtime.h>
#include <math.h>

#define BB 8
#define TT 512
#define HH 8
#define ESS 96
#define EMBD 768
#define FFD 3072
#define NLAYER 6
#define KHMAX 576   // 96 * 6, history feature pitch

typedef unsigned short ushort_t;
typedef __attribute__((ext_vector_type(8))) short short8;
typedef __attribute__((ext_vector_type(4))) float f32x4;
typedef __attribute__((ext_vector_type(4))) unsigned short ushort4v;
typedef __attribute__((ext_vector_type(8))) unsigned short ushort8v;

static __device__ __forceinline__ ushort_t f2b(float f) {
    unsigned u = __builtin_bit_cast(unsigned, f);
    unsigned r = (u + 0x7fffu + ((u >> 16) & 1u)) >> 16;
    return (ushort_t)r;
}
static __device__ __forceinline__ float b2f(ushort_t u) {
    return __builtin_bit_cast(float, ((unsigned)u) << 16);
}

#define GLDS(gp, lp) __builtin_amdgcn_global_load_lds( \
    (const __attribute__((address_space(1))) void*)(gp), \
    (__attribute__((address_space(3))) void*)(lp), 16, 0, 0)

// ---------------------------------------------------------------------------
// bf16 MFMA GEMM: C = alpha * A(M,K) * B(N,K)^T (+beta*C) (+bias) (+gelu)
// GELU uses tanh-form. Staged tiles use the 32-col-safe XOR swizzle
// (source col ^= ((row>>1)&3)<<3, same XOR on fragment reads) to kill the
// 8-way bank conflict on 64B-row-stride ds_read_b128.
// ---------------------------------------------------------------------------
template<int BM, int BN, int WM, int WN, int OUTBF, int HASBIAS, int GELU, int BETA>
__global__ __launch_bounds__(256) void gemm_mfma(
    const ushort_t* __restrict__ A, int lda,
    const ushort_t* __restrict__ B, int ldb,
    void* __restrict__ Cv, int ldc,
    int K, float alpha,
    const float* __restrict__ bias,
    int bdiv, long sAb, long sAh, long sBb, long sBh, long sCb, long sCh)
{
    constexpr int BK = 32;
    constexpr int WTM = BM / WM;
    constexpr int WTN = BN / WN;
    constexpr int MF = WTM / 16, NF = WTN / 16;
    constexpr int ACH = (BM * BK * 2) / 1024;
    constexpr int BCH = (BN * BK * 2) / 1024;

    const int z = blockIdx.z;
    const int zb = z / bdiv, zh = z % bdiv;
    A += (long)zb * sAb + (long)zh * sAh;
    B += (long)zb * sBb + (long)zh * sBh;
    const long coff = (long)zb * sCb + (long)zh * sCh;

    __shared__ ushort_t As[BM * BK];
    __shared__ ushort_t Bs[BN * BK];

    const int tid = threadIdx.x;
    const int w = tid >> 6, lane = tid & 63;
    const int wr = w / WN, wc = w % WN;
    const int m0 = blockIdx.y * BM;
    const int n0 = blockIdx.x * BN;

    f32x4 acc[MF][NF] = {};

    const int fr = lane & 15;
    const int kb = lane >> 4;
    const int swz = ((fr >> 1) & 3) << 3;            // fragment-read XOR
    const int rl = lane >> 2;                        // staging row in chunk
    const int cl = ((lane & 3) * 8) ^ (((rl >> 1) & 3) << 3);  // src col

    for (int k0 = 0; k0 < K; k0 += BK) {
#pragma unroll
        for (int q = 0; q < (ACH + 3) / 4; ++q) {
            int ci = q * 4 + w;
            if (ci < ACH) {
                int r = ci * 16 + rl;
                GLDS(A + (long)(m0 + r) * lda + (k0 + cl), (char*)As + ci * 1024);
            }
        }
#pragma unroll
        for (int q = 0; q < (BCH + 3) / 4; ++q) {
            int ci = q * 4 + w;
            if (ci < BCH) {
                int r = ci * 16 + rl;
                GLDS(B + (long)(n0 + r) * ldb + (k0 + cl), (char*)Bs + ci * 1024);
            }
        }
        __syncthreads();

        short8 af[MF], bfr[NF];
#pragma unroll
        for (int fm = 0; fm < MF; ++fm)
            af[fm] = *(const short8*)&As[(wr * WTM + fm * 16 + fr) * 32 + (kb * 8 ^ swz)];
#pragma unroll
        for (int fn = 0; fn < NF; ++fn)
            bfr[fn] = *(const short8*)&Bs[(wc * WTN + fn * 16 + fr) * 32 + (kb * 8 ^ swz)];
#pragma unroll
        for (int fm = 0; fm < MF; ++fm)
#pragma unroll
            for (int fn = 0; fn < NF; ++fn)
                acc[fm][fn] = __builtin_amdgcn_mfma_f32_16x16x32_bf16(
                    af[fm], bfr[fn], acc[fm][fn], 0, 0, 0);
        __syncthreads();
    }

    const int cr = lane >> 4;
    const int cc = lane & 15;
#pragma unroll
    for (int fm = 0; fm < MF; ++fm) {
#pragma unroll
        for (int fn = 0; fn < NF; ++fn) {
#pragma unroll
            for (int j = 0; j < 4; ++j) {
                int gm = m0 + wr * WTM + fm * 16 + cr * 4 + j;
                int gn = n0 + wc * WTN + fn * 16 + cc;
                float v = alpha * acc[fm][fn][j];
                if (HASBIAS) v += bias[gn];
                if (GELU) {
                    float zz = 1.5957691216f * fmaf(0.044715f * v * v, v, v);
                    v = v / (1.f + __expf(-zz));
                }
                long idx = coff + (long)gm * ldc + gn;
                if (BETA) v += ((const float*)Cv)[idx];
                if (OUTBF) ((ushort_t*)Cv)[idx] = f2b(v);
                else       ((float*)Cv)[idx] = v;
            }
        }
    }
}

// ---------------------------------------------------------------------------
// kqv GEMM with scatter epilogue: A = xb (B*T*H, 96), B = Wkqv (288, 96).
// Writes K -> Kh[..,loff+n], Q*scale -> Qh[..,loff+n], V -> Vt[(bh,s),t].
// Same 32-col-safe staging/read swizzle as gemm_mfma.
// ---------------------------------------------------------------------------
__global__ __launch_bounds__(256) void kqv_gemm(
    const ushort_t* __restrict__ A,       // xb, lda 96
    const ushort_t* __restrict__ Bw,      // Wkqvb, ldb 96
    ushort_t* __restrict__ Kh, ushort_t* __restrict__ Qh,
    ushort_t* __restrict__ Vt, int loff, float scale)
{
    constexpr int BM = 128, BN = 96, BK = 32;
    __shared__ ushort_t As[BM * BK];
    __shared__ ushort_t Bs[BN * BK];

    const int tid = threadIdx.x;
    const int w = tid >> 6, lane = tid & 63;
    const int m0 = blockIdx.y * BM;
    const int n0 = blockIdx.x * BN;

    f32x4 acc[2][6] = {};
    const int fr = lane & 15;
    const int kb = lane >> 4;
    const int swz = ((fr >> 1) & 3) << 3;
    const int rl = lane >> 2;
    const int cl = ((lane & 3) * 8) ^ (((rl >> 1) & 3) << 3);

    for (int k0 = 0; k0 < 96; k0 += BK) {
#pragma unroll
        for (int q = 0; q < 2; ++q) {
            int ci = q * 4 + w;
            int r = ci * 16 + rl;
            GLDS(A + (long)(m0 + r) * ESS + (k0 + cl), (char*)As + ci * 1024);
        }
        {
            int ci = w;
            int r = ci * 16 + rl;
            GLDS(Bw + (long)(n0 + r) * ESS + (k0 + cl), (char*)Bs + ci * 1024);
            if (w < 2) {
                int ci2 = 4 + w;
                int r2 = ci2 * 16 + rl;
                GLDS(Bw + (long)(n0 + r2) * ESS + (k0 + cl), (char*)Bs + ci2 * 1024);
            }
        }
        __syncthreads();

        short8 af[2], bfr[6];
#pragma unroll
        for (int fm = 0; fm < 2; ++fm)
            af[fm] = *(const short8*)&As[(w * 32 + fm * 16 + fr) * 32 + (kb * 8 ^ swz)];
#pragma unroll
        for (int fn = 0; fn < 6; ++fn)
            bfr[fn] = *(const short8*)&Bs[(fn * 16 + fr) * 32 + (kb * 8 ^ swz)];
#pragma unroll
        for (int fm = 0; fm < 2; ++fm)
#pragma unroll
            for (int fn = 0; fn < 6; ++fn)
                acc[fm][fn] = __builtin_amdgcn_mfma_f32_16x16x32_bf16(
                    af[fm], bfr[fn], acc[fm][fn], 0, 0, 0);
        __syncthreads();
    }

    const int cr = lane >> 4;
    const int cc = lane & 15;
    const int kind = blockIdx.x;      // 0 = K, 1 = Q, 2 = V
#pragma unroll
    for (int fm = 0; fm < 2; ++fm) {
#pragma unroll
        for (int fn = 0; fn < 6; ++fn) {
#pragma unroll
            for (int j = 0; j < 4; ++j) {
                int gm = m0 + w * 32 + fm * 16 + cr * 4 + j;
                int s = fn * 16 + cc;
                float v = acc[fm][fn][j];
                int h = gm & 7;
                int bt = gm >> 3;
                int t = bt & 511, b = bt >> 9;
                int bh = b * HH + h;
                if (kind == 0)
                    Kh[((long)(bh * TT + t)) * KHMAX + loff + s] = f2b(v);
                else if (kind == 1)
                    Qh[((long)(bh * TT + t)) * KHMAX + loff + s] = f2b(v * scale);
                else
                    Vt[((long)(bh * ESS + s)) * TT + t] = f2b(v);
            }
        }
    }
}

// ---------------------------------------------------------------------------
// Fused attention with Q/K-history accumulation (RealFormer carry).
// R20 structure (measured floor): 64 Q-rows/block, 8 waves, 512 blocks,
// all staged tiles swizzled, phase-3 V double-buffered.
// ---------------------------------------------------------------------------
__global__ __launch_bounds__(512) void fused_attn(
    const ushort_t* __restrict__ Qh,    // (B*H, T, 576) bf16, cols [0,Kd)
    const ushort_t* __restrict__ Kh,    // (B*H, T, 576) bf16
    const ushort_t* __restrict__ Vt,    // (B*H, 96, T) bf16
    ushort_t* __restrict__ attn,        // (B,T,EMB) bf16
    int Kd)
{
    __shared__ char lds[79872];
    ushort_t* Pt  = (ushort_t*)lds;             // 64 KiB: P 64x512 bf16 (swizzled)
    ushort_t* Bs  = (ushort_t*)lds;             // union: K tile 512x32 (32 KiB)
    ushort_t* As  = (ushort_t*)(lds + 32768);   // union: Q tile 64x32 (4 KiB)
    ushort_t* Vs0 = (ushort_t*)(lds + 65536);   // 6 KiB: V^T chunk buf 0
    ushort_t* Vs1 = (ushort_t*)(lds + 71680);   // 6 KiB: V^T chunk buf 1
    float* red    = (float*)(lds + 77824);      // 1 KiB
    float* red2   = (float*)(lds + 78848);      // 1 KiB

    // XCD swizzle: hw xcd = wg & 7 (round-robin)
    const int wg = blockIdx.x;
    const int xcd = wg & 7;
    const int sub = wg >> 3;          // 0..63, sequential within an XCD
    const int m0 = (sub & 7) * 64;    // m-tile fastest -> same bh consecutive
    const int bh = (sub >> 3) * 8 + xcd;
    const int b = bh >> 3, h = bh & 7;

    const int tid = threadIdx.x;
    const int w = tid >> 6, lane = tid & 63;
    const int g = w >> 2;             // row group: 0 = rows m0..31, 1 = +32..63
    const int wg4 = w & 3;            // role within group
    const int fr = lane & 15, kb = lane >> 4;
    const int cr = kb, cc = fr;
    const int swz = ((fr >> 1) & 3) << 3;

    const int rl = lane >> 2;                        // 0..15 within chunk
    const int cl = ((lane & 3) * 8) ^ (((rl >> 1) & 3) << 3);

    f32x4 acc[2][8] = {};

    // ---- phase 1: S = Q_hist K_hist^T over Kd feature cols ----
    for (int k0 = 0; k0 < Kd; k0 += 32) {
        if (w < 4) {                  // Q tile 64x32 = 4 chunks
            int r = w * 16 + rl;
            GLDS(Qh + ((long)(bh * TT + m0 + r)) * KHMAX + k0 + cl,
                 (char*)As + w * 1024);
        }
#pragma unroll
        for (int q = 0; q < 4; ++q) { // K tile 512x32 = 32 chunks, 4 per wave
            int ci = q * 8 + w;
            int r = ci * 16 + rl;
            GLDS(Kh + ((long)(bh * TT + r)) * KHMAX + k0 + cl,
                 (char*)Bs + ci * 1024);
        }
        __syncthreads();
        short8 af0 = *(const short8*)&As[(g * 32 + fr) * 32 + (kb * 8 ^ swz)];
        short8 af1 = *(const short8*)&As[(g * 32 + 16 + fr) * 32 + (kb * 8 ^ swz)];
#pragma unroll
        for (int fn = 0; fn < 8; ++fn) {
            short8 bf = *(const short8*)&Bs[(wg4 * 128 + fn * 16 + fr) * 32 + (kb * 8 ^ swz)];
            acc[0][fn] = __builtin_amdgcn_mfma_f32_16x16x32_bf16(af0, bf, acc[0][fn], 0, 0, 0);
            acc[1][fn] = __builtin_amdgcn_mfma_f32_16x16x32_bf16(af1, bf, acc[1][fn], 0, 0, 0);
        }
        __syncthreads();
    }

    // ---- phase 2: softmax over key axis (per 32-row group) ----
#pragma unroll
    for (int fm = 0; fm < 2; ++fm)
#pragma unroll
        for (int j = 0; j < 4; ++j) {
            float mx = -1e30f;
#pragma unroll
            for (int fn = 0; fn < 8; ++fn) mx = fmaxf(mx, acc[fm][fn][j]);
            for (int o = 1; o <= 8; o <<= 1) mx = fmaxf(mx, __shfl_xor(mx, o));
            if (cc == 0) red[g * 128 + wg4 * 32 + fm * 16 + cr * 4 + j] = mx;
        }
    __syncthreads();

    float inv[2][4];
#pragma unroll
    for (int fm = 0; fm < 2; ++fm)
#pragma unroll
        for (int j = 0; j < 4; ++j) {
            int r = fm * 16 + cr * 4 + j;
            const float* rg = red + g * 128;
            float mx = fmaxf(fmaxf(rg[r], rg[32 + r]), fmaxf(rg[64 + r], rg[96 + r]));
            float s = 0.f;
#pragma unroll
            for (int fn = 0; fn < 8; ++fn) {
                float e = __expf(acc[fm][fn][j] - mx);
                acc[fm][fn][j] = e;
                s += e;
            }
            for (int o = 1; o <= 8; o <<= 1) s += __shfl_xor(s, o);
            if (cc == 0) red2[g * 128 + wg4 * 32 + r] = s;
        }
    __syncthreads();
#pragma unroll
    for (int fm = 0; fm < 2; ++fm)
#pragma unroll
        for (int j = 0; j < 4; ++j) {
            int r = fm * 16 + cr * 4 + j;
            const float* rg = red2 + g * 128;
            inv[fm][j] = 1.f / (rg[r] + rg[32 + r] + rg[64 + r] + rg[96 + r]);
        }
    __syncthreads();   // acc scaled; Pt (Bs/As union) free to overwrite

    // write P (bf16) into swizzled LDS tile (512-wide rows: col ^= (row&7)<<3)
#pragma unroll
    for (int fm = 0; fm < 2; ++fm)
#pragma unroll
        for (int fn = 0; fn < 8; ++fn)
#pragma unroll
            for (int j = 0; j < 4; ++j) {
                int row = g * 32 + fm * 16 + cr * 4 + j;
                int col = wg4 * 128 + fn * 16 + cc;
                Pt[row * 512 + (col ^ ((row & 7) << 3))] = f2b(acc[fm][fn][j] * inv[fm][j]);
            }

    // prefetch V(0) into Vs0 under the publish barrier (pre-swizzled source)
    if (w < 6) {
        int r = w * 16 + rl;
        GLDS(Vt + ((long)(bh * ESS + r)) * TT + cl, (char*)Vs0 + w * 1024);
    }
    __syncthreads();   // P visible AND V(0) loaded (barrier drains vmcnt)

    // ---- phase 3: attn = P @ V, double-buffered V, 1 barrier/step ----
    const int wr = w >> 1, wc2 = w & 1;   // wr 0..3: 16-row slices of 64
    const int prow = wr * 16 + fr;
    f32x4 po[3] = {};
#pragma unroll
    for (int step = 0; step < 16; ++step) {
        const int j0 = step * 32;
        ushort_t* cur = (step & 1) ? Vs1 : Vs0;
        ushort_t* nxt = (step & 1) ? Vs0 : Vs1;
        if (step + 1 < 16 && w < 6) {
            int r = w * 16 + rl;
            GLDS(Vt + ((long)(bh * ESS + r)) * TT + j0 + 32 + cl, (char*)nxt + w * 1024);
        }
        short8 pa = *(const short8*)&Pt[prow * 512 + ((j0 + kb * 8) ^ ((prow & 7) << 3))];
#pragma unroll
        for (int fn = 0; fn < 3; ++fn) {
            short8 vb = *(const short8*)&cur[(wc2 * 48 + fn * 16 + fr) * 32 + (kb * 8 ^ swz)];
            po[fn] = __builtin_amdgcn_mfma_f32_16x16x32_bf16(pa, vb, po[fn], 0, 0, 0);
        }
        __syncthreads();   // publishes nxt, frees cur for step+1's staging
    }

#pragma unroll
    for (int fn = 0; fn < 3; ++fn)
#pragma unroll
        for (int j = 0; j < 4; ++j) {
            int grow = m0 + wr * 16 + cr * 4 + j;
            int gcol = h * ESS + wc2 * 48 + fn * 16 + cc;
            attn[((long)(b * TT + grow)) * EMBD + gcol] = f2b(po[fn][j]);
        }
}

// ---------------------------------------------------------------------------
__global__ __launch_bounds__(256) void cvt_f2b(
    const float* __restrict__ in, ushort_t* __restrict__ out)
{
    const int i = blockIdx.x * 256 + threadIdx.x;
    float4 v = ((const float4*)in)[i];
    ushort4v o = {f2b(v.x), f2b(v.y), f2b(v.z), f2b(v.w)};
    ((ushort4v*)out)[i] = o;
}

// ---------------------------------------------------------------------------
// Weight conversion, 8 floats/thread -> one 16B store.
// Per-layer layout in 8-float units: [wkqv 3456 | wproj 73728 | w1 294912 |
// w2 294912] = 667008 per layer.
// ---------------------------------------------------------------------------
static __device__ __forceinline__ void cvt_w_one8(
    int r8, int layer,
    const float* Wkqv, const float* Wproj, const float* w1, const float* w2,
    ushort_t* dst_layer)
{
    const float* src; int base;
    if (r8 < 3456)        { src = Wkqv  + (long)layer * 27648;   base = 0; }
    else if (r8 < 77184)  { src = Wproj + (long)layer * 589824;  base = 3456; }
    else if (r8 < 372096) { src = w1    + (long)layer * 2359296; base = 77184; }
    else                  { src = w2    + (long)layer * 2359296; base = 372096; }
    int j = r8 - base;
    float4 v0 = ((const float4*)src)[j * 2];
    float4 v1 = ((const float4*)src)[j * 2 + 1];
    ushort8v o = {f2b(v0.x), f2b(v0.y), f2b(v0.z), f2b(v0.w),
                  f2b(v1.x), f2b(v1.y), f2b(v1.z), f2b(v1.w)};
    ((ushort8v*)dst_layer)[r8] = o;
}

__global__ __launch_bounds__(256) void cvt_weights_all(
    const float* __restrict__ Wkqv, const float* __restrict__ Wproj,
    const float* __restrict__ w1, const float* __restrict__ w2,
    ushort_t* __restrict__ dst)      // 6 layers, stride 5336064 ushorts
{
    int i8 = blockIdx.x * 256 + threadIdx.x;    // 0 .. 4002047
    int layer = i8 / 667008;
    int r8 = i8 - layer * 667008;
    cvt_w_one8(r8, layer, Wkqv, Wproj, w1, w2, dst + (long)layer * 5336064);
}

__global__ __launch_bounds__(256) void cvt_weights_layer(
    const float* __restrict__ Wkqv, const float* __restrict__ Wproj,
    const float* __restrict__ w1, const float* __restrict__ w2,
    ushort_t* __restrict__ dst, int layer)      // one layer into dst
{
    int r8 = blockIdx.x * 256 + threadIdx.x;    // 0 .. 667007
    cvt_w_one8(r8, layer, Wkqv, Wproj, w1, w2, dst);
}

// ---------------------------------------------------------------------------
// Residual stream lives in bf16 (xio). LN computes in fp32:
//   xnew = LayerNorm(xio + sum_{i<NR} res_i (+bias)) * g + b -> bf16 xio
// FINAL variant also writes fp32 to xf (the harness output buffer).
// ---------------------------------------------------------------------------
template<int NR, int FINAL>
__global__ __launch_bounds__(192) void add_ln(
    ushort_t* __restrict__ xio, const ushort_t* __restrict__ res, long rstride,
    const float* __restrict__ bias,
    const float* __restrict__ g, const float* __restrict__ bta,
    float* __restrict__ xf)
{
    const long row = blockIdx.x;
    ushort4v* xr = (ushort4v*)(xio + row * EMBD);
    __shared__ float sh[4];
    const int tid = threadIdx.x;
    const int lane = tid & 63, w = tid >> 6;

    ushort4v xu = xr[tid];
    float v[4] = {b2f(xu.x), b2f(xu.y), b2f(xu.z), b2f(xu.w)};
#pragma unroll
    for (int p = 0; p < NR; ++p) {
        ushort4v u = ((const ushort4v*)(res + p * rstride + row * EMBD))[tid];
        v[0] += b2f(u.x); v[1] += b2f(u.y); v[2] += b2f(u.z); v[3] += b2f(u.w);
    }
    if (bias) {
        float4 b4 = ((const float4*)bias)[tid];
        v[0] += b4.x; v[1] += b4.y; v[2] += b4.z; v[3] += b4.w;
    }
    float s = v[0] + v[1] + v[2] + v[3];
    for (int o = 32; o; o >>= 1) s += __shfl_xor(s, o);
    if (lane == 0) sh[w] = s;
    __syncthreads();
    float mu = (sh[0] + sh[1] + sh[2]) * (1.f / EMBD);

    float var = 0.f;
#pragma unroll
    for (int c = 0; c < 4; ++c) { float d = v[c] - mu; var += d * d; }
    for (int o = 32; o; o >>= 1) var += __shfl_xor(var, o);
    __syncthreads();
    if (lane == 0) sh[w] = var;
    __syncthreads();
    var = (sh[0] + sh[1] + sh[2]) * (1.f / EMBD);
    float rstd = rsqrtf(var + 1e-5f);

    const float4 g4 = ((const float4*)g)[tid];
    const float4 b4 = ((const float4*)bta)[tid];
    float o0 = (v[0] - mu) * rstd * g4.x + b4.x;
    float o1 = (v[1] - mu) * rstd * g4.y + b4.y;
    float o2 = (v[2] - mu) * rstd * g4.z + b4.z;
    float o3 = (v[3] - mu) * rstd * g4.w + b4.w;
    ushort4v ob = {f2b(o0), f2b(o1), f2b(o2), f2b(o3)};
    xr[tid] = ob;
    if (FINAL) {
        float4 ov = {o0, o1, o2, o3};
        ((float4*)(xf + row * EMBD))[tid] = ov;
    }
}

// ---------------------------------------------------------------------------
extern "C" void kernel_launch(void* const* d_in, const int* in_sizes, int n_in,
                              void* d_out, int out_size, void* d_ws, size_t ws_size,
                              hipStream_t stream) {
    const float* x_in  = (const float*)d_in[0];
    const float* Wkqv  = (const float*)d_in[1];
    const float* Wproj = (const float*)d_in[2];
    const float* ln1_g = (const float*)d_in[3];
    const float* ln1_b = (const float*)d_in[4];
    const float* ln2_g = (const float*)d_in[5];
    const float* ln2_b = (const float*)d_in[6];
    const float* ff_w1 = (const float*)d_in[7];
    const float* ff_b1 = (const float*)d_in[8];
    const float* ff_w2 = (const float*)d_in[9];
    const float* ff_b2 = (const float*)d_in[10];

    float* xout = (float*)d_out;                          // written by final LN only
    char* ws = (char*)d_ws;
    ushort_t* Qh     = (ushort_t*)(ws);                   // 37.7 MB
    ushort_t* Kh     = (ushort_t*)(ws + 37748736);        // 37.7 MB
    ushort_t* Vtb    = (ushort_t*)(ws + 75497472);        // 6.3 MB (union res0)
    ushort_t* resb   = (ushort_t*)(ws + 75497472);        // 4 x 6.3 MB bf16 partials
    ushort_t* h1b    = (ushort_t*)(ws + 100663296);       // 25.2 MB
    ushort_t* xb     = (ushort_t*)(ws + 125829120);       // 6.3 MB bf16 residual stream
    ushort_t* attnb  = (ushort_t*)(ws + 132120576);       // 6.3 MB
    ushort_t* Wall   = (ushort_t*)(ws + 138412032);
    const size_t WLAYER_B = 10672128;          // bytes per layer slot
    const int    WLAYER_E = 5336064;           // ushorts per layer slot
    const int big = (ws_size >= 138412032 + 6 * WLAYER_B) ? 1 : 0;
    const long RES_STRIDE = 3145728;           // partial stride in elements (6.3 MB)

    cvt_f2b<<<3072, 256, 0, stream>>>(x_in, xb);
    if (big)
        cvt_weights_all<<<15633, 256, 0, stream>>>(Wkqv, Wproj, ff_w1, ff_w2, Wall);

    const float scale = 0.10206207261596577f;  // 1/sqrt(96)

    for (int l = 0; l < NLAYER; ++l) {
        const float* b1 = ff_b1 + (size_t)l * FFD;
        const float* b2 = ff_b2 + (size_t)l * EMBD;

        ushort_t* Wl = Wall + (big ? (long)l * WLAYER_E : 0);
        if (!big)
            cvt_weights_layer<<<2606, 256, 0, stream>>>(Wkqv, Wproj, ff_w1, ff_w2, Wl, l);
        ushort_t* Wkqvb  = Wl;
        ushort_t* Wprojb = Wl + 27648;
        ushort_t* W1b    = Wl + 617472;
        ushort_t* W2b    = Wl + 2976768;

        // kqv GEMM with direct scatter epilogue: K,Q(scaled) -> history, V -> Vt
        kqv_gemm<<<dim3(3, 256, 1), 256, 0, stream>>>(
            xb, Wkqvb, Kh, Qh, Vtb, l * ESS, scale);

        // fused: S = Qh Kh^T (scale pre-folded, Kd=96*(l+1)); attn = softmax @ V
        fused_attn<<<512, 512, 0, stream>>>(
            Qh, Kh, Vtb, attnb, ESS * (l + 1));

        // res partials (bf16) = attn @ Wproj^T split-K2 (Vtb dead)
        gemm_mfma<128, 128, 2, 2, 1, 0, 0, 0><<<dim3(6, 32, 2), 256, 0, stream>>>(
            attnb, EMBD, Wprojb, EMBD, resb, EMBD, EMBD / 2, 1.f, nullptr,
            1, 384, 0, 384, 0, RES_STRIDE, 0);

        add_ln<2, 0><<<BB * TT, 192, 0, stream>>>(xb, resb, RES_STRIDE, nullptr,
            ln1_g + (size_t)l * EMBD, ln1_b + (size_t)l * EMBD, nullptr);

        // h1 = gelu(xb @ W1^T + b1), fast-gelu epilogue
        gemm_mfma<128, 128, 2, 2, 1, 1, 1, 0><<<dim3(24, 32, 1), 256, 0, stream>>>(
            xb, EMBD, W1b, EMBD, h1b, FFD, EMBD, 1.f, b1,
            1, 0, 0, 0, 0, 0, 0);

        // res partials (bf16) = h1 @ W2^T split-K4 (b2 applied in ln2)
        gemm_mfma<128, 128, 2, 2, 1, 0, 0, 0><<<dim3(6, 32, 4), 256, 0, stream>>>(
            h1b, FFD, W2b, FFD, resb, EMBD, FFD / 4, 1.f, nullptr,
            1, 768, 0, 768, 0, RES_STRIDE, 0);

        if (l == NLAYER - 1)
            add_ln<4, 1><<<BB * TT, 192, 0, stream>>>(xb, resb, RES_STRIDE, b2,
                ln2_g + (size_t)l * EMBD, ln2_b + (size_t)l * EMBD, xout);
        else
            add_ln<4, 0><<<BB * TT, 192, 0, stream>>>(xb, resb, RES_STRIDE, b2,
                ln2_g + (size_t)l * EMBD, ln2_b + (size_t)l * EMBD, nullptr);
    }
}